// Round 1
// 1792.166 us; speedup vs baseline: 1.0014x; 1.0014x over previous
//
#include <hip/hip_runtime.h>
#include <hip/hip_bf16.h>
#include <math.h>

// ---- model dims ----
constexpr int Bn  = 4;
constexpr int Tn  = 8192;
constexpr int Dn  = 1024;
constexpr int Pn  = 512;
constexpr int SEGn= 16;     // T/P
constexpr int Sn  = 4;
constexpr int Ln  = 4;
constexpr int NHn = 16;
constexpr int NKVn= 4;
constexpr int HDn = 64;
constexpr int FFn = 4096;
constexpr int KCn = 256;
constexpr int Vn  = 257;
constexpr int DHn = 512;    // conv hidden (D/2)

// ---- workspace layout (float elements). total = 33,015,296 floats = 126 MB ----
constexpr long OFF_EW  = 0;                       // 3*257*512 = 394752
constexpr long OFF_CA  = 394752;                  // B*T
constexpr long OFF_CB  = 427520;
constexpr long OFF_CC  = 460288;
constexpr long OFF_ENT = 493056;                  // B*P
constexpr long OFF_IDX = 495104;                  // B*P (int)
constexpr long OFF_XP  = 497152;                  // B*P*D = 2097152
constexpr long OFF_RL  = 2594304;                 // B*P
constexpr long OFF_SEL = 2596352;                 // B*KC (int)
constexpr long OFF_G   = 2597376;                 // B*KC
constexpr long SCR     = 2598400;
// layer-phase scratch (offsets relative to SCR):
constexpr long SC_XS   = 0;         // 1048576
constexpr long SC_H    = 1048576;   // 1048576 (interleaved hi|lo ushort rows)
constexpr long SC_Q    = 2097152;   // 1048576
constexpr long SC_K    = 3145728;   // 262144
constexpr long SC_V    = 3407872;   // 262144
constexpr long SC_AOUT = 3670016;   // 1048576 (hi|lo)
constexpr long SC_AO   = 4718592;   // 1048576
constexpr long SC_H2   = 5767168;   // 1048576 (hi|lo)
constexpr long SC_GACT = 6815744;   // 4194304
constexpr long SC_UACT = 11010048;  // 4194304
constexpr long SC_FF   = 15204352;  // 1048576
// decoder-phase (overlays layer region):
constexpr long SC_PROJ = 0;         // 8388608
constexpr long SC_HMLP = 8388608;   // 524288
constexpr long SC_WIN  = 8912896;   // 8192
constexpr long SC_Y    = 8921088;   // 8388608 (hi|lo: 8192 rows x 2048 ushort)
// encoder-phase temporaries (overlay scr, used before layer loop):
constexpr long SC_EA   = 0;         // 384*2048 ushort = 393216 floats
constexpr long SC_WB   = 524288;    // 1536*2048 ushort = 1572864 floats
// new regions (absolute float offsets in ws):
constexpr long OFF_WT    = 19908096;  // 4M floats = 8M ushort: WHL [N][2K] interleaved
constexpr long OFF_PARTS = 24102400;  // 4718592 floats (max: head 2*8192*257)
constexpr long OFF_GHL   = 28820992;  // 4M floats: gact-hl (layer) / xp-hl (decoder)
// total 33015296

typedef __attribute__((ext_vector_type(8))) short short8;
typedef __attribute__((ext_vector_type(4))) float floatx4;

// ---- helpers ----
__device__ __forceinline__ float geluf(float x) {
    // tanh-gelu via fast exp: tanh(u) = 1 - 2/(e^{2u}+1) (branchless, inf-safe)
    float u = 0.7978845608028654f * (x + 0.044715f * x * x * x);
    float e = __expf(2.f * u);
    float t = 1.f - 2.f / (e + 1.f);
    return 0.5f * x * (1.f + t);
}
__device__ __forceinline__ float sigmf(float x) { return 1.f / (1.f + expf(-x)); }

// fp32 -> bf16 hi/lo split (truncation; x ~= hi + lo, err ~2^-17 rel)
__device__ __forceinline__ void cvt_hilo(float x, unsigned short& h, unsigned short& l) {
    unsigned u = __float_as_uint(x);
    h = (unsigned short)(u >> 16);
    float r = x - __uint_as_float(u & 0xffff0000u);
    l = (unsigned short)(__float_as_uint(r) >> 16);
}

// async global->LDS, 16B per lane (dest = wave-uniform base + lane*16)
typedef const __attribute__((address_space(1))) unsigned int* gas_p;
typedef __attribute__((address_space(3))) unsigned int* las_p;
__device__ __forceinline__ void gload16(const unsigned short* g, unsigned short* l) {
    __builtin_amdgcn_global_load_lds((gas_p)g, (las_p)l, 16, 0, 0);
}

// block (256 threads) sum reduce; red must be __shared__ float[4]
__device__ __forceinline__ float blk_sum256(float v, float* red) {
    for (int o = 32; o > 0; o >>= 1) v += __shfl_down(v, o);
    int lane = threadIdx.x & 63, w = threadIdx.x >> 6;
    if (lane == 0) red[w] = v;
    __syncthreads();
    float r = red[0] + red[1] + red[2] + red[3];
    __syncthreads();
    return r;
}

// ---- encoder A-operand: emb padded to 384 rows, interleaved hi|lo ----
__global__ void k_emb_pad(const float* __restrict__ emb, unsigned short* __restrict__ EA) {
    int i = blockIdx.x * blockDim.x + threadIdx.x;
    if (i >= 384 * 1024) return;
    int r = i >> 10, d = i & 1023;
    float v = (r < Vn) ? emb[r * 1024 + d] : 0.f;
    unsigned short hh, ll;
    cvt_hilo(v, hh, ll);
    EA[(long)r * 2048 + d] = hh;
    EA[(long)r * 2048 + 1024 + d] = ll;
}

// ---- encoder B-operand: WB[n=o*3+dk][k] = w1[o][k][dk], interleaved hi|lo ----
__global__ void k_wconv_w1(const float* __restrict__ w1, unsigned short* __restrict__ WB) {
    int i = blockIdx.x * blockDim.x + threadIdx.x;
    if (i >= 1536 * 1024) return;
    int n = i >> 10, k = i & 1023;
    float v = w1[(n / 3) * 3072 + k * 3 + (n % 3)];
    unsigned short hh, ll;
    cvt_hilo(v, hh, ll);
    WB[(long)n * 2048 + k] = hh;
    WB[(long)n * 2048 + 1024 + k] = ll;
}

// ---- reduce EW splitK partials and remap [v][o*3+dk] -> [dk][v][o] ----
__global__ void k_ewred(const float* __restrict__ parts, float* __restrict__ EW) {
    int i = blockIdx.x * blockDim.x + threadIdx.x;
    if (i >= 3 * Vn * DHn) return;
    int dk = i / (Vn * DHn);
    int rem = i - dk * (Vn * DHn);
    int v = rem >> 9, o = rem & 511;
    long src = (long)v * 1536 + o * 3 + dk;
    float s = 0.f;
    constexpr long MN = 384L * 1536;
    #pragma unroll
    for (int c = 0; c < 4; c++) s += parts[c * MN + src];
    EW[i] = s;
}

// ---- K1: per (b,t): h1 column via EW lookups + gelu, reduce to 3 dots with w2 ----
__global__ void k_conv1(const int* __restrict__ tok, const float* __restrict__ EW,
                        const float* __restrict__ b1, const float* __restrict__ w2,
                        float* __restrict__ cA, float* __restrict__ cB, float* __restrict__ cC) {
    int wave = threadIdx.x >> 6, lane = threadIdx.x & 63;
    int gidx = blockIdx.x * 4 + wave;     // b*T + t
    int b = gidx / Tn, t = gidx - b * Tn;
    int tk  = tok[b * Tn + t];
    int tkm = (t > 0)      ? tok[b * Tn + t - 1] : -1;
    int tkp = (t < Tn - 1) ? tok[b * Tn + t + 1] : -1;
    const float* E0 = EW;
    const float* E1 = EW + (long)Vn * DHn;
    const float* E2 = EW + 2L * Vn * DHn;
    float a0 = 0.f, a1 = 0.f, a2 = 0.f;
    #pragma unroll
    for (int u = 0; u < DHn / 64; u++) {
        int o = lane + u * 64;
        float s = b1[o] + E1[tk * DHn + o];
        if (tkm >= 0) s += E0[tkm * DHn + o];
        if (tkp >= 0) s += E2[tkp * DHn + o];
        float hg = geluf(s);
        a0 += hg * w2[o * 3 + 0];
        a1 += hg * w2[o * 3 + 1];
        a2 += hg * w2[o * 3 + 2];
    }
    for (int o = 32; o > 0; o >>= 1) {
        a0 += __shfl_down(a0, o); a1 += __shfl_down(a1, o); a2 += __shfl_down(a2, o);
    }
    if (lane == 0) { cA[gidx] = a0; cB[gidx] = a1; cC[gidx] = a2; }
}

// ---- K2: lg per token -> per-patch softmax -> ent, idx ----
__global__ void k_patchstats(const float* __restrict__ cA, const float* __restrict__ cB,
                             const float* __restrict__ cC, const float* __restrict__ b2,
                             float* __restrict__ ent_out, int* __restrict__ idx_out) {
    int pid = blockIdx.x * blockDim.x + threadIdx.x;   // b*P + p
    if (pid >= Bn * Pn) return;
    int b = pid / Pn, p = pid - b * Pn;
    float lgv[SEGn];
    float m = -3.4e38f;
    for (int s = 0; s < SEGn; s++) {
        int t = p * SEGn + s;
        float v = b2[0] + cB[b * Tn + t];
        if (t > 0)      v += cA[b * Tn + t - 1];
        if (t < Tn - 1) v += cC[b * Tn + t + 1];
        lgv[s] = v; m = fmaxf(m, v);
    }
    float Z = 0.f;
    for (int s = 0; s < SEGn; s++) { lgv[s] = expf(lgv[s] - m); Z += lgv[s]; }
    float inv = 1.f / Z;
    float bp = 0.f, en = 0.f;
    for (int s = 0; s < SEGn; s++) {
        float w = lgv[s] * inv;
        bp += w * (float)(p * SEGn + s);
        en -= w * logf(fmaxf(w, 1e-8f));
    }
    en *= (1.f / 2.772588722239781f);   // / ln(16)
    ent_out[pid] = en;
    int ix = (int)bp;
    ix = ix < 0 ? 0 : (ix > Tn - 1 ? Tn - 1 : ix);
    idx_out[pid] = ix;
}

// ---- K3: xp[b,p,:] = rmsnorm(emb[tok[b, idx[b,p]]], enc_norm_w). block per row ----
__global__ void k_xp(const int* __restrict__ tok, const int* __restrict__ idx,
                     const float* __restrict__ emb, const float* __restrict__ nw,
                     float* __restrict__ xp) {
    int pid = blockIdx.x;
    int b = pid / Pn;
    int tk = tok[b * Tn + idx[pid]];
    const float* row = emb + (long)tk * Dn;
    __shared__ float red[4];
    float v[4]; float ss = 0.f;
    #pragma unroll
    for (int j = 0; j < 4; j++) { v[j] = row[threadIdx.x + j * 256]; ss += v[j] * v[j]; }
    ss = blk_sum256(ss, red);
    float sc = 1.f / sqrtf(ss * (1.f / Dn) + 1e-6f);
    #pragma unroll
    for (int j = 0; j < 4; j++) {
        int d = threadIdx.x + j * 256;
        xp[(long)pid * Dn + d] = v[j] * sc * nw[d];
    }
}

// ---- K4: rl[b,p] = xp[b,p,:]·rw + ent. block per row ----
__global__ void k_router(const float* __restrict__ xp, const float* __restrict__ rw,
                         const float* __restrict__ ent, float* __restrict__ rl) {
    int pid = blockIdx.x;
    const float* xr = xp + (long)pid * Dn;
    __shared__ float red[4];
    float s = 0.f;
    #pragma unroll
    for (int j = 0; j < 4; j++) { int d = threadIdx.x + j * 256; s += xr[d] * rw[d]; }
    s = blk_sum256(s, red);
    if (threadIdx.x == 0) rl[pid] = s + ent[pid];
}

// ---- K5: exact top-k (KC of P) with jax tie semantics, output ascending by index ----
__global__ void k_topk(const float* __restrict__ rl, int* __restrict__ sel, float* __restrict__ g) {
    int b = blockIdx.x, p = threadIdx.x;
    __shared__ float vals[Pn];
    __shared__ int flag[Pn];
    float v = rl[b * Pn + p];
    vals[p] = v;
    __syncthreads();
    int rank = 0;
    for (int q = 0; q < Pn; q++) {
        float vq = vals[q];
        rank += (vq > v || (vq == v && q < p)) ? 1 : 0;
    }
    int selected = rank < KCn ? 1 : 0;
    flag[p] = selected;
    __syncthreads();
    if (selected) {
        int pos = 0;
        for (int q = 0; q < p; q++) pos += flag[q];
        sel[b * KCn + pos] = p;
        g[b * KCn + pos] = sigmf(v);
    }
}

// ---- K6: gather xs = xp[b, sel]; h = rmsnorm(xs, ln1) emitted interleaved hi|lo ----
__global__ void k_gather_ln1(const float* __restrict__ xp, const int* __restrict__ sel,
                             const float* __restrict__ w, float* __restrict__ xs,
                             unsigned short* __restrict__ hHL) {
    int r = blockIdx.x;            // b*KC + j
    int b = r / KCn;
    int p = sel[r];
    const float* src = xp + ((long)b * Pn + p) * Dn;
    __shared__ float red[4];
    float v[4]; float ss = 0.f;
    #pragma unroll
    for (int j = 0; j < 4; j++) { v[j] = src[threadIdx.x + j * 256]; ss += v[j] * v[j]; }
    ss = blk_sum256(ss, red);
    float sc = 1.f / sqrtf(ss * (1.f / Dn) + 1e-6f);
    #pragma unroll
    for (int j = 0; j < 4; j++) {
        int d = threadIdx.x + j * 256;
        xs[(long)r * Dn + d] = v[j];
        unsigned short hh, ll;
        cvt_hilo(v[j] * sc * w[d], hh, ll);
        hHL[(long)r * 2048 + d] = hh;
        hHL[(long)r * 2048 + 1024 + d] = ll;
    }
}

// ---- weight convert+transpose: W[K][N] fp32 -> WHL[n][2K] interleaved hi|lo ----
// grid (ceil(N/32), K/32), block 256 (=32x8)
__global__ void k_wconv(const float* __restrict__ Wm, unsigned short* __restrict__ Whl,
                        int K, int N) {
    __shared__ float t[32][33];
    int n0 = blockIdx.x * 32, k0 = blockIdx.y * 32;
    int tx = threadIdx.x & 31, ty = threadIdx.x >> 5;
    #pragma unroll
    for (int r = 0; r < 4; r++) {
        int k = k0 + ty + 8 * r, n = n0 + tx;
        t[ty + 8 * r][tx] = (n < N) ? Wm[(long)k * N + n] : 0.f;
    }
    __syncthreads();
    long K2 = 2L * K;
    #pragma unroll
    for (int r = 0; r < 4; r++) {
        int n = n0 + ty + 8 * r, k = k0 + tx;
        float v = t[tx][ty + 8 * r];
        unsigned short hh, ll;
        cvt_hilo(v, hh, ll);
        Whl[(long)n * K2 + k] = hh;
        Whl[(long)n * K2 + K + k] = ll;
    }
}

// ---- elementwise fp32 -> interleaved hi|lo rows of 1024 ----
__global__ void k_xcvt(const float* __restrict__ src, unsigned short* __restrict__ dhl, int n) {
    int i = blockIdx.x * blockDim.x + threadIdx.x;
    if (i >= n) return;
    int r = i >> 10, d = i & 1023;
    unsigned short hh, ll;
    cvt_hilo(src[i], hh, ll);
    dhl[(long)r * 2048 + d] = hh;
    dhl[(long)r * 2048 + 1024 + d] = ll;
}

// ---- MFMA GEMM on interleaved hi|lo operands. A[M][2K], B[N][2K] ushort rows
//      (first K = bf16-hi, next K = bf16-lo). global_load_lds staging with XOR
//      chunk swizzle (pos = chunk ^ (row&7) within 128B LDS rows) applied on the
//      per-lane global source (stage) and the ds_read address (read) — rule #21.
// grid (ceil(N/128), M/128, splitK), block 256. splitK>1 -> parts; else C(+bias).
// M%128==0, (K/splitK)%32==0.
__global__ __launch_bounds__(256, 2) void k_mfma3(
        const unsigned short* __restrict__ Ag, const unsigned short* __restrict__ Bg,
        float* __restrict__ Cmat, const float* __restrict__ bias,
        int M, int N, int K, int splitK, float* __restrict__ parts) {
    __shared__ alignas(16) unsigned short As[128 * 64], Bs[128 * 64];
    int tid = threadIdx.x;
    int m0 = blockIdx.y * 128, n0 = blockIdx.x * 128;
    int kc = blockIdx.z;
    int Kc = K / splitK, kbase = kc * Kc, KT = Kc >> 5;
    int lane = tid & 63, wid = tid >> 6;
    int wm = (wid & 1) * 64, wn = (wid >> 1) * 64;
    int quad = lane >> 4, l16 = lane & 15;

    // staging geometry: 16 segments of 1KB per tile (4 per wave); lane L covers
    // row seg*8 + (L>>3), LDS slot L&7, which must hold logical chunk (L&7)^(row&7).
    int srow8 = lane >> 3;
    int spos  = lane & 7;
    int cch   = spos ^ srow8;                       // row&7 == srow8 for every segment
    long K2 = 2L * K;
    long coff = (cch < 4) ? (long)(cch * 8) : (long)K + (long)((cch - 4) * 8);
    const unsigned short* Aseg = Ag + (long)(m0 + srow8) * K2 + coff;
    const unsigned short* Bseg = Bg + (long)(n0 + srow8) * K2 + coff;   // OOB rows (pad) read garbage, never stored

    floatx4 acc[4][4];
    #pragma unroll
    for (int i = 0; i < 4; i++)
        #pragma unroll
        for (int j = 0; j < 4; j++) acc[i][j] = (floatx4){0.f, 0.f, 0.f, 0.f};

    int ph = quad ^ (l16 & 7);                      // hi-chunk slot; lo = ph^4
    for (int ks = 0; ks < KT; ks++) {
        long kb = kbase + (long)ks * 32;
        __syncthreads();                            // WAR: prev-tile frag reads done
        #pragma unroll
        for (int t = 0; t < 4; t++) {
            int sa = wid * 4 + t;
            gload16(Aseg + (long)sa * 8 * K2 + kb, As + sa * 512);
            gload16(Bseg + (long)sa * 8 * K2 + kb, Bs + sa * 512);
        }
        __syncthreads();                            // compiler drains vmcnt(0) before barrier

        short8 ah[4], al2[4], bh[4], bl2[4];
        #pragma unroll
        for (int i = 0; i < 4; i++) {
            int r = wm + i * 16 + l16;
            ah[i]  = *(const short8*)&As[r * 64 + ph * 8];
            al2[i] = *(const short8*)&As[r * 64 + (ph ^ 4) * 8];
        }
        #pragma unroll
        for (int j = 0; j < 4; j++) {
            int c = wn + j * 16 + l16;
            bh[j]  = *(const short8*)&Bs[c * 64 + ph * 8];
            bl2[j] = *(const short8*)&Bs[c * 64 + (ph ^ 4) * 8];
        }
        #pragma unroll
        for (int i = 0; i < 4; i++)
            #pragma unroll
            for (int j = 0; j < 4; j++) {
                acc[i][j] = __builtin_amdgcn_mfma_f32_16x16x32_bf16(ah[i],  bh[j],  acc[i][j], 0, 0, 0);
                acc[i][j] = __builtin_amdgcn_mfma_f32_16x16x32_bf16(ah[i],  bl2[j], acc[i][j], 0, 0, 0);
                acc[i][j] = __builtin_amdgcn_mfma_f32_16x16x32_bf16(al2[i], bh[j],  acc[i][j], 0, 0, 0);
            }
    }

    // epilogue: C/D layout col=lane&15, row=quad*4+reg (m89/m91)
    long MN = (long)M * N;
    #pragma unroll
    for (int j = 0; j < 4; j++) {
        int n = n0 + wn + j * 16 + l16;
        if (n >= N) continue;
        float bvx = bias ? bias[n] : 0.f;
        #pragma unroll
        for (int i = 0; i < 4; i++) {
            int mb = m0 + wm + i * 16 + quad * 4;
            #pragma unroll
            for (int r = 0; r < 4; r++) {
                if (splitK > 1) parts[kc * MN + (long)(mb + r) * N + n] = acc[i][j][r];
                else            Cmat[(long)(mb + r) * N + n] = acc[i][j][r] + bvx;
            }
        }
    }
}

// ---- reduce splitK partials (+optional bias) ----
__global__ void k_reduce(const float* __restrict__ parts, float* __restrict__ out,
                         const float* __restrict__ bias, long MN, int sk, int N) {
    long i = (long)blockIdx.x * blockDim.x + threadIdx.x;
    if (i >= MN) return;
    float s = 0.f;
    for (int c = 0; c < sk; c++) s += parts[c * MN + i];
    if (bias) s += bias[(int)(i % N)];
    out[i] = s;
}

// ---- RoPE in-place on (B*KC, nh*64), positions = sel[row] ----
__global__ void k_rope(float* __restrict__ buf, const int* __restrict__ sel, int nh) {
    int tid = blockIdx.x * blockDim.x + threadIdx.x;
    int total = Bn * KCn * nh * 32;
    if (tid >= total) return;
    int d = tid & 31;
    int h = (tid >> 5) % nh;
    int r = tid / (32 * nh);
    int pos = sel[r];
    float theta = powf(10000.f, -(float)(2 * d) / 64.f);
    float ang = (float)pos * theta;
    float c = cosf(ang), s = sinf(ang);
    long base = (long)r * (nh * 64) + h * 64 + d;
    float x1 = buf[base], x2 = buf[base + 32];
    buf[base]      = x1 * c - x2 * s;
    buf[base + 32] = x2 * c + x1 * s;
}

// ---- MFMA flash attention (R4 structure); epilogue emits aout interleaved hi|lo ----
constexpr int APS = 72;
__global__ __launch_bounds__(256) void k_attn(const float* __restrict__ q, const float* __restrict__ k,
                       const float* __restrict__ v, unsigned short* __restrict__ aoHL) {
    int bx = blockIdx.x, h = blockIdx.y, b = blockIdx.z;
    int hk = h >> 2;
    int qb0 = bx * 64;
    int tid = threadIdx.x, lane = tid & 63, wid = tid >> 6;
    int quad = lane >> 4, l16 = lane & 15;
    __shared__ alignas(16) unsigned short LdsA[9216], LdsB[9216];
    unsigned short* Kh = LdsA;          unsigned short* Kl = LdsB;
    unsigned short* Ph = LdsA;          unsigned short* Pl = LdsB;
    unsigned short* Vth = LdsA + 4608;  unsigned short* Vtl = LdsB + 4608;

    int qrow = qb0 + wid * 16 + l16;
    short8 qh[2], ql[2];
    #pragma unroll
    for (int ks = 0; ks < 2; ks++) {
        const float* qp = q + ((long)(b * KCn + qrow)) * (NHn * HDn) + h * HDn + ks * 32 + quad * 8;
        float tmp[8];
        *(float4*)tmp = *(const float4*)qp;
        *(float4*)(tmp + 4) = *(const float4*)(qp + 4);
        #pragma unroll
        for (int j = 0; j < 8; j++) {
            unsigned short hh, ll;
            cvt_hilo(tmp[j], hh, ll);
            qh[ks][j] = (short)hh; ql[ks][j] = (short)ll;
        }
    }

    floatx4 sacc[16];
    #pragma unroll
    for (int t = 0; t < 16; t++) sacc[t] = (floatx4){0.f, 0.f, 0.f, 0.f};

    int qmax = qb0 + 63;
    int nkc = qmax / 128 + 1;
    for (int kc = 0; kc < nkc; kc++) {
        __syncthreads();
        {
            int r = tid >> 1, dh = (tid & 1) * 32;
            const float* kp = k + ((long)(b * KCn + kc * 128 + r)) * (NKVn * HDn) + hk * HDn + dh;
            #pragma unroll
            for (int f = 0; f < 8; f++) {
                float tmp[4];
                *(float4*)tmp = *(const float4*)(kp + f * 4);
                unsigned short h0, h1, h2, h3, l0, l1, l2, l3;
                cvt_hilo(tmp[0], h0, l0); cvt_hilo(tmp[1], h1, l1);
                cvt_hilo(tmp[2], h2, l2); cvt_hilo(tmp[3], h3, l3);
                *(ushort4*)&Kh[r * APS + dh + f * 4] = make_ushort4(h0, h1, h2, h3);
                *(ushort4*)&Kl[r * APS + dh + f * 4] = make_ushort4(l0, l1, l2, l3);
            }
        }
        __syncthreads();
        #pragma unroll
        for (int tj = 0; tj < 8; tj++) {
            int kr = tj * 16 + l16;
            int gt = kc * 8 + tj;
            #pragma unroll
            for (int ks = 0; ks < 2; ks++) {
                short8 bh0 = *(const short8*)&Kh[kr * APS + ks * 32 + quad * 8];
                short8 bl0 = *(const short8*)&Kl[kr * APS + ks * 32 + quad * 8];
                sacc[gt] = __builtin_amdgcn_mfma_f32_16x16x32_bf16(qh[ks], bh0, sacc[gt], 0, 0, 0);
                sacc[gt] = __builtin_amdgcn_mfma_f32_16x16x32_bf16(qh[ks], bl0, sacc[gt], 0, 0, 0);
                sacc[gt] = __builtin_amdgcn_mfma_f32_16x16x32_bf16(ql[ks], bh0, sacc[gt], 0, 0, 0);
            }
        }
    }

    float rowinv[4];
    #pragma unroll
    for (int r = 0; r < 4; r++) {
        int qg = qb0 + wid * 16 + quad * 4 + r;
        float mm = -3.4e38f;
        #pragma unroll
        for (int t = 0; t < 16; t++) {
            int key = t * 16 + l16;
            float s = (key <= qg) ? sacc[t][r] * 0.125f : -1e30f;
            sacc[t][r] = s;
            mm = fmaxf(mm, s);
        }
        #pragma unroll
        for (int o = 1; o < 16; o <<= 1) mm = fmaxf(mm, __shfl_xor(mm, o));
        float zz = 0.f;
        #pragma unroll
        for (int t = 0; t < 16; t++) {
            float e = expf(sacc[t][r] - mm);
            sacc[t][r] = e; zz += e;
        }
        #pragma unroll
        for (int o = 1; o < 16; o <<= 1) zz += __shfl_xor(zz, o);
        rowinv[r] = 1.f / zz;
    }

    floatx4 oacc[4];
    #pragma unroll
    for (int dt = 0; dt < 4; dt++) oacc[dt] = (floatx4){0.f, 0.f, 0.f, 0.f};
    int npv = qmax / 64 + 1;
    for (int c4 = 0; c4 < npv; c4++) {
        __syncthreads();
        {
            #pragma unroll
            for (int it = 0; it < 4; it++) {
                int task = tid + 256 * it;
                int kloc = task & 63, d4 = (task >> 6) * 4;
                float tmp[4];
                *(float4*)tmp = *(const float4*)(v + ((long)(b * KCn + c4 * 64 + kloc)) * (NKVn * HDn) + hk * HDn + d4);
                #pragma unroll
                for (int i = 0; i < 4; i++) {
                    unsigned short hh, ll;
                    cvt_hilo(tmp[i], hh, ll);
                    Vth[(d4 + i) * APS + kloc] = hh;
                    Vtl[(d4 + i) * APS + kloc] = ll;
                }
            }
        }
        #pragma unroll
        for (int tt = 0; tt < 4; tt++) {
            int t = c4 * 4 + tt;
            #pragma unroll
            for (int r = 0; r < 4; r++) {
                int row = wid * 16 + quad * 4 + r;
                float pv2 = sacc[t][r] * rowinv[r];
                unsigned short hh, ll;
                cvt_hilo(pv2, hh, ll);
                Ph[row * APS + tt * 16 + l16] = hh;
                Pl[row * APS + tt * 16 + l16] = ll;
            }
        }
        __syncthreads();
        short8 pah[2], pal[2];
        #pragma unroll
        for (int ks = 0; ks < 2; ks++) {
            pah[ks] = *(const short8*)&Ph[(wid * 16 + l16) * APS + ks * 32 + quad * 8];
            pal[ks] = *(const short8*)&Pl[(wid * 16 + l16) * APS + ks * 32 + quad * 8];
        }
        #pragma unroll
        for (int dt = 0; dt < 4; dt++) {
            #pragma unroll
            for (int ks = 0; ks < 2; ks++) {
                short8 vbh = *(const short8*)&Vth[(dt * 16 + l16) * APS + ks * 32 + quad * 8];
                short8 vbl = *(const short8*)&Vtl[(dt * 16 + l16) * APS + ks * 32 + quad * 8];
                oacc[dt] = __builtin_amdgcn_mfma_f32_16x16x32_bf16(pah[ks], vbh, oacc[dt], 0, 0, 0);
                oacc[dt] = __builtin_amdgcn_mfma_f32_16x16x32_bf16(pah[ks], vbl, oacc[dt], 0, 0, 0);
                oacc[dt] = __builtin_amdgcn_mfma_f32_16x16x32_bf16(pal[ks], vbh, oacc[dt], 0, 0, 0);
            }
        }
    }

    #pragma unroll
    for (int dt = 0; dt < 4; dt++) {
        #pragma unroll
        for (int r = 0; r < 4; r++) {
            int row = qb0 + wid * 16 + quad * 4 + r;
            long base = ((long)(b * KCn + row)) * 2048 + h * HDn + dt * 16 + l16;
            unsigned short hh, ll;
            cvt_hilo(oacc[dt][r], hh, ll);
            aoHL[base] = hh; aoHL[base + 1024] = ll;
        }
    }
}

// ---- x2 = xs + ao; h2 = rmsnorm(x2, ln2) emitted interleaved hi|lo ----
__global__ void k_add_ln2(const float* __restrict__ xs, const float* __restrict__ ao,
                          const float* __restrict__ w, unsigned short* __restrict__ h2HL) {
    int r = blockIdx.x;
    __shared__ float red[4];
    float v[4]; float ss = 0.f;
    #pragma unroll
    for (int j = 0; j < 4; j++) {
        int d = threadIdx.x + j * 256;
        float x = xs[(long)r * Dn + d] + ao[(long)r * Dn + d];
        v[j] = x; ss += x * x;
    }
    ss = blk_sum256(ss, red);
    float sc = 1.f / sqrtf(ss * (1.f / Dn) + 1e-6f);
    #pragma unroll
    for (int j = 0; j < 4; j++) {
        int d = threadIdx.x + j * 256;
        unsigned short hh, ll;
        cvt_hilo(v[j] * sc * w[d], hh, ll);
        h2HL[(long)r * 2048 + d] = hh;
        h2HL[(long)r * 2048 + 1024 + d] = ll;
    }
}

// ---- silu(g)*u -> interleaved hi|lo rows of 4096 ----
__global__ void k_silu_mul(const float* __restrict__ gact, const float* __restrict__ uact,
                           unsigned short* __restrict__ ghl, int n) {
    int i = blockIdx.x * blockDim.x + threadIdx.x;
    if (i < n) {
        float x = gact[i];
        unsigned short hh, ll;
        cvt_hilo(x * sigmf(x) * uact[i], hh, ll);
        int r = i >> 12, c = i & 4095;
        ghl[(long)r * 8192 + c] = hh;
        ghl[(long)r * 8192 + 4096 + c] = ll;
    }
}

// ---- xp[b, sel[b,j], :] += g * (ao + ff). block per (b,j) ----
__global__ void k_scatter(float* __restrict__ xp, const float* __restrict__ ao,
                          const float* __restrict__ ff, const float* __restrict__ g,
                          const int* __restrict__ sel) {
    int r = blockIdx.x;
    int b = r / KCn;
    int p = sel[r];
    float gg = g[r];
    float* dst = xp + ((long)b * Pn + p) * Dn;
    #pragma unroll
    for (int j = 0; j < 4; j++) {
        int d = threadIdx.x + j * 256;
        dst[d] += gg * (ao[(long)r * Dn + d] + ff[(long)r * Dn + d]);
    }
}

// ---- win = sigmoid(gelu(hmlp) @ w2 + b2) ----
__global__ void k_win(const float* __restrict__ hmlp, const float* __restrict__ w2,
                      const float* __restrict__ b2, float* __restrict__ win) {
    int tid = blockIdx.x * blockDim.x + threadIdx.x;
    if (tid >= Bn * Pn * Sn) return;
    int s = tid & 3; int r = tid >> 2;
    float acc = b2[s];
    const float* hr = hmlp + (long)r * 256;
    for (int i = 0; i < 256; i++) acc += geluf(hr[i]) * w2[i * 4 + s];
    win[tid] = sigmf(acc);
}

// ---- y = rmsnorm(proj*win, dec_norm_w) emitted interleaved hi|lo ----
__global__ void k_dec_norm(const float* __restrict__ proj, const float* __restrict__ win,
                           const float* __restrict__ w, unsigned short* __restrict__ yHL) {
    int r = blockIdx.x;
    float wv = win[r];
    __shared__ float red[4];
    float v[4]; float ss = 0.f;
    #pragma unroll
    for (int j = 0; j < 4; j++) {
        int d = threadIdx.x + j * 256;
        float x = proj[(long)r * Dn + d] * wv;
        v[j] = x; ss += x * x;
    }
    ss = blk_sum256(ss, red);
    float sc = 1.f / sqrtf(ss * (1.f / Dn) + 1e-6f);
    #pragma unroll
    for (int j = 0; j < 4; j++) {
        int d = threadIdx.x + j * 256;
        unsigned short hh, ll;
        cvt_hilo(v[j] * sc * w[d], hh, ll);
        yHL[(long)r * 2048 + d] = hh;
        yHL[(long)r * 2048 + 1024 + d] = ll;
    }
}

extern "C" void kernel_launch(void* const* d_in, const int* in_sizes, int n_in,
                              void* d_out, int out_size, void* d_ws, size_t ws_size,
                              hipStream_t stream) {
    const int*   tokens     = (const int*)  d_in[0];
    const float* emb        = (const float*)d_in[1];
    const float* bp_w1      = (const float*)d_in[2];
    const float* bp_b1      = (const float*)d_in[3];
    const float* bp_w2      = (const float*)d_in[4];
    const float* bp_b2      = (const float*)d_in[5];
    const float* enc_norm_w = (const float*)d_in[6];
    const float* router_w   = (const float*)d_in[7];
    const float* ln1_w      = (const float*)d_in[8];
    const float* ln2_w      = (const float*)d_in[9];
    const float* q_w        = (const float*)d_in[10];
    const float* k_w        = (const float*)d_in[11];
    const float* v_w        = (const float*)d_in[12];
    const float* o_w        = (const float*)d_in[13];
    const float* gate_w     = (const float*)d_in[14];
    const float* up_w       = (const float*)d_in[15];
    const float* down_w     = (const float*)d_in[16];
    const float* dec_proj_w = (const float*)d_in[17];
    const float* dec_proj_b = (const float*)d_in[18];
    const float* dec_mlp_w1 = (const float*)d_in[19];
    const float* dec_mlp_b1 = (const float*)d_in[20];
    const float* dec_mlp_w2 = (const float*)d_in[21];
    const float* dec_mlp_b2 = (const float*)d_in[22];
    const float* dec_norm_w = (const float*)d_in[23];
    const float* head_w     = (const float*)d_in[24];
    float* out = (float*)d_out;

    float* W = (float*)d_ws;
    float* EW   = W + OFF_EW;
    float* cA   = W + OFF_CA;
    float* cB   = W + OFF_CB;
    float* cC   = W + OFF_CC;
    float* ent  = W + OFF_ENT;
    int*   idxb = (int*)(W + OFF_IDX);
    float* xp   = W + OFF_XP;
    float* rl   = W + OFF_RL;
    int*   sel  = (int*)(W + OFF_SEL);
    float* g    = W + OFF_G;
    float* scr  = W + SCR;
    float* xs   = scr + SC_XS;
    unsigned short* hHL   = (unsigned short*)(scr + SC_H);
    float* qb   = scr + SC_Q;
    float* kb   = scr + SC_K;
    float* vb   = scr + SC_V;
    unsigned short* aoutHL = (unsigned short*)(scr + SC_AOUT);
    float* ao   = scr + SC_AO;
    unsigned short* h2HL  = (unsigned short*)(scr + SC_H2);
    float* gact = scr + SC_GACT;
    float* uact = scr + SC_UACT;
    float* ffb  = scr + SC_FF;
    float* proj = scr + SC_PROJ;
    float* hmlp = scr + SC_HMLP;
    float* win  = scr + SC_WIN;
    unsigned short* yHL   = (unsigned short*)(scr + SC_Y);
    unsigned short* EA    = (unsigned short*)(scr + SC_EA);   // encoder only
    unsigned short* WB    = (unsigned short*)(scr + SC_WB);   // encoder only
    unsigned short* WHL   = (unsigned short*)(W + OFF_WT);
    float* parts = W + OFF_PARTS;
    unsigned short* ghHL  = (unsigned short*)(W + OFF_GHL);   // layer: silu-out hl
    unsigned short* xpHL  = (unsigned short*)(W + OFF_GHL);   // decoder: xp hl

    // byte-patch encoder: EW via MFMA hi/lo GEMM (M=384 pad, N=1536, K=1024)
    k_emb_pad<<<1536, 256, 0, stream>>>(emb, EA);
    k_wconv_w1<<<6144, 256, 0, stream>>>(bp_w1, WB);
    k_mfma3<<<dim3(12, 3, 4), 256, 0, stream>>>(EA, WB, nullptr, nullptr, 384, 1536, 1024, 4, parts);
    k_ewred<<<1542, 256, 0, stream>>>(parts, EW);
    k_conv1<<<Bn * Tn / 4, 256, 0, stream>>>(tokens, EW, bp_b1, bp_w2, cA, cB, cC);
    k_patchstats<<<(Bn * Pn + 255) / 256, 256, 0, stream>>>(cA, cB, cC, bp_b2, ent, idxb);
    k_xp<<<Bn * Pn, 256, 0, stream>>>(tokens, idxb, emb, enc_norm_w, xp);

    for (int l = 0; l < Ln; l++) {
        k_router<<<Bn * Pn, 256, 0, stream>>>(xp, router_w + (long)l * Dn, ent, rl);
        k_topk<<<Bn, Pn, 0, stream>>>(rl, sel, g);
        k_gather_ln1<<<Bn * KCn, 256, 0, stream>>>(xp, sel, ln1_w + (long)l * Dn, xs, hHL);

        k_wconv<<<dim3(32, 32), 256, 0, stream>>>(q_w + (long)l * Dn * Dn, WHL, 1024, 1024);
        k_mfma3<<<dim3(8, 8, 4), 256, 0, stream>>>(hHL, WHL, nullptr, nullptr, 1024, 1024, 1024, 4, parts);
        k_reduce<<<4096, 256, 0, stream>>>(parts, qb, nullptr, 1048576, 4, 1024);

        k_wconv<<<dim3(8, 32), 256, 0, stream>>>(k_w + (long)l * Dn * 256, WHL, 1024, 256);
        k_mfma3<<<dim3(2, 8, 8), 256, 0, stream>>>(hHL, WHL, nullptr, nullptr, 1024, 256, 1024, 8, parts);
        k_reduce<<<1024, 256, 0, stream>>>(parts, kb, nullptr, 262144, 8, 256);

        k_wconv<<<dim3(8, 32), 256, 0, stream>>>(v_w + (long)l * Dn * 256, WHL, 1024, 256);
        k_mfma3<<<dim3(2, 8, 8), 256, 0, stream>>>(hHL, WHL, nullptr, nullptr, 1024, 256, 1024, 8, parts);
        k_reduce<<<1024, 256, 0, stream>>>(parts, vb, nullptr, 262144, 8, 256);

        k_rope<<<(Bn * KCn * NHn * 32 + 255) / 256, 256, 0, stream>>>(qb, sel, NHn);
        k_rope<<<(Bn * KCn * NKVn * 32 + 255) / 256, 256, 0, stream>>>(kb, sel, NKVn);
        k_attn<<<dim3(4, NHn, Bn), 256, 0, stream>>>(qb, kb, vb, aoutHL);

        k_wconv<<<dim3(32, 32), 256, 0, stream>>>(o_w + (long)l * Dn * Dn, WHL, 1024, 1024);
        k_mfma3<<<dim3(8, 8, 4), 256, 0, stream>>>(aoutHL, WHL, nullptr, nullptr, 1024, 1024, 1024, 4, parts);
        k_reduce<<<4096, 256, 0, stream>>>(parts, ao, nullptr, 1048576, 4, 1024);

        k_add_ln2<<<Bn * KCn, 256, 0, stream>>>(xs, ao, ln2_w + (long)l * Dn, h2HL);

        k_wconv<<<dim3(128, 32), 256, 0, stream>>>(gate_w + (long)l * Dn * FFn, WHL, 1024, 4096);
        k_mfma3<<<dim3(32, 8, 1), 256, 0, stream>>>(h2HL, WHL, gact, nullptr, 1024, 4096, 1024, 1, parts);
        k_wconv<<<dim3(128, 32), 256, 0, stream>>>(up_w + (long)l * Dn * FFn, WHL, 1024, 4096);
        k_mfma3<<<dim3(32, 8, 1), 256, 0, stream>>>(h2HL, WHL, uact, nullptr, 1024, 4096, 1024, 1, parts);

        k_silu_mul<<<(Bn * KCn * FFn + 255) / 256, 256, 0, stream>>>(gact, uact, ghHL, Bn * KCn * FFn);

        k_wconv<<<dim3(32, 128), 256, 0, stream>>>(down_w + (long)l * FFn * Dn, WHL, 4096, 1024);
        k_mfma3<<<dim3(8, 8, 4), 256, 0, stream>>>(ghHL, WHL, nullptr, nullptr, 1024, 1024, 4096, 4, parts);
        k_reduce<<<4096, 256, 0, stream>>>(parts, ffb, nullptr, 1048576, 4, 1024);

        k_scatter<<<Bn * KCn, 256, 0, stream>>>(xp, ao, ffb, g, sel);
    }

    // decoder
    k_xcvt<<<8192, 256, 0, stream>>>(xp, xpHL, 2097152);
    k_wconv<<<dim3(128, 32), 256, 0, stream>>>(dec_proj_w, WHL, 1024, 4096);
    k_mfma3<<<dim3(32, 16, 1), 256, 0, stream>>>(xpHL, WHL, proj, dec_proj_b, 2048, 4096, 1024, 1, parts);
    k_wconv<<<dim3(8, 32), 256, 0, stream>>>(dec_mlp_w1, WHL, 1024, 256);
    k_mfma3<<<dim3(2, 16, 4), 256, 0, stream>>>(xpHL, WHL, nullptr, nullptr, 2048, 256, 1024, 4, parts);
    k_reduce<<<2048, 256, 0, stream>>>(parts, hmlp, dec_mlp_b1, 524288, 4, 256);
    k_win<<<(Bn * Pn * Sn + 255) / 256, 256, 0, stream>>>(hmlp, dec_mlp_w2, dec_mlp_b2, win);
    k_dec_norm<<<Bn * Pn * Sn, 256, 0, stream>>>(proj, win, dec_norm_w, yHL);
    k_wconv<<<dim3(9, 32), 256, 0, stream>>>(head_w, WHL, 1024, 257);
    k_mfma3<<<dim3(3, 64, 2), 256, 0, stream>>>(yHL, WHL, nullptr, nullptr, 8192, 257, 1024, 2, parts);
    k_reduce<<<8224, 256, 0, stream>>>(parts, out, nullptr, 2105344, 2, 257);
}

// Round 3
// 1606.590 us; speedup vs baseline: 1.1170x; 1.1155x over previous
//
#include <hip/hip_runtime.h>
#include <hip/hip_bf16.h>
#include <math.h>

// ---- model dims ----
constexpr int Bn  = 4;
constexpr int Tn  = 8192;
constexpr int Dn  = 1024;
constexpr int Pn  = 512;
constexpr int SEGn= 16;     // T/P
constexpr int Sn  = 4;
constexpr int Ln  = 4;
constexpr int NHn = 16;
constexpr int NKVn= 4;
constexpr int HDn = 64;
constexpr int FFn = 4096;
constexpr int KCn = 256;
constexpr int Vn  = 257;
constexpr int DHn = 512;    // conv hidden (D/2)

// ---- workspace layout (float elements). total = 33,015,296 floats = 126 MB ----
constexpr long OFF_EW  = 0;                       // 3*257*512 = 394752
constexpr long OFF_CA  = 394752;                  // B*T
constexpr long OFF_CB  = 427520;
constexpr long OFF_CC  = 460288;
constexpr long OFF_ENT = 493056;                  // B*P
constexpr long OFF_IDX = 495104;                  // B*P (int)
constexpr long OFF_XP  = 497152;                  // B*P*D = 2097152
constexpr long OFF_RL  = 2594304;                 // B*P
constexpr long OFF_SEL = 2596352;                 // B*KC (int)
constexpr long OFF_G   = 2597376;                 // B*KC
constexpr long SCR     = 2598400;
// layer-phase scratch (offsets relative to SCR):
constexpr long SC_XS   = 0;         // 1048576
constexpr long SC_H    = 1048576;   // 1048576 (interleaved hi|lo ushort rows)
constexpr long SC_Q    = 2097152;   // 1048576
constexpr long SC_KV   = 3145728;   // 524288  (fused K|V, row stride 512)
constexpr long SC_AOUT = 3670016;   // 1048576 (hi|lo)
constexpr long SC_AO   = 4718592;   // 1048576
constexpr long SC_H2   = 5767168;   // 1048576 (hi|lo)
constexpr long SC_GU   = 6815744;   // 8388608 (fused gate|up C, row stride 8192)
constexpr long SC_FF   = 15204352;  // 1048576
// decoder-phase (overlays layer region):
constexpr long SC_PROJ = 0;         // 8388608
constexpr long SC_HMLP = 8388608;   // 524288
constexpr long SC_WIN  = 8912896;   // 8192
constexpr long SC_Y    = 8921088;   // 8388608 (hi|lo: 8192 rows x 2048 ushort)
// encoder-phase temporaries (overlay scr, used before layer loop):
constexpr long SC_EA   = 0;         // 384*2048 ushort = 393216 floats
constexpr long SC_WB   = 524288;    // 1536*2048 ushort = 1572864 floats
// new regions (absolute float offsets in ws):
constexpr long OFF_WT    = 19908096;  // 4M floats = 8M ushort: WHL [N][2K] interleaved
constexpr long OFF_PARTS = 24102400;  // 4718592 floats; ALSO rows 4096.. of fused
                                      // gate|up B-panel (parts dead at that point)
constexpr long OFF_GHL   = 28820992;  // 4M floats: silu-out hl (layer) / xp hl (dec)
// total 33015296

typedef __attribute__((ext_vector_type(8))) short short8;
typedef __attribute__((ext_vector_type(4))) float floatx4;

// ---- helpers ----
__device__ __forceinline__ float geluf(float x) {
    // tanh-gelu via fast exp: tanh(u) = 1 - 2/(e^{2u}+1) (branchless, inf-safe)
    float u = 0.7978845608028654f * (x + 0.044715f * x * x * x);
    float e = __expf(2.f * u);
    float t = 1.f - 2.f / (e + 1.f);
    return 0.5f * x * (1.f + t);
}
__device__ __forceinline__ float sigmf(float x) { return 1.f / (1.f + expf(-x)); }

// fp32 -> bf16 hi/lo split (truncation; x ~= hi + lo, err ~2^-17 rel)
__device__ __forceinline__ void cvt_hilo(float x, unsigned short& h, unsigned short& l) {
    unsigned u = __float_as_uint(x);
    h = (unsigned short)(u >> 16);
    float r = x - __uint_as_float(u & 0xffff0000u);
    l = (unsigned short)(__float_as_uint(r) >> 16);
}

// async global->LDS, 16B per lane (dest = wave-uniform base + lane*16)
typedef const __attribute__((address_space(1))) unsigned int* gas_p;
typedef __attribute__((address_space(3))) unsigned int* las_p;
__device__ __forceinline__ void gload16(const unsigned short* g, unsigned short* l) {
    __builtin_amdgcn_global_load_lds((gas_p)g, (las_p)l, 16, 0, 0);
}

// block (256 threads) sum reduce; red must be __shared__ float[4]
__device__ __forceinline__ float blk_sum256(float v, float* red) {
    for (int o = 32; o > 0; o >>= 1) v += __shfl_down(v, o);
    int lane = threadIdx.x & 63, w = threadIdx.x >> 6;
    if (lane == 0) red[w] = v;
    __syncthreads();
    float r = red[0] + red[1] + red[2] + red[3];
    __syncthreads();
    return r;
}

// ---- encoder A-operand: emb padded to 384 rows, interleaved hi|lo ----
__global__ void k_emb_pad(const float* __restrict__ emb, unsigned short* __restrict__ EA) {
    int i = blockIdx.x * blockDim.x + threadIdx.x;
    if (i >= 384 * 1024) return;
    int r = i >> 10, d = i & 1023;
    float v = (r < Vn) ? emb[r * 1024 + d] : 0.f;
    unsigned short hh, ll;
    cvt_hilo(v, hh, ll);
    EA[(long)r * 2048 + d] = hh;
    EA[(long)r * 2048 + 1024 + d] = ll;
}

// ---- encoder B-operand: WB[n=o*3+dk][k] = w1[o][k][dk], interleaved hi|lo ----
__global__ void k_wconv_w1(const float* __restrict__ w1, unsigned short* __restrict__ WB) {
    int i = blockIdx.x * blockDim.x + threadIdx.x;
    if (i >= 1536 * 1024) return;
    int n = i >> 10, k = i & 1023;
    float v = w1[(n / 3) * 3072 + k * 3 + (n % 3)];
    unsigned short hh, ll;
    cvt_hilo(v, hh, ll);
    WB[(long)n * 2048 + k] = hh;
    WB[(long)n * 2048 + 1024 + k] = ll;
}

// ---- reduce EW splitK partials and remap [v][o*3+dk] -> [dk][v][o] ----
__global__ void k_ewred(const float* __restrict__ parts, float* __restrict__ EW) {
    int i = blockIdx.x * blockDim.x + threadIdx.x;
    if (i >= 3 * Vn * DHn) return;
    int dk = i / (Vn * DHn);
    int rem = i - dk * (Vn * DHn);
    int v = rem >> 9, o = rem & 511;
    long src = (long)v * 1536 + o * 3 + dk;
    float s = 0.f;
    constexpr long MN = 384L * 1536;
    #pragma unroll
    for (int c = 0; c < 4; c++) s += parts[c * MN + src];
    EW[i] = s;
}

// ---- K1: per (b,t): h1 column via EW lookups + gelu, reduce to 3 dots with w2 ----
__global__ void k_conv1(const int* __restrict__ tok, const float* __restrict__ EW,
                        const float* __restrict__ b1, const float* __restrict__ w2,
                        float* __restrict__ cA, float* __restrict__ cB, float* __restrict__ cC) {
    int wave = threadIdx.x >> 6, lane = threadIdx.x & 63;
    int gidx = blockIdx.x * 4 + wave;     // b*T + t
    int b = gidx / Tn, t = gidx - b * Tn;
    int tk  = tok[b * Tn + t];
    int tkm = (t > 0)      ? tok[b * Tn + t - 1] : -1;
    int tkp = (t < Tn - 1) ? tok[b * Tn + t + 1] : -1;
    const float* E0 = EW;
    const float* E1 = EW + (long)Vn * DHn;
    const float* E2 = EW + 2L * Vn * DHn;
    float a0 = 0.f, a1 = 0.f, a2 = 0.f;
    #pragma unroll
    for (int u = 0; u < DHn / 64; u++) {
        int o = lane + u * 64;
        float s = b1[o] + E1[tk * DHn + o];
        if (tkm >= 0) s += E0[tkm * DHn + o];
        if (tkp >= 0) s += E2[tkp * DHn + o];
        float hg = geluf(s);
        a0 += hg * w2[o * 3 + 0];
        a1 += hg * w2[o * 3 + 1];
        a2 += hg * w2[o * 3 + 2];
    }
    for (int o = 32; o > 0; o >>= 1) {
        a0 += __shfl_down(a0, o); a1 += __shfl_down(a1, o); a2 += __shfl_down(a2, o);
    }
    if (lane == 0) { cA[gidx] = a0; cB[gidx] = a1; cC[gidx] = a2; }
}

// ---- K2: lg per token -> per-patch softmax -> ent, idx ----
__global__ void k_patchstats(const float* __restrict__ cA, const float* __restrict__ cB,
                             const float* __restrict__ cC, const float* __restrict__ b2,
                             float* __restrict__ ent_out, int* __restrict__ idx_out) {
    int pid = blockIdx.x * blockDim.x + threadIdx.x;   // b*P + p
    if (pid >= Bn * Pn) return;
    int b = pid / Pn, p = pid - b * Pn;
    float lgv[SEGn];
    float m = -3.4e38f;
    for (int s = 0; s < SEGn; s++) {
        int t = p * SEGn + s;
        float v = b2[0] + cB[b * Tn + t];
        if (t > 0)      v += cA[b * Tn + t - 1];
        if (t < Tn - 1) v += cC[b * Tn + t + 1];
        lgv[s] = v; m = fmaxf(m, v);
    }
    float Z = 0.f;
    for (int s = 0; s < SEGn; s++) { lgv[s] = expf(lgv[s] - m); Z += lgv[s]; }
    float inv = 1.f / Z;
    float bp = 0.f, en = 0.f;
    for (int s = 0; s < SEGn; s++) {
        float w = lgv[s] * inv;
        bp += w * (float)(p * SEGn + s);
        en -= w * logf(fmaxf(w, 1e-8f));
    }
    en *= (1.f / 2.772588722239781f);   // / ln(16)
    ent_out[pid] = en;
    int ix = (int)bp;
    ix = ix < 0 ? 0 : (ix > Tn - 1 ? Tn - 1 : ix);
    idx_out[pid] = ix;
}

// ---- K3: xp[b,p,:] = rmsnorm(emb[tok[b, idx[b,p]]], enc_norm_w). block per row ----
__global__ void k_xp(const int* __restrict__ tok, const int* __restrict__ idx,
                     const float* __restrict__ emb, const float* __restrict__ nw,
                     float* __restrict__ xp) {
    int pid = blockIdx.x;
    int b = pid / Pn;
    int tk = tok[b * Tn + idx[pid]];
    const float* row = emb + (long)tk * Dn;
    __shared__ float red[4];
    float v[4]; float ss = 0.f;
    #pragma unroll
    for (int j = 0; j < 4; j++) { v[j] = row[threadIdx.x + j * 256]; ss += v[j] * v[j]; }
    ss = blk_sum256(ss, red);
    float sc = 1.f / sqrtf(ss * (1.f / Dn) + 1e-6f);
    #pragma unroll
    for (int j = 0; j < 4; j++) {
        int d = threadIdx.x + j * 256;
        xp[(long)pid * Dn + d] = v[j] * sc * nw[d];
    }
}

// ---- K4: rl[b,p] = xp[b,p,:]·rw + ent. block per row ----
__global__ void k_router(const float* __restrict__ xp, const float* __restrict__ rw,
                         const float* __restrict__ ent, float* __restrict__ rl) {
    int pid = blockIdx.x;
    const float* xr = xp + (long)pid * Dn;
    __shared__ float red[4];
    float s = 0.f;
    #pragma unroll
    for (int j = 0; j < 4; j++) { int d = threadIdx.x + j * 256; s += xr[d] * rw[d]; }
    s = blk_sum256(s, red);
    if (threadIdx.x == 0) rl[pid] = s + ent[pid];
}

// ---- K5: exact top-k (KC of P) with jax tie semantics, output ascending by index ----
__global__ void k_topk(const float* __restrict__ rl, int* __restrict__ sel, float* __restrict__ g) {
    int b = blockIdx.x, p = threadIdx.x;
    __shared__ float vals[Pn];
    __shared__ int flag[Pn];
    float v = rl[b * Pn + p];
    vals[p] = v;
    __syncthreads();
    int rank = 0;
    for (int q = 0; q < Pn; q++) {
        float vq = vals[q];
        rank += (vq > v || (vq == v && q < p)) ? 1 : 0;
    }
    int selected = rank < KCn ? 1 : 0;
    flag[p] = selected;
    __syncthreads();
    if (selected) {
        int pos = 0;
        for (int q = 0; q < p; q++) pos += flag[q];
        sel[b * KCn + pos] = p;
        g[b * KCn + pos] = sigmf(v);
    }
}

// ---- K6: gather xs = xp[b, sel]; h = rmsnorm(xs, ln1) emitted interleaved hi|lo ----
__global__ void k_gather_ln1(const float* __restrict__ xp, const int* __restrict__ sel,
                             const float* __restrict__ w, float* __restrict__ xs,
                             unsigned short* __restrict__ hHL) {
    int r = blockIdx.x;            // b*KC + j
    int b = r / KCn;
    int p = sel[r];
    const float* src = xp + ((long)b * Pn + p) * Dn;
    __shared__ float red[4];
    float v[4]; float ss = 0.f;
    #pragma unroll
    for (int j = 0; j < 4; j++) { v[j] = src[threadIdx.x + j * 256]; ss += v[j] * v[j]; }
    ss = blk_sum256(ss, red);
    float sc = 1.f / sqrtf(ss * (1.f / Dn) + 1e-6f);
    #pragma unroll
    for (int j = 0; j < 4; j++) {
        int d = threadIdx.x + j * 256;
        xs[(long)r * Dn + d] = v[j];
        unsigned short hh, ll;
        cvt_hilo(v[j] * sc * w[d], hh, ll);
        hHL[(long)r * 2048 + d] = hh;
        hHL[(long)r * 2048 + 1024 + d] = ll;
    }
}

// ---- weight convert+transpose: W[K][N] fp32 -> WHL[n][2K] interleaved hi|lo ----
// grid (ceil(N/32), K/32), block 256 (=32x8)
__global__ void k_wconv(const float* __restrict__ Wm, unsigned short* __restrict__ Whl,
                        int K, int N) {
    __shared__ float t[32][33];
    int n0 = blockIdx.x * 32, k0 = blockIdx.y * 32;
    int tx = threadIdx.x & 31, ty = threadIdx.x >> 5;
    #pragma unroll
    for (int r = 0; r < 4; r++) {
        int k = k0 + ty + 8 * r, n = n0 + tx;
        t[ty + 8 * r][tx] = (n < N) ? Wm[(long)k * N + n] : 0.f;
    }
    __syncthreads();
    long K2 = 2L * K;
    #pragma unroll
    for (int r = 0; r < 4; r++) {
        int n = n0 + ty + 8 * r, k = k0 + tx;
        float v = t[tx][ty + 8 * r];
        unsigned short hh, ll;
        cvt_hilo(v, hh, ll);
        Whl[(long)n * K2 + k] = hh;
        Whl[(long)n * K2 + K + k] = ll;
    }
}

// ---- elementwise fp32 -> interleaved hi|lo rows of 1024 ----
__global__ void k_xcvt(const float* __restrict__ src, unsigned short* __restrict__ dhl, int n) {
    int i = blockIdx.x * blockDim.x + threadIdx.x;
    if (i >= n) return;
    int r = i >> 10, d = i & 1023;
    unsigned short hh, ll;
    cvt_hilo(src[i], hh, ll);
    dhl[(long)r * 2048 + d] = hh;
    dhl[(long)r * 2048 + 1024 + d] = ll;
}

// ---- MFMA GEMM on interleaved hi|lo operands. A[M][2K], B[N][2K] ushort rows.
//      2-phase pipeline (T3 minimum form): double-buffered LDS; stage tile ks+1
//      via global_load_lds BEFORE computing tile ks; single __syncthreads per
//      K-step (its implicit vmcnt(0)+barrier drains AFTER the MFMA cluster, so
//      load flight overlaps compute). XOR chunk swizzle on source+read (rule #21).
// grid (ceil(N/128), M/128, splitK), block 256. splitK>1 -> parts; else C(+bias).
// M%128==0, (K/splitK)%32==0.
__global__ __launch_bounds__(256, 2) void k_mfma3(
        const unsigned short* __restrict__ Ag, const unsigned short* __restrict__ Bg,
        float* __restrict__ Cmat, const float* __restrict__ bias,
        int M, int N, int K, int splitK, float* __restrict__ parts) {
    __shared__ alignas(16) unsigned short As[2][128 * 64], Bs[2][128 * 64];
    int tid = threadIdx.x;
    int m0 = blockIdx.y * 128, n0 = blockIdx.x * 128;
    int kc = blockIdx.z;
    int Kc = K / splitK, kbase = kc * Kc, KT = Kc >> 5;
    int lane = tid & 63, wid = tid >> 6;
    int wm = (wid & 1) * 64, wn = (wid >> 1) * 64;
    int quad = lane >> 4, l16 = lane & 15;

    // staging geometry: 16 segments of 1KB per tile (4 per wave); lane L covers
    // row seg*8 + (L>>3), LDS slot L&7, which must hold logical chunk (L&7)^(row&7).
    int srow8 = lane >> 3;
    int spos  = lane & 7;
    int cch   = spos ^ srow8;                       // row&7 == srow8 for every segment
    long K2 = 2L * K;
    long coff = (cch < 4) ? (long)(cch * 8) : (long)K + (long)((cch - 4) * 8);
    const unsigned short* Aseg = Ag + (long)(m0 + srow8) * K2 + coff;
    const unsigned short* Bseg = Bg + (long)(n0 + srow8) * K2 + coff;   // OOB rows (pad) read garbage, never stored

    floatx4 acc[4][4];
    #pragma unroll
    for (int i = 0; i < 4; i++)
        #pragma unroll
        for (int j = 0; j < 4; j++) acc[i][j] = (floatx4){0.f, 0.f, 0.f, 0.f};

    auto stagef = [&](unsigned short* Ad, unsigned short* Bd, long kb) {
        #pragma unroll
        for (int t = 0; t < 4; t++) {
            int sa = wid * 4 + t;
            gload16(Aseg + (long)sa * 8 * K2 + kb, Ad + sa * 512);
            gload16(Bseg + (long)sa * 8 * K2 + kb, Bd + sa * 512);
        }
    };

    int ph = quad ^ (l16 & 7);                      // hi-chunk slot; lo = ph^4
    stagef(As[0], Bs[0], kbase);
    __syncthreads();                                // tile 0 resident
    int cur = 0;
    for (int ks = 0; ks < KT; ks++) {
        if (ks + 1 < KT)                            // prefetch next tile into other buf
            stagef(As[cur ^ 1], Bs[cur ^ 1], kbase + (long)(ks + 1) * 32);

        const unsigned short* Ac = As[cur];
        const unsigned short* Bc = Bs[cur];
        short8 ah[4], al2[4], bh[4], bl2[4];
        #pragma unroll
        for (int i = 0; i < 4; i++) {
            int r = wm + i * 16 + l16;
            ah[i]  = *(const short8*)&Ac[r * 64 + ph * 8];
            al2[i] = *(const short8*)&Ac[r * 64 + (ph ^ 4) * 8];
        }
        #pragma unroll
        for (int j = 0; j < 4; j++) {
            int c = wn + j * 16 + l16;
            bh[j]  = *(const short8*)&Bc[c * 64 + ph * 8];
            bl2[j] = *(const short8*)&Bc[c * 64 + (ph ^ 4) * 8];
        }
        #pragma unroll
        for (int i = 0; i < 4; i++)
            #pragma unroll
            for (int j = 0; j < 4; j++) {
                acc[i][j] = __builtin_amdgcn_mfma_f32_16x16x32_bf16(ah[i],  bh[j],  acc[i][j], 0, 0, 0);
                acc[i][j] = __builtin_amdgcn_mfma_f32_16x16x32_bf16(ah[i],  bl2[j], acc[i][j], 0, 0, 0);
                acc[i][j] = __builtin_amdgcn_mfma_f32_16x16x32_bf16(al2[i], bh[j],  acc[i][j], 0, 0, 0);
            }
        __syncthreads();   // drains this iter's prefetch (vmcnt0) + WAR protection
        cur ^= 1;
    }

    // epilogue: C/D layout col=lane&15, row=quad*4+reg (m89/m91)
    long MN = (long)M * N;
    #pragma unroll
    for (int j = 0; j < 4; j++) {
        int n = n0 + wn + j * 16 + l16;
        if (n >= N) continue;
        float bvx = bias ? bias[n] : 0.f;
        #pragma unroll
        for (int i = 0; i < 4; i++) {
            int mb = m0 + wm + i * 16 + quad * 4;
            #pragma unroll
            for (int r = 0; r < 4; r++) {
                if (splitK > 1) parts[kc * MN + (long)(mb + r) * N + n] = acc[i][j][r];
                else            Cmat[(long)(mb + r) * N + n] = acc[i][j][r] + bvx;
            }
        }
    }
}

// ---- reduce splitK partials (+optional bias) ----
__global__ void k_reduce(const float* __restrict__ parts, float* __restrict__ out,
                         const float* __restrict__ bias, long MN, int sk, int N) {
    long i = (long)blockIdx.x * blockDim.x + threadIdx.x;
    if (i >= MN) return;
    float s = 0.f;
    for (int c = 0; c < sk; c++) s += parts[c * MN + i];
    if (bias) s += bias[(int)(i % N)];
    out[i] = s;
}

// ---- RoPE in-place on (B*KC, rows of `stride`), heads 0..nh-1, pos = sel[row] ----
__global__ void k_rope(float* __restrict__ buf, const int* __restrict__ sel, int nh, int stride) {
    int tid = blockIdx.x * blockDim.x + threadIdx.x;
    int total = Bn * KCn * nh * 32;
    if (tid >= total) return;
    int d = tid & 31;
    int h = (tid >> 5) % nh;
    int r = tid / (32 * nh);
    int pos = sel[r];
    float theta = powf(10000.f, -(float)(2 * d) / 64.f);
    float ang = (float)pos * theta;
    float c = cosf(ang), s = sinf(ang);
    long base = (long)r * stride + h * 64 + d;
    float x1 = buf[base], x2 = buf[base + 32];
    buf[base]      = x1 * c - x2 * s;
    buf[base + 32] = x2 * c + x1 * s;
}

// ---- MFMA flash attention; K/V fused in kv (row stride 512: k cols 0..255,
//      v cols 256..511); epilogue emits aout interleaved hi|lo ----
constexpr int APS = 72;
__global__ __launch_bounds__(256) void k_attn(const float* __restrict__ q, const float* __restrict__ kv,
                       unsigned short* __restrict__ aoHL) {
    int bx = blockIdx.x, h = blockIdx.y, b = blockIdx.z;
    int hk = h >> 2;
    int qb0 = bx * 64;
    int tid = threadIdx.x, lane = tid & 63, wid = tid >> 6;
    int quad = lane >> 4, l16 = lane & 15;
    __shared__ alignas(16) unsigned short LdsA[9216], LdsB[9216];
    unsigned short* Kh = LdsA;          unsigned short* Kl = LdsB;
    unsigned short* Ph = LdsA;          unsigned short* Pl = LdsB;
    unsigned short* Vth = LdsA + 4608;  unsigned short* Vtl = LdsB + 4608;

    int qrow = qb0 + wid * 16 + l16;
    short8 qh[2], ql[2];
    #pragma unroll
    for (int ks = 0; ks < 2; ks++) {
        const float* qp = q + ((long)(b * KCn + qrow)) * (NHn * HDn) + h * HDn + ks * 32 + quad * 8;
        float tmp[8];
        *(float4*)tmp = *(const float4*)qp;
        *(float4*)(tmp + 4) = *(const float4*)(qp + 4);
        #pragma unroll
        for (int j = 0; j < 8; j++) {
            unsigned short hh, ll;
            cvt_hilo(tmp[j], hh, ll);
            qh[ks][j] = (short)hh; ql[ks][j] = (short)ll;
        }
    }

    floatx4 sacc[16];
    #pragma unroll
    for (int t = 0; t < 16; t++) sacc[t] = (floatx4){0.f, 0.f, 0.f, 0.f};

    int qmax = qb0 + 63;
    int nkc = qmax / 128 + 1;
    for (int kc = 0; kc < nkc; kc++) {
        __syncthreads();
        {
            int r = tid >> 1, dh = (tid & 1) * 32;
            const float* kp = kv + ((long)(b * KCn + kc * 128 + r)) * 512 + hk * HDn + dh;
            #pragma unroll
            for (int f = 0; f < 8; f++) {
                float tmp[4];
                *(float4*)tmp = *(const float4*)(kp + f * 4);
                unsigned short h0, h1, h2, h3, l0, l1, l2, l3;
                cvt_hilo(tmp[0], h0, l0); cvt_hilo(tmp[1], h1, l1);
                cvt_hilo(tmp[2], h2, l2); cvt_hilo(tmp[3], h3, l3);
                *(ushort4*)&Kh[r * APS + dh + f * 4] = make_ushort4(h0, h1, h2, h3);
                *(ushort4*)&Kl[r * APS + dh + f * 4] = make_ushort4(l0, l1, l2, l3);
            }
        }
        __syncthreads();
        #pragma unroll
        for (int tj = 0; tj < 8; tj++) {
            int kr = tj * 16 + l16;
            int gt = kc * 8 + tj;
            #pragma unroll
            for (int ks = 0; ks < 2; ks++) {
                short8 bh0 = *(const short8*)&Kh[kr * APS + ks * 32 + quad * 8];
                short8 bl0 = *(const short8*)&Kl[kr * APS + ks * 32 + quad * 8];
                sacc[gt] = __builtin_amdgcn_mfma_f32_16x16x32_bf16(qh[ks], bh0, sacc[gt], 0, 0, 0);
                sacc[gt] = __builtin_amdgcn_mfma_f32_16x16x32_bf16(qh[ks], bl0, sacc[gt], 0, 0, 0);
                sacc[gt] = __builtin_amdgcn_mfma_f32_16x16x32_bf16(ql[ks], bh0, sacc[gt], 0, 0, 0);
            }
        }
    }

    float rowinv[4];
    #pragma unroll
    for (int r = 0; r < 4; r++) {
        int qg = qb0 + wid * 16 + quad * 4 + r;
        float mm = -3.4e38f;
        #pragma unroll
        for (int t = 0; t < 16; t++) {
            int key = t * 16 + l16;
            float s = (key <= qg) ? sacc[t][r] * 0.125f : -1e30f;
            sacc[t][r] = s;
            mm = fmaxf(mm, s);
        }
        #pragma unroll
        for (int o = 1; o < 16; o <<= 1) mm = fmaxf(mm, __shfl_xor(mm, o));
        float zz = 0.f;
        #pragma unroll
        for (int t = 0; t < 16; t++) {
            float e = expf(sacc[t][r] - mm);
            sacc[t][r] = e; zz += e;
        }
        #pragma unroll
        for (int o = 1; o < 16; o <<= 1) zz += __shfl_xor(zz, o);
        rowinv[r] = 1.f / zz;
    }

    floatx4 oacc[4];
    #pragma unroll
    for (int dt = 0; dt < 4; dt++) oacc[dt] = (floatx4){0.f, 0.f, 0.f, 0.f};
    int npv = qmax / 64 + 1;
    for (int c4 = 0; c4 < npv; c4++) {
        __syncthreads();
        {
            #pragma unroll
            for (int it = 0; it < 4; it++) {
                int task = tid + 256 * it;
                int kloc = task & 63, d4 = (task >> 6) * 4;
                float tmp[4];
                *(float4*)tmp = *(const float4*)(kv + ((long)(b * KCn + c4 * 64 + kloc)) * 512 + 256 + hk * HDn + d4);
                #pragma unroll
                for (int i = 0; i < 4; i++) {
                    unsigned short hh, ll;
                    cvt_hilo(tmp[i], hh, ll);
                    Vth[(d4 + i) * APS + kloc] = hh;
                    Vtl[(d4 + i) * APS + kloc] = ll;
                }
            }
        }
        #pragma unroll
        for (int tt = 0; tt < 4; tt++) {
            int t = c4 * 4 + tt;
            #pragma unroll
            for (int r = 0; r < 4; r++) {
                int row = wid * 16 + quad * 4 + r;
                float pv2 = sacc[t][r] * rowinv[r];
                unsigned short hh, ll;
                cvt_hilo(pv2, hh, ll);
                Ph[row * APS + tt * 16 + l16] = hh;
                Pl[row * APS + tt * 16 + l16] = ll;
            }
        }
        __syncthreads();
        short8 pah[2], pal[2];
        #pragma unroll
        for (int ks = 0; ks < 2; ks++) {
            pah[ks] = *(const short8*)&Ph[(wid * 16 + l16) * APS + ks * 32 + quad * 8];
            pal[ks] = *(const short8*)&Pl[(wid * 16 + l16) * APS + ks * 32 + quad * 8];
        }
        #pragma unroll
        for (int dt = 0; dt < 4; dt++) {
            #pragma unroll
            for (int ks = 0; ks < 2; ks++) {
                short8 vbh = *(const short8*)&Vth[(dt * 16 + l16) * APS + ks * 32 + quad * 8];
                short8 vbl = *(const short8*)&Vtl[(dt * 16 + l16) * APS + ks * 32 + quad * 8];
                oacc[dt] = __builtin_amdgcn_mfma_f32_16x16x32_bf16(pah[ks], vbh, oacc[dt], 0, 0, 0);
                oacc[dt] = __builtin_amdgcn_mfma_f32_16x16x32_bf16(pah[ks], vbl, oacc[dt], 0, 0, 0);
                oacc[dt] = __builtin_amdgcn_mfma_f32_16x16x32_bf16(pal[ks], vbh, oacc[dt], 0, 0, 0);
            }
        }
    }

    #pragma unroll
    for (int dt = 0; dt < 4; dt++) {
        #pragma unroll
        for (int r = 0; r < 4; r++) {
            int row = qb0 + wid * 16 + quad * 4 + r;
            long base = ((long)(b * KCn + row)) * 2048 + h * HDn + dt * 16 + l16;
            unsigned short hh, ll;
            cvt_hilo(oacc[dt][r], hh, ll);
            aoHL[base] = hh; aoHL[base + 1024] = ll;
        }
    }
}

// ---- x2 = xs + ao; h2 = rmsnorm(x2, ln2) emitted interleaved hi|lo ----
__global__ void k_add_ln2(const float* __restrict__ xs, const float* __restrict__ ao,
                          const float* __restrict__ w, unsigned short* __restrict__ h2HL) {
    int r = blockIdx.x;
    __shared__ float red[4];
    float v[4]; float ss = 0.f;
    #pragma unroll
    for (int j = 0; j < 4; j++) {
        int d = threadIdx.x + j * 256;
        float x = xs[(long)r * Dn + d] + ao[(long)r * Dn + d];
        v[j] = x; ss += x * x;
    }
    ss = blk_sum256(ss, red);
    float sc = 1.f / sqrtf(ss * (1.f / Dn) + 1e-6f);
    #pragma unroll
    for (int j = 0; j < 4; j++) {
        int d = threadIdx.x + j * 256;
        unsigned short hh, ll;
        cvt_hilo(v[j] * sc * w[d], hh, ll);
        h2HL[(long)r * 2048 + d] = hh;
        h2HL[(long)r * 2048 + 1024 + d] = ll;
    }
}

// ---- silu(gate)*up on fused C (row stride 8192: gate 0..4095, up 4096..8191) ----
__global__ void k_silu_mul(const float* __restrict__ C, unsigned short* __restrict__ ghl, int n) {
    int i = blockIdx.x * blockDim.x + threadIdx.x;
    if (i < n) {
        int r = i >> 12, c = i & 4095;
        float x = C[(long)r * 8192 + c];
        float u = C[(long)r * 8192 + 4096 + c];
        unsigned short hh, ll;
        cvt_hilo(x * sigmf(x) * u, hh, ll);
        ghl[(long)r * 8192 + c] = hh;
        ghl[(long)r * 8192 + 4096 + c] = ll;
    }
}

// ---- xp[b, sel[b,j], :] += g * (ao + ff). block per (b,j) ----
__global__ void k_scatter(float* __restrict__ xp, const float* __restrict__ ao,
                          const float* __restrict__ ff, const float* __restrict__ g,
                          const int* __restrict__ sel) {
    int r = blockIdx.x;
    int b = r / KCn;
    int p = sel[r];
    float gg = g[r];
    float* dst = xp + ((long)b * Pn + p) * Dn;
    #pragma unroll
    for (int j = 0; j < 4; j++) {
        int d = threadIdx.x + j * 256;
        dst[d] += gg * (ao[(long)r * Dn + d] + ff[(long)r * Dn + d]);
    }
}

// ---- win = sigmoid(gelu(hmlp) @ w2 + b2) ----
__global__ void k_win(const float* __restrict__ hmlp, const float* __restrict__ w2,
                      const float* __restrict__ b2, float* __restrict__ win) {
    int tid = blockIdx.x * blockDim.x + threadIdx.x;
    if (tid >= Bn * Pn * Sn) return;
    int s = tid & 3; int r = tid >> 2;
    float acc = b2[s];
    const float* hr = hmlp + (long)r * 256;
    for (int i = 0; i < 256; i++) acc += geluf(hr[i]) * w2[i * 4 + s];
    win[tid] = sigmf(acc);
}

// ---- y = rmsnorm(proj*win, dec_norm_w) emitted interleaved hi|lo ----
__global__ void k_dec_norm(const float* __restrict__ proj, const float* __restrict__ win,
                           const float* __restrict__ w, unsigned short* __restrict__ yHL) {
    int r = blockIdx.x;
    float wv = win[r];
    __shared__ float red[4];
    float v[4]; float ss = 0.f;
    #pragma unroll
    for (int j = 0; j < 4; j++) {
        int d = threadIdx.x + j * 256;
        float x = proj[(long)r * Dn + d] * wv;
        v[j] = x; ss += x * x;
    }
    ss = blk_sum256(ss, red);
    float sc = 1.f / sqrtf(ss * (1.f / Dn) + 1e-6f);
    #pragma unroll
    for (int j = 0; j < 4; j++) {
        int d = threadIdx.x + j * 256;
        unsigned short hh, ll;
        cvt_hilo(v[j] * sc * w[d], hh, ll);
        yHL[(long)r * 2048 + d] = hh;
        yHL[(long)r * 2048 + 1024 + d] = ll;
    }
}

extern "C" void kernel_launch(void* const* d_in, const int* in_sizes, int n_in,
                              void* d_out, int out_size, void* d_ws, size_t ws_size,
                              hipStream_t stream) {
    const int*   tokens     = (const int*)  d_in[0];
    const float* emb        = (const float*)d_in[1];
    const float* bp_w1      = (const float*)d_in[2];
    const float* bp_b1      = (const float*)d_in[3];
    const float* bp_w2      = (const float*)d_in[4];
    const float* bp_b2      = (const float*)d_in[5];
    const float* enc_norm_w = (const float*)d_in[6];
    const float* router_w   = (const float*)d_in[7];
    const float* ln1_w      = (const float*)d_in[8];
    const float* ln2_w      = (const float*)d_in[9];
    const float* q_w        = (const float*)d_in[10];
    const float* k_w        = (const float*)d_in[11];
    const float* v_w        = (const float*)d_in[12];
    const float* o_w        = (const float*)d_in[13];
    const float* gate_w     = (const float*)d_in[14];
    const float* up_w       = (const float*)d_in[15];
    const float* down_w     = (const float*)d_in[16];
    const float* dec_proj_w = (const float*)d_in[17];
    const float* dec_proj_b = (const float*)d_in[18];
    const float* dec_mlp_w1 = (const float*)d_in[19];
    const float* dec_mlp_b1 = (const float*)d_in[20];
    const float* dec_mlp_w2 = (const float*)d_in[21];
    const float* dec_mlp_b2 = (const float*)d_in[22];
    const float* dec_norm_w = (const float*)d_in[23];
    const float* head_w     = (const float*)d_in[24];
    float* out = (float*)d_out;

    float* W = (float*)d_ws;
    float* EW   = W + OFF_EW;
    float* cA   = W + OFF_CA;
    float* cB   = W + OFF_CB;
    float* cC   = W + OFF_CC;
    float* ent  = W + OFF_ENT;
    int*   idxb = (int*)(W + OFF_IDX);
    float* xp   = W + OFF_XP;
    float* rl   = W + OFF_RL;
    int*   sel  = (int*)(W + OFF_SEL);
    float* g    = W + OFF_G;
    float* scr  = W + SCR;
    float* xs   = scr + SC_XS;
    unsigned short* hHL   = (unsigned short*)(scr + SC_H);
    float* qb   = scr + SC_Q;
    float* kvb  = scr + SC_KV;
    unsigned short* aoutHL = (unsigned short*)(scr + SC_AOUT);
    float* ao   = scr + SC_AO;
    unsigned short* h2HL  = (unsigned short*)(scr + SC_H2);
    float* gupC = scr + SC_GU;
    float* ffb  = scr + SC_FF;
    float* proj = scr + SC_PROJ;
    float* hmlp = scr + SC_HMLP;
    float* win  = scr + SC_WIN;
    unsigned short* yHL   = (unsigned short*)(scr + SC_Y);
    unsigned short* EA    = (unsigned short*)(scr + SC_EA);   // encoder only
    unsigned short* WB    = (unsigned short*)(scr + SC_WB);   // encoder only
    unsigned short* WHL   = (unsigned short*)(W + OFF_WT);
    float* parts = W + OFF_PARTS;
    unsigned short* ghHL  = (unsigned short*)(W + OFF_GHL);   // layer: silu-out hl
    unsigned short* xpHL  = (unsigned short*)(W + OFF_GHL);   // decoder: xp hl

    // byte-patch encoder: EW via MFMA hi/lo GEMM (M=384 pad, N=1536, K=1024)
    k_emb_pad<<<1536, 256, 0, stream>>>(emb, EA);
    k_wconv_w1<<<6144, 256, 0, stream>>>(bp_w1, WB);
    k_mfma3<<<dim3(12, 3, 4), 256, 0, stream>>>(EA, WB, nullptr, nullptr, 384, 1536, 1024, 4, parts);
    k_ewred<<<1542, 256, 0, stream>>>(parts, EW);
    k_conv1<<<Bn * Tn / 4, 256, 0, stream>>>(tokens, EW, bp_b1, bp_w2, cA, cB, cC);
    k_patchstats<<<(Bn * Pn + 255) / 256, 256, 0, stream>>>(cA, cB, cC, bp_b2, ent, idxb);
    k_xp<<<Bn * Pn, 256, 0, stream>>>(tokens, idxb, emb, enc_norm_w, xp);

    for (int l = 0; l < Ln; l++) {
        k_router<<<Bn * Pn, 256, 0, stream>>>(xp, router_w + (long)l * Dn, ent, rl);
        k_topk<<<Bn, Pn, 0, stream>>>(rl, sel, g);
        k_gather_ln1<<<Bn * KCn, 256, 0, stream>>>(xp, sel, ln1_w + (long)l * Dn, xs, hHL);

        k_wconv<<<dim3(32, 32), 256, 0, stream>>>(q_w + (long)l * Dn * Dn, WHL, 1024, 1024);
        k_mfma3<<<dim3(8, 8, 4), 256, 0, stream>>>(hHL, WHL, nullptr, nullptr, 1024, 1024, 1024, 4, parts);
        k_reduce<<<4096, 256, 0, stream>>>(parts, qb, nullptr, 1048576, 4, 1024);

        // fused K|V GEMM: B rows 0..255 = k_w cols, 256..511 = v_w cols
        k_wconv<<<dim3(8, 32), 256, 0, stream>>>(k_w + (long)l * Dn * 256, WHL, 1024, 256);
        k_wconv<<<dim3(8, 32), 256, 0, stream>>>(v_w + (long)l * Dn * 256, WHL + 256L * 2048, 1024, 256);
        k_mfma3<<<dim3(4, 8, 8), 256, 0, stream>>>(hHL, WHL, nullptr, nullptr, 1024, 512, 1024, 8, parts);
        k_reduce<<<2048, 256, 0, stream>>>(parts, kvb, nullptr, 524288, 8, 512);

        k_rope<<<(Bn * KCn * NHn * 32 + 255) / 256, 256, 0, stream>>>(qb, sel, NHn, 1024);
        k_rope<<<(Bn * KCn * NKVn * 32 + 255) / 256, 256, 0, stream>>>(kvb, sel, NKVn, 512);
        k_attn<<<dim3(4, NHn, Bn), 256, 0, stream>>>(qb, kvb, aoutHL);

        k_wconv<<<dim3(32, 32), 256, 0, stream>>>(o_w + (long)l * Dn * Dn, WHL, 1024, 1024);
        k_mfma3<<<dim3(8, 8, 4), 256, 0, stream>>>(aoutHL, WHL, nullptr, nullptr, 1024, 1024, 1024, 4, parts);
        k_reduce<<<4096, 256, 0, stream>>>(parts, ao, nullptr, 1048576, 4, 1024);

        k_add_ln2<<<Bn * KCn, 256, 0, stream>>>(xs, ao, ln2_w + (long)l * Dn, h2HL);

        // fused gate|up GEMM: B rows 0..4095 = gate, 4096..8191 = up (spans WT+PARTS;
        // parts is dead here — last consumer was O's reduce, next is down's splitK)
        k_wconv<<<dim3(128, 32), 256, 0, stream>>>(gate_w + (long)l * Dn * FFn, WHL, 1024, 4096);
        k_wconv<<<dim3(128, 32), 256, 0, stream>>>(up_w + (long)l * Dn * FFn, WHL + 4096L * 2048, 1024, 4096);
        k_mfma3<<<dim3(64, 8, 1), 256, 0, stream>>>(h2HL, WHL, gupC, nullptr, 1024, 8192, 1024, 1, parts);

        k_silu_mul<<<(Bn * KCn * FFn + 255) / 256, 256, 0, stream>>>(gupC, ghHL, Bn * KCn * FFn);

        k_wconv<<<dim3(32, 128), 256, 0, stream>>>(down_w + (long)l * FFn * Dn, WHL, 4096, 1024);
        k_mfma3<<<dim3(8, 8, 4), 256, 0, stream>>>(ghHL, WHL, nullptr, nullptr, 1024, 1024, 4096, 4, parts);
        k_reduce<<<4096, 256, 0, stream>>>(parts, ffb, nullptr, 1048576, 4, 1024);

        k_scatter<<<Bn * KCn, 256, 0, stream>>>(xp, ao, ffb, g, sel);
    }

    // decoder
    k_xcvt<<<8192, 256, 0, stream>>>(xp, xpHL, 2097152);
    k_wconv<<<dim3(128, 32), 256, 0, stream>>>(dec_proj_w, WHL, 1024, 4096);
    k_mfma3<<<dim3(32, 16, 1), 256, 0, stream>>>(xpHL, WHL, proj, dec_proj_b, 2048, 4096, 1024, 1, parts);
    k_wconv<<<dim3(8, 32), 256, 0, stream>>>(dec_mlp_w1, WHL, 1024, 256);
    k_mfma3<<<dim3(2, 16, 4), 256, 0, stream>>>(xpHL, WHL, nullptr, nullptr, 2048, 256, 1024, 4, parts);
    k_reduce<<<2048, 256, 0, stream>>>(parts, hmlp, dec_mlp_b1, 524288, 4, 256);
    k_win<<<(Bn * Pn * Sn + 255) / 256, 256, 0, stream>>>(hmlp, dec_mlp_w2, dec_mlp_b2, win);
    k_dec_norm<<<Bn * Pn * Sn, 256, 0, stream>>>(proj, win, dec_norm_w, yHL);
    k_wconv<<<dim3(9, 32), 256, 0, stream>>>(head_w, WHL, 1024, 257);
    k_mfma3<<<dim3(3, 64, 2), 256, 0, stream>>>(yHL, WHL, nullptr, nullptr, 8192, 257, 1024, 2, parts);
    k_reduce<<<8224, 256, 0, stream>>>(parts, out, nullptr, 2105344, 2, 257);
}

// Round 4
// 1455.690 us; speedup vs baseline: 1.2328x; 1.1037x over previous
//
#include <hip/hip_runtime.h>
#include <hip/hip_bf16.h>
#include <math.h>

// ---- model dims ----
constexpr int Bn  = 4;
constexpr int Tn  = 8192;
constexpr int Dn  = 1024;
constexpr int Pn  = 512;
constexpr int SEGn= 16;     // T/P
constexpr int Sn  = 4;
constexpr int Ln  = 4;
constexpr int NHn = 16;
constexpr int NKVn= 4;
constexpr int HDn = 64;
constexpr int FFn = 4096;
constexpr int KCn = 256;
constexpr int Vn  = 257;
constexpr int DHn = 512;    // conv hidden (D/2)

// ---- workspace layout (float elements). total = 33,015,296 floats = 126 MB ----
constexpr long OFF_EW  = 0;                       // 3*257*512 = 394752
constexpr long OFF_CA  = 394752;                  // B*T
constexpr long OFF_CB  = 427520;
constexpr long OFF_CC  = 460288;
constexpr long OFF_ENT = 493056;                  // B*P
constexpr long OFF_IDX = 495104;                  // B*P (int)
constexpr long OFF_XP  = 497152;                  // B*P*D = 2097152
constexpr long OFF_RL  = 2594304;                 // B*P
constexpr long OFF_SEL = 2596352;                 // B*KC (int)
constexpr long OFF_G   = 2597376;                 // B*KC
constexpr long SCR     = 2598400;
// layer-phase scratch (offsets relative to SCR):
constexpr long SC_XS   = 0;         // 1048576
constexpr long SC_H    = 1048576;   // 1048576 (interleaved hi|lo ushort rows)
constexpr long SC_QKV  = 2097152;   // 1572864 (fused q|k|v fp32, row stride 1536)
constexpr long SC_AOUT = 3670016;   // 1048576 (hi|lo)
constexpr long SC_AO   = 4718592;   // 1048576
constexpr long SC_H2   = 5767168;   // 1048576 (hi|lo)
constexpr long SC_GU   = 6815744;   // 8388608 (fused gate|up C, row stride 8192)
// decoder-phase (overlays layer region):
constexpr long SC_PROJ = 0;         // 8912896 (fused proj|hmlp C, row stride 4352)
constexpr long SC_Y    = 8921088;   // 8388608 (hi|lo: 8192 rows x 2048 ushort)
// encoder-phase temporaries (overlay scr, used before layer loop):
constexpr long SC_EA   = 0;         // 384*2048 ushort = 393216 floats
constexpr long SC_WB   = 524288;    // 1536*2048 ushort = 1572864 floats
// new regions (absolute float offsets in ws):
constexpr long OFF_WT    = 19908096;  // 4M floats = 8M ushort: WHL [N][2K] interleaved
constexpr long OFF_PARTS = 24102400;  // 4718592 floats; ALSO overflow rows of large
                                      // B-panels (parts provably dead at those points)
constexpr long OFF_BIASC = OFF_PARTS + 4500000;  // 4352-float concat bias (decoder)
constexpr long OFF_GHL   = 28820992;  // 4M floats: silu-out hl (layer) / xp hl (dec)
// total 33015296

typedef __attribute__((ext_vector_type(8))) short short8;
typedef __attribute__((ext_vector_type(4))) float floatx4;

// ---- helpers ----
__device__ __forceinline__ float geluf(float x) {
    // tanh-gelu via fast exp: tanh(u) = 1 - 2/(e^{2u}+1) (branchless, inf-safe)
    float u = 0.7978845608028654f * (x + 0.044715f * x * x * x);
    float e = __expf(2.f * u);
    float t = 1.f - 2.f / (e + 1.f);
    return 0.5f * x * (1.f + t);
}
__device__ __forceinline__ float sigmf(float x) { return 1.f / (1.f + expf(-x)); }

// fp32 -> bf16 hi/lo split (truncation; x ~= hi + lo, err ~2^-17 rel)
__device__ __forceinline__ void cvt_hilo(float x, unsigned short& h, unsigned short& l) {
    unsigned u = __float_as_uint(x);
    h = (unsigned short)(u >> 16);
    float r = x - __uint_as_float(u & 0xffff0000u);
    l = (unsigned short)(__float_as_uint(r) >> 16);
}

// async global->LDS, 16B per lane (dest = wave-uniform base + lane*16)
typedef const __attribute__((address_space(1))) unsigned int* gas_p;
typedef __attribute__((address_space(3))) unsigned int* las_p;
__device__ __forceinline__ void gload16(const unsigned short* g, unsigned short* l) {
    __builtin_amdgcn_global_load_lds((gas_p)g, (las_p)l, 16, 0, 0);
}

// block (256 threads) sum reduce; red must be __shared__ float[4]
__device__ __forceinline__ float blk_sum256(float v, float* red) {
    for (int o = 32; o > 0; o >>= 1) v += __shfl_down(v, o);
    int lane = threadIdx.x & 63, w = threadIdx.x >> 6;
    if (lane == 0) red[w] = v;
    __syncthreads();
    float r = red[0] + red[1] + red[2] + red[3];
    __syncthreads();
    return r;
}

// ---- encoder A-operand: emb padded to 384 rows, interleaved hi|lo ----
__global__ void k_emb_pad(const float* __restrict__ emb, unsigned short* __restrict__ EA) {
    int i = blockIdx.x * blockDim.x + threadIdx.x;
    if (i >= 384 * 1024) return;
    int r = i >> 10, d = i & 1023;
    float v = (r < Vn) ? emb[r * 1024 + d] : 0.f;
    unsigned short hh, ll;
    cvt_hilo(v, hh, ll);
    EA[(long)r * 2048 + d] = hh;
    EA[(long)r * 2048 + 1024 + d] = ll;
}

// ---- encoder B-operand: WB[n=o*3+dk][k] = w1[o][k][dk], interleaved hi|lo ----
__global__ void k_wconv_w1(const float* __restrict__ w1, unsigned short* __restrict__ WB) {
    int i = blockIdx.x * blockDim.x + threadIdx.x;
    if (i >= 1536 * 1024) return;
    int n = i >> 10, k = i & 1023;
    float v = w1[(n / 3) * 3072 + k * 3 + (n % 3)];
    unsigned short hh, ll;
    cvt_hilo(v, hh, ll);
    WB[(long)n * 2048 + k] = hh;
    WB[(long)n * 2048 + 1024 + k] = ll;
}

// ---- reduce EW splitK partials and remap [v][o*3+dk] -> [dk][v][o] ----
__global__ void k_ewred(const float* __restrict__ parts, float* __restrict__ EW) {
    int i = blockIdx.x * blockDim.x + threadIdx.x;
    if (i >= 3 * Vn * DHn) return;
    int dk = i / (Vn * DHn);
    int rem = i - dk * (Vn * DHn);
    int v = rem >> 9, o = rem & 511;
    long src = (long)v * 1536 + o * 3 + dk;
    float s = 0.f;
    constexpr long MN = 384L * 1536;
    #pragma unroll
    for (int c = 0; c < 4; c++) s += parts[c * MN + src];
    EW[i] = s;
}

// ---- K1: per (b,t): h1 column via EW lookups + gelu, reduce to 3 dots with w2 ----
__global__ void k_conv1(const int* __restrict__ tok, const float* __restrict__ EW,
                        const float* __restrict__ b1, const float* __restrict__ w2,
                        float* __restrict__ cA, float* __restrict__ cB, float* __restrict__ cC) {
    int wave = threadIdx.x >> 6, lane = threadIdx.x & 63;
    int gidx = blockIdx.x * 4 + wave;     // b*T + t
    int b = gidx / Tn, t = gidx - b * Tn;
    int tk  = tok[b * Tn + t];
    int tkm = (t > 0)      ? tok[b * Tn + t - 1] : -1;
    int tkp = (t < Tn - 1) ? tok[b * Tn + t + 1] : -1;
    const float* E0 = EW;
    const float* E1 = EW + (long)Vn * DHn;
    const float* E2 = EW + 2L * Vn * DHn;
    float a0 = 0.f, a1 = 0.f, a2 = 0.f;
    #pragma unroll
    for (int u = 0; u < DHn / 64; u++) {
        int o = lane + u * 64;
        float s = b1[o] + E1[tk * DHn + o];
        if (tkm >= 0) s += E0[tkm * DHn + o];
        if (tkp >= 0) s += E2[tkp * DHn + o];
        float hg = geluf(s);
        a0 += hg * w2[o * 3 + 0];
        a1 += hg * w2[o * 3 + 1];
        a2 += hg * w2[o * 3 + 2];
    }
    for (int o = 32; o > 0; o >>= 1) {
        a0 += __shfl_down(a0, o); a1 += __shfl_down(a1, o); a2 += __shfl_down(a2, o);
    }
    if (lane == 0) { cA[gidx] = a0; cB[gidx] = a1; cC[gidx] = a2; }
}

// ---- K2: lg per token -> per-patch softmax -> ent, idx ----
__global__ void k_patchstats(const float* __restrict__ cA, const float* __restrict__ cB,
                             const float* __restrict__ cC, const float* __restrict__ b2,
                             float* __restrict__ ent_out, int* __restrict__ idx_out) {
    int pid = blockIdx.x * blockDim.x + threadIdx.x;   // b*P + p
    if (pid >= Bn * Pn) return;
    int b = pid / Pn, p = pid - b * Pn;
    float lgv[SEGn];
    float m = -3.4e38f;
    for (int s = 0; s < SEGn; s++) {
        int t = p * SEGn + s;
        float v = b2[0] + cB[b * Tn + t];
        if (t > 0)      v += cA[b * Tn + t - 1];
        if (t < Tn - 1) v += cC[b * Tn + t + 1];
        lgv[s] = v; m = fmaxf(m, v);
    }
    float Z = 0.f;
    for (int s = 0; s < SEGn; s++) { lgv[s] = expf(lgv[s] - m); Z += lgv[s]; }
    float inv = 1.f / Z;
    float bp = 0.f, en = 0.f;
    for (int s = 0; s < SEGn; s++) {
        float w = lgv[s] * inv;
        bp += w * (float)(p * SEGn + s);
        en -= w * logf(fmaxf(w, 1e-8f));
    }
    en *= (1.f / 2.772588722239781f);   // / ln(16)
    ent_out[pid] = en;
    int ix = (int)bp;
    ix = ix < 0 ? 0 : (ix > Tn - 1 ? Tn - 1 : ix);
    idx_out[pid] = ix;
}

// ---- K3: xp[b,p,:] = rmsnorm(emb[tok[b, idx[b,p]]], enc_norm_w). block per row ----
__global__ void k_xp(const int* __restrict__ tok, const int* __restrict__ idx,
                     const float* __restrict__ emb, const float* __restrict__ nw,
                     float* __restrict__ xp) {
    int pid = blockIdx.x;
    int b = pid / Pn;
    int tk = tok[b * Tn + idx[pid]];
    const float* row = emb + (long)tk * Dn;
    __shared__ float red[4];
    float v[4]; float ss = 0.f;
    #pragma unroll
    for (int j = 0; j < 4; j++) { v[j] = row[threadIdx.x + j * 256]; ss += v[j] * v[j]; }
    ss = blk_sum256(ss, red);
    float sc = 1.f / sqrtf(ss * (1.f / Dn) + 1e-6f);
    #pragma unroll
    for (int j = 0; j < 4; j++) {
        int d = threadIdx.x + j * 256;
        xp[(long)pid * Dn + d] = v[j] * sc * nw[d];
    }
}

// ---- K4: rl[b,p] = xp[b,p,:]·rw + ent. block per row ----
__global__ void k_router(const float* __restrict__ xp, const float* __restrict__ rw,
                         const float* __restrict__ ent, float* __restrict__ rl) {
    int pid = blockIdx.x;
    const float* xr = xp + (long)pid * Dn;
    __shared__ float red[4];
    float s = 0.f;
    #pragma unroll
    for (int j = 0; j < 4; j++) { int d = threadIdx.x + j * 256; s += xr[d] * rw[d]; }
    s = blk_sum256(s, red);
    if (threadIdx.x == 0) rl[pid] = s + ent[pid];
}

// ---- K5: exact top-k (KC of P) with jax tie semantics, output ascending by index ----
__global__ void k_topk(const float* __restrict__ rl, int* __restrict__ sel, float* __restrict__ g) {
    int b = blockIdx.x, p = threadIdx.x;
    __shared__ float vals[Pn];
    __shared__ int flag[Pn];
    float v = rl[b * Pn + p];
    vals[p] = v;
    __syncthreads();
    int rank = 0;
    for (int q = 0; q < Pn; q++) {
        float vq = vals[q];
        rank += (vq > v || (vq == v && q < p)) ? 1 : 0;
    }
    int selected = rank < KCn ? 1 : 0;
    flag[p] = selected;
    __syncthreads();
    if (selected) {
        int pos = 0;
        for (int q = 0; q < p; q++) pos += flag[q];
        sel[b * KCn + pos] = p;
        g[b * KCn + pos] = sigmf(v);
    }
}

// ---- K6: gather xs = xp[b, sel]; h = rmsnorm(xs, ln1) emitted interleaved hi|lo ----
__global__ void k_gather_ln1(const float* __restrict__ xp, const int* __restrict__ sel,
                             const float* __restrict__ w, float* __restrict__ xs,
                             unsigned short* __restrict__ hHL) {
    int r = blockIdx.x;            // b*KC + j
    int b = r / KCn;
    int p = sel[r];
    const float* src = xp + ((long)b * Pn + p) * Dn;
    __shared__ float red[4];
    float v[4]; float ss = 0.f;
    #pragma unroll
    for (int j = 0; j < 4; j++) { v[j] = src[threadIdx.x + j * 256]; ss += v[j] * v[j]; }
    ss = blk_sum256(ss, red);
    float sc = 1.f / sqrtf(ss * (1.f / Dn) + 1e-6f);
    #pragma unroll
    for (int j = 0; j < 4; j++) {
        int d = threadIdx.x + j * 256;
        xs[(long)r * Dn + d] = v[j];
        unsigned short hh, ll;
        cvt_hilo(v[j] * sc * w[d], hh, ll);
        hHL[(long)r * 2048 + d] = hh;
        hHL[(long)r * 2048 + 1024 + d] = ll;
    }
}

// ---- weight convert+transpose core: W[K][N] fp32 -> WHL[roff+n][2K] hi|lo ----
__device__ __forceinline__ void wconv_body(const float* __restrict__ Wm,
                                           unsigned short* __restrict__ Whl,
                                           int K, int N, int roff, int n0, int k0) {
    __shared__ float t[32][33];
    int tx = threadIdx.x & 31, ty = threadIdx.x >> 5;
    #pragma unroll
    for (int r = 0; r < 4; r++) {
        int k = k0 + ty + 8 * r, n = n0 + tx;
        t[ty + 8 * r][tx] = (n < N) ? Wm[(long)k * N + n] : 0.f;
    }
    __syncthreads();
    long K2 = 2L * K;
    #pragma unroll
    for (int r = 0; r < 4; r++) {
        int n = n0 + ty + 8 * r, k = k0 + tx;
        float v = t[tx][ty + 8 * r];
        unsigned short hh, ll;
        cvt_hilo(v, hh, ll);
        Whl[(long)(roff + n) * K2 + k] = hh;
        Whl[(long)(roff + n) * K2 + K + k] = ll;
    }
}

// grid (ceil(N/32), K/32), block 256
__global__ void k_wconv(const float* __restrict__ Wm, unsigned short* __restrict__ Whl,
                        int K, int N, int roff) {
    wconv_body(Wm, Whl, K, N, roff, blockIdx.x * 32, blockIdx.y * 32);
}

// two equal-N panels stacked: rows 0..Nh-1 = A, Nh..2Nh-1 = B. grid (2*Nh/32, K/32)
__global__ void k_wconv2(const float* __restrict__ Wa, const float* __restrict__ Wb,
                         unsigned short* __restrict__ Whl, int K, int Nh) {
    int nb = Nh >> 5;
    int bx = blockIdx.x;
    const float* src = (bx < nb) ? Wa : Wb;
    int xb = (bx < nb) ? bx : bx - nb;
    int roff = (bx < nb) ? 0 : Nh;
    wconv_body(src, Whl, K, Nh, roff, xb * 32, blockIdx.y * 32);
}

// q|k|v panels: rows 0..1023 = q_w, 1024..1279 = k_w, 1280..1535 = v_w. grid (48,32)
__global__ void k_wconv_qkv(const float* __restrict__ qw, const float* __restrict__ kw,
                            const float* __restrict__ vw, unsigned short* __restrict__ Whl) {
    int bx = blockIdx.x;
    const float* src; int xb, roff, Nsrc;
    if (bx < 32)      { src = qw; xb = bx;      roff = 0;    Nsrc = 1024; }
    else if (bx < 40) { src = kw; xb = bx - 32; roff = 1024; Nsrc = 256; }
    else              { src = vw; xb = bx - 40; roff = 1280; Nsrc = 256; }
    wconv_body(src, Whl, 1024, Nsrc, roff, xb * 32, blockIdx.y * 32);
}

// ---- elementwise fp32 -> interleaved hi|lo rows of 1024 ----
__global__ void k_xcvt(const float* __restrict__ src, unsigned short* __restrict__ dhl, int n) {
    int i = blockIdx.x * blockDim.x + threadIdx.x;
    if (i >= n) return;
    int r = i >> 10, d = i & 1023;
    unsigned short hh, ll;
    cvt_hilo(src[i], hh, ll);
    dhl[(long)r * 2048 + d] = hh;
    dhl[(long)r * 2048 + 1024 + d] = ll;
}

// ---- MFMA GEMM on interleaved hi|lo operands. A[M][2K], B[N][2K] ushort rows.
//      2-phase pipeline: double-buffered LDS; stage tile ks+1 via global_load_lds
//      BEFORE computing tile ks; single __syncthreads per K-step (implicit
//      vmcnt(0)+barrier drains AFTER the MFMA cluster -> flight overlaps compute).
//      XOR chunk swizzle on source+read (rule #21).
// grid (ceil(N/128), M/128, splitK), block 256. splitK>1 -> parts; else C(+bias).
// M%128==0, (K/splitK)%32==0.
__global__ __launch_bounds__(256, 2) void k_mfma3(
        const unsigned short* __restrict__ Ag, const unsigned short* __restrict__ Bg,
        float* __restrict__ Cmat, const float* __restrict__ bias,
        int M, int N, int K, int splitK, float* __restrict__ parts) {
    __shared__ alignas(16) unsigned short As[2][128 * 64], Bs[2][128 * 64];
    int tid = threadIdx.x;
    int m0 = blockIdx.y * 128, n0 = blockIdx.x * 128;
    int kc = blockIdx.z;
    int Kc = K / splitK, kbase = kc * Kc, KT = Kc >> 5;
    int lane = tid & 63, wid = tid >> 6;
    int wm = (wid & 1) * 64, wn = (wid >> 1) * 64;
    int quad = lane >> 4, l16 = lane & 15;

    // staging geometry: 16 segments of 1KB per tile (4 per wave); lane L covers
    // row seg*8 + (L>>3), LDS slot L&7, which must hold logical chunk (L&7)^(row&7).
    int srow8 = lane >> 3;
    int spos  = lane & 7;
    int cch   = spos ^ srow8;                       // row&7 == srow8 for every segment
    long K2 = 2L * K;
    long coff = (cch < 4) ? (long)(cch * 8) : (long)K + (long)((cch - 4) * 8);
    const unsigned short* Aseg = Ag + (long)(m0 + srow8) * K2 + coff;
    const unsigned short* Bseg = Bg + (long)(n0 + srow8) * K2 + coff;   // OOB rows (pad) read garbage, never stored

    floatx4 acc[4][4];
    #pragma unroll
    for (int i = 0; i < 4; i++)
        #pragma unroll
        for (int j = 0; j < 4; j++) acc[i][j] = (floatx4){0.f, 0.f, 0.f, 0.f};

    auto stagef = [&](unsigned short* Ad, unsigned short* Bd, long kb) {
        #pragma unroll
        for (int t = 0; t < 4; t++) {
            int sa = wid * 4 + t;
            gload16(Aseg + (long)sa * 8 * K2 + kb, Ad + sa * 512);
            gload16(Bseg + (long)sa * 8 * K2 + kb, Bd + sa * 512);
        }
    };

    int ph = quad ^ (l16 & 7);                      // hi-chunk slot; lo = ph^4
    stagef(As[0], Bs[0], kbase);
    __syncthreads();                                // tile 0 resident
    int cur = 0;
    for (int ks = 0; ks < KT; ks++) {
        if (ks + 1 < KT)                            // prefetch next tile into other buf
            stagef(As[cur ^ 1], Bs[cur ^ 1], kbase + (long)(ks + 1) * 32);

        const unsigned short* Ac = As[cur];
        const unsigned short* Bc = Bs[cur];
        short8 ah[4], al2[4], bh[4], bl2[4];
        #pragma unroll
        for (int i = 0; i < 4; i++) {
            int r = wm + i * 16 + l16;
            ah[i]  = *(const short8*)&Ac[r * 64 + ph * 8];
            al2[i] = *(const short8*)&Ac[r * 64 + (ph ^ 4) * 8];
        }
        #pragma unroll
        for (int j = 0; j < 4; j++) {
            int c = wn + j * 16 + l16;
            bh[j]  = *(const short8*)&Bc[c * 64 + ph * 8];
            bl2[j] = *(const short8*)&Bc[c * 64 + (ph ^ 4) * 8];
        }
        #pragma unroll
        for (int i = 0; i < 4; i++)
            #pragma unroll
            for (int j = 0; j < 4; j++) {
                acc[i][j] = __builtin_amdgcn_mfma_f32_16x16x32_bf16(ah[i],  bh[j],  acc[i][j], 0, 0, 0);
                acc[i][j] = __builtin_amdgcn_mfma_f32_16x16x32_bf16(ah[i],  bl2[j], acc[i][j], 0, 0, 0);
                acc[i][j] = __builtin_amdgcn_mfma_f32_16x16x32_bf16(al2[i], bh[j],  acc[i][j], 0, 0, 0);
            }
        __syncthreads();   // drains this iter's prefetch (vmcnt0) + WAR protection
        cur ^= 1;
    }

    // epilogue: C/D layout col=lane&15, row=quad*4+reg (m89/m91)
    long MN = (long)M * N;
    #pragma unroll
    for (int j = 0; j < 4; j++) {
        int n = n0 + wn + j * 16 + l16;
        if (n >= N) continue;
        float bvx = bias ? bias[n] : 0.f;
        #pragma unroll
        for (int i = 0; i < 4; i++) {
            int mb = m0 + wm + i * 16 + quad * 4;
            #pragma unroll
            for (int r = 0; r < 4; r++) {
                if (splitK > 1) parts[kc * MN + (long)(mb + r) * N + n] = acc[i][j][r];
                else            Cmat[(long)(mb + r) * N + n] = acc[i][j][r] + bvx;
            }
        }
    }
}

// ---- reduce splitK partials (+optional bias) ----
__global__ void k_reduce(const float* __restrict__ parts, float* __restrict__ out,
                         const float* __restrict__ bias, long MN, int sk, int N) {
    long i = (long)blockIdx.x * blockDim.x + threadIdx.x;
    if (i >= MN) return;
    float s = 0.f;
    for (int c = 0; c < sk; c++) s += parts[c * MN + i];
    if (bias) s += bias[(int)(i % N)];
    out[i] = s;
}

// ---- fused QKV finish: sum splitK=2 parts + RoPE (q heads 0-15, k slots 16-19,
//      v slots 20-23 pass-through). block per row (B*KC), 256 thr, 768 pairs ----
__global__ void k_qkv_finish(const float* __restrict__ parts, const int* __restrict__ sel,
                             float* __restrict__ qkv) {
    int r = blockIdx.x;
    int pos = sel[r];
    constexpr long MN = 1024L * 1536;
    #pragma unroll
    for (int it = 0; it < 3; it++) {
        int pp = threadIdx.x + it * 256;          // 0..767
        int head = pp >> 5, d = pp & 31;
        long c1 = (long)r * 1536 + head * 64 + d;
        float s1 = parts[c1] + parts[MN + c1];
        float s2 = parts[c1 + 32] + parts[MN + c1 + 32];
        if (head < 20) {
            float theta = powf(10000.f, -(float)(2 * d) / 64.f);
            float ang = (float)pos * theta;
            float cc = cosf(ang), ssn = sinf(ang);
            qkv[c1]      = s1 * cc - s2 * ssn;
            qkv[c1 + 32] = s2 * cc + s1 * ssn;
        } else {
            qkv[c1] = s1; qkv[c1 + 32] = s2;
        }
    }
}

// ---- MFMA flash attention; fused qkv buffer (row stride 1536: q cols 0..1023,
//      k cols 1024..1279, v cols 1280..1535); epilogue emits aout hi|lo ----
constexpr int APS = 72;
__global__ __launch_bounds__(256) void k_attn(const float* __restrict__ qkv,
                       unsigned short* __restrict__ aoHL) {
    int bx = blockIdx.x, h = blockIdx.y, b = blockIdx.z;
    int hk = h >> 2;
    int qb0 = bx * 64;
    int tid = threadIdx.x, lane = tid & 63, wid = tid >> 6;
    int quad = lane >> 4, l16 = lane & 15;
    __shared__ alignas(16) unsigned short LdsA[9216], LdsB[9216];
    unsigned short* Kh = LdsA;          unsigned short* Kl = LdsB;
    unsigned short* Ph = LdsA;          unsigned short* Pl = LdsB;
    unsigned short* Vth = LdsA + 4608;  unsigned short* Vtl = LdsB + 4608;

    int qrow = qb0 + wid * 16 + l16;
    short8 qh[2], ql[2];
    #pragma unroll
    for (int ks = 0; ks < 2; ks++) {
        const float* qp = qkv + ((long)(b * KCn + qrow)) * 1536 + h * HDn + ks * 32 + quad * 8;
        float tmp[8];
        *(float4*)tmp = *(const float4*)qp;
        *(float4*)(tmp + 4) = *(const float4*)(qp + 4);
        #pragma unroll
        for (int j = 0; j < 8; j++) {
            unsigned short hh, ll;
            cvt_hilo(tmp[j], hh, ll);
            qh[ks][j] = (short)hh; ql[ks][j] = (short)ll;
        }
    }

    floatx4 sacc[16];
    #pragma unroll
    for (int t = 0; t < 16; t++) sacc[t] = (floatx4){0.f, 0.f, 0.f, 0.f};

    int qmax = qb0 + 63;
    int nkc = qmax / 128 + 1;
    for (int kc = 0; kc < nkc; kc++) {
        __syncthreads();
        {
            int r = tid >> 1, dh = (tid & 1) * 32;
            const float* kp = qkv + ((long)(b * KCn + kc * 128 + r)) * 1536 + 1024 + hk * HDn + dh;
            #pragma unroll
            for (int f = 0; f < 8; f++) {
                float tmp[4];
                *(float4*)tmp = *(const float4*)(kp + f * 4);
                unsigned short h0, h1, h2, h3, l0, l1, l2, l3;
                cvt_hilo(tmp[0], h0, l0); cvt_hilo(tmp[1], h1, l1);
                cvt_hilo(tmp[2], h2, l2); cvt_hilo(tmp[3], h3, l3);
                *(ushort4*)&Kh[r * APS + dh + f * 4] = make_ushort4(h0, h1, h2, h3);
                *(ushort4*)&Kl[r * APS + dh + f * 4] = make_ushort4(l0, l1, l2, l3);
            }
        }
        __syncthreads();
        #pragma unroll
        for (int tj = 0; tj < 8; tj++) {
            int kr = tj * 16 + l16;
            int gt = kc * 8 + tj;
            #pragma unroll
            for (int ks = 0; ks < 2; ks++) {
                short8 bh0 = *(const short8*)&Kh[kr * APS + ks * 32 + quad * 8];
                short8 bl0 = *(const short8*)&Kl[kr * APS + ks * 32 + quad * 8];
                sacc[gt] = __builtin_amdgcn_mfma_f32_16x16x32_bf16(qh[ks], bh0, sacc[gt], 0, 0, 0);
                sacc[gt] = __builtin_amdgcn_mfma_f32_16x16x32_bf16(qh[ks], bl0, sacc[gt], 0, 0, 0);
                sacc[gt] = __builtin_amdgcn_mfma_f32_16x16x32_bf16(ql[ks], bh0, sacc[gt], 0, 0, 0);
            }
        }
    }

    float rowinv[4];
    #pragma unroll
    for (int r = 0; r < 4; r++) {
        int qg = qb0 + wid * 16 + quad * 4 + r;
        float mm = -3.4e38f;
        #pragma unroll
        for (int t = 0; t < 16; t++) {
            int key = t * 16 + l16;
            float s = (key <= qg) ? sacc[t][r] * 0.125f : -1e30f;
            sacc[t][r] = s;
            mm = fmaxf(mm, s);
        }
        #pragma unroll
        for (int o = 1; o < 16; o <<= 1) mm = fmaxf(mm, __shfl_xor(mm, o));
        float zz = 0.f;
        #pragma unroll
        for (int t = 0; t < 16; t++) {
            float e = expf(sacc[t][r] - mm);
            sacc[t][r] = e; zz += e;
        }
        #pragma unroll
        for (int o = 1; o < 16; o <<= 1) zz += __shfl_xor(zz, o);
        rowinv[r] = 1.f / zz;
    }

    floatx4 oacc[4];
    #pragma unroll
    for (int dt = 0; dt < 4; dt++) oacc[dt] = (floatx4){0.f, 0.f, 0.f, 0.f};
    int npv = qmax / 64 + 1;
    for (int c4 = 0; c4 < npv; c4++) {
        __syncthreads();
        {
            #pragma unroll
            for (int it = 0; it < 4; it++) {
                int task = tid + 256 * it;
                int kloc = task & 63, d4 = (task >> 6) * 4;
                float tmp[4];
                *(float4*)tmp = *(const float4*)(qkv + ((long)(b * KCn + c4 * 64 + kloc)) * 1536 + 1280 + hk * HDn + d4);
                #pragma unroll
                for (int i = 0; i < 4; i++) {
                    unsigned short hh, ll;
                    cvt_hilo(tmp[i], hh, ll);
                    Vth[(d4 + i) * APS + kloc] = hh;
                    Vtl[(d4 + i) * APS + kloc] = ll;
                }
            }
        }
        #pragma unroll
        for (int tt = 0; tt < 4; tt++) {
            int t = c4 * 4 + tt;
            #pragma unroll
            for (int r = 0; r < 4; r++) {
                int row = wid * 16 + quad * 4 + r;
                float pv2 = sacc[t][r] * rowinv[r];
                unsigned short hh, ll;
                cvt_hilo(pv2, hh, ll);
                Ph[row * APS + tt * 16 + l16] = hh;
                Pl[row * APS + tt * 16 + l16] = ll;
            }
        }
        __syncthreads();
        short8 pah[2], pal[2];
        #pragma unroll
        for (int ks = 0; ks < 2; ks++) {
            pah[ks] = *(const short8*)&Ph[(wid * 16 + l16) * APS + ks * 32 + quad * 8];
            pal[ks] = *(const short8*)&Pl[(wid * 16 + l16) * APS + ks * 32 + quad * 8];
        }
        #pragma unroll
        for (int dt = 0; dt < 4; dt++) {
            #pragma unroll
            for (int ks = 0; ks < 2; ks++) {
                short8 vbh = *(const short8*)&Vth[(dt * 16 + l16) * APS + ks * 32 + quad * 8];
                short8 vbl = *(const short8*)&Vtl[(dt * 16 + l16) * APS + ks * 32 + quad * 8];
                oacc[dt] = __builtin_amdgcn_mfma_f32_16x16x32_bf16(pah[ks], vbh, oacc[dt], 0, 0, 0);
                oacc[dt] = __builtin_amdgcn_mfma_f32_16x16x32_bf16(pah[ks], vbl, oacc[dt], 0, 0, 0);
                oacc[dt] = __builtin_amdgcn_mfma_f32_16x16x32_bf16(pal[ks], vbh, oacc[dt], 0, 0, 0);
            }
        }
    }

    #pragma unroll
    for (int dt = 0; dt < 4; dt++) {
        #pragma unroll
        for (int r = 0; r < 4; r++) {
            int row = qb0 + wid * 16 + quad * 4 + r;
            long base = ((long)(b * KCn + row)) * 2048 + h * HDn + dt * 16 + l16;
            unsigned short hh, ll;
            cvt_hilo(oacc[dt][r], hh, ll);
            aoHL[base] = hh; aoHL[base + 1024] = ll;
        }
    }
}

// ---- fused: ao = reduce(O parts); x2 = xs + ao; h2 = rmsnorm(x2, ln2) hi|lo ----
__global__ void k_add_ln2_red(const float* __restrict__ parts, const float* __restrict__ xs,
                              const float* __restrict__ w, float* __restrict__ ao,
                              unsigned short* __restrict__ h2HL) {
    int r = blockIdx.x;
    constexpr long MN = 1024L * 1024;
    __shared__ float red[4];
    float v[4]; float ss = 0.f;
    #pragma unroll
    for (int j = 0; j < 4; j++) {
        int d = threadIdx.x + j * 256;
        long i = (long)r * Dn + d;
        float a = 0.f;
        #pragma unroll
        for (int c = 0; c < 4; c++) a += parts[c * MN + i];
        ao[i] = a;
        float x = xs[i] + a;
        v[j] = x; ss += x * x;
    }
    ss = blk_sum256(ss, red);
    float sc = 1.f / sqrtf(ss * (1.f / Dn) + 1e-6f);
    #pragma unroll
    for (int j = 0; j < 4; j++) {
        int d = threadIdx.x + j * 256;
        unsigned short hh, ll;
        cvt_hilo(v[j] * sc * w[d], hh, ll);
        h2HL[(long)r * 2048 + d] = hh;
        h2HL[(long)r * 2048 + 1024 + d] = ll;
    }
}

// ---- silu(gate)*up on fused C (row stride 8192: gate 0..4095, up 4096..8191) ----
__global__ void k_silu_mul(const float* __restrict__ C, unsigned short* __restrict__ ghl, int n) {
    int i = blockIdx.x * blockDim.x + threadIdx.x;
    if (i < n) {
        int r = i >> 12, c = i & 4095;
        float x = C[(long)r * 8192 + c];
        float u = C[(long)r * 8192 + 4096 + c];
        unsigned short hh, ll;
        cvt_hilo(x * sigmf(x) * u, hh, ll);
        ghl[(long)r * 8192 + c] = hh;
        ghl[(long)r * 8192 + 4096 + c] = ll;
    }
}

// ---- fused: ff = reduce(down parts); xp[b, sel[b,j], :] += g * (ao + ff) ----
__global__ void k_scatter_red(float* __restrict__ xp, const float* __restrict__ ao,
                              const float* __restrict__ parts, const float* __restrict__ g,
                              const int* __restrict__ sel) {
    int r = blockIdx.x;
    int b = r / KCn;
    int p = sel[r];
    float gg = g[r];
    constexpr long MN = 1024L * 1024;
    float* dst = xp + ((long)b * Pn + p) * Dn;
    #pragma unroll
    for (int j = 0; j < 4; j++) {
        int d = threadIdx.x + j * 256;
        long i = (long)r * Dn + d;
        float f = 0.f;
        #pragma unroll
        for (int c = 0; c < 4; c++) f += parts[c * MN + i];
        dst[d] += gg * (ao[i] + f);
    }
}

// ---- decoder: concat bias [dec_proj_b | dec_mlp_b1] (4352) ----
__global__ void k_catbias(const float* __restrict__ a, const float* __restrict__ b,
                          float* __restrict__ o) {
    int i = blockIdx.x * blockDim.x + threadIdx.x;
    if (i < 4352) o[i] = (i < 4096) ? a[i] : b[i - 4096];
}

// ---- fused decoder norm: win = sigmoid(gelu(hmlp_row)@w2[:,s]+b2[s]);
//      y = rmsnorm(proj*win, dec_norm_w) hi|lo. projC row stride 4352:
//      proj cols s*1024..s*1024+1023, hmlp cols 4096..4351. block per (bp,s) ----
__global__ void k_dec_norm_win(const float* __restrict__ projC, const float* __restrict__ w2,
                               const float* __restrict__ b2, const float* __restrict__ w,
                               unsigned short* __restrict__ yHL) {
    int r = blockIdx.x;            // bp*4 + s
    int bp = r >> 2, s = r & 3;
    __shared__ float red[4];
    const float* hr = projC + (long)bp * 4352 + 4096;
    float acc = geluf(hr[threadIdx.x]) * w2[threadIdx.x * 4 + s];
    acc = blk_sum256(acc, red);
    float wv = sigmf(acc + b2[s]);
    const float* pr = projC + (long)bp * 4352 + s * 1024;
    float v[4]; float ss = 0.f;
    #pragma unroll
    for (int j = 0; j < 4; j++) {
        int d = threadIdx.x + j * 256;
        float x = pr[d] * wv;
        v[j] = x; ss += x * x;
    }
    ss = blk_sum256(ss, red);
    float sc = 1.f / sqrtf(ss * (1.f / Dn) + 1e-6f);
    #pragma unroll
    for (int j = 0; j < 4; j++) {
        int d = threadIdx.x + j * 256;
        unsigned short hh, ll;
        cvt_hilo(v[j] * sc * w[d], hh, ll);
        yHL[(long)r * 2048 + d] = hh;
        yHL[(long)r * 2048 + 1024 + d] = ll;
    }
}

extern "C" void kernel_launch(void* const* d_in, const int* in_sizes, int n_in,
                              void* d_out, int out_size, void* d_ws, size_t ws_size,
                              hipStream_t stream) {
    const int*   tokens     = (const int*)  d_in[0];
    const float* emb        = (const float*)d_in[1];
    const float* bp_w1      = (const float*)d_in[2];
    const float* bp_b1      = (const float*)d_in[3];
    const float* bp_w2      = (const float*)d_in[4];
    const float* bp_b2      = (const float*)d_in[5];
    const float* enc_norm_w = (const float*)d_in[6];
    const float* router_w   = (const float*)d_in[7];
    const float* ln1_w      = (const float*)d_in[8];
    const float* ln2_w      = (const float*)d_in[9];
    const float* q_w        = (const float*)d_in[10];
    const float* k_w        = (const float*)d_in[11];
    const float* v_w        = (const float*)d_in[12];
    const float* o_w        = (const float*)d_in[13];
    const float* gate_w     = (const float*)d_in[14];
    const float* up_w       = (const float*)d_in[15];
    const float* down_w     = (const float*)d_in[16];
    const float* dec_proj_w = (const float*)d_in[17];
    const float* dec_proj_b = (const float*)d_in[18];
    const float* dec_mlp_w1 = (const float*)d_in[19];
    const float* dec_mlp_b1 = (const float*)d_in[20];
    const float* dec_mlp_w2 = (const float*)d_in[21];
    const float* dec_mlp_b2 = (const float*)d_in[22];
    const float* dec_norm_w = (const float*)d_in[23];
    const float* head_w     = (const float*)d_in[24];
    float* out = (float*)d_out;

    float* W = (float*)d_ws;
    float* EW   = W + OFF_EW;
    float* cA   = W + OFF_CA;
    float* cB   = W + OFF_CB;
    float* cC   = W + OFF_CC;
    float* ent  = W + OFF_ENT;
    int*   idxb = (int*)(W + OFF_IDX);
    float* xp   = W + OFF_XP;
    float* rl   = W + OFF_RL;
    int*   sel  = (int*)(W + OFF_SEL);
    float* g    = W + OFF_G;
    float* scr  = W + SCR;
    float* xs   = scr + SC_XS;
    unsigned short* hHL   = (unsigned short*)(scr + SC_H);
    float* qkv  = scr + SC_QKV;
    unsigned short* aoutHL = (unsigned short*)(scr + SC_AOUT);
    float* ao   = scr + SC_AO;
    unsigned short* h2HL  = (unsigned short*)(scr + SC_H2);
    float* gupC = scr + SC_GU;
    float* projC= scr + SC_PROJ;
    unsigned short* yHL   = (unsigned short*)(scr + SC_Y);
    unsigned short* EA    = (unsigned short*)(scr + SC_EA);   // encoder only
    unsigned short* WB    = (unsigned short*)(scr + SC_WB);   // encoder only
    unsigned short* WHL   = (unsigned short*)(W + OFF_WT);
    float* parts = W + OFF_PARTS;
    float* biasc = W + OFF_BIASC;
    unsigned short* ghHL  = (unsigned short*)(W + OFF_GHL);   // layer: silu-out hl
    unsigned short* xpHL  = (unsigned short*)(W + OFF_GHL);   // decoder: xp hl

    // byte-patch encoder: EW via MFMA hi/lo GEMM (M=384 pad, N=1536, K=1024)
    k_emb_pad<<<1536, 256, 0, stream>>>(emb, EA);
    k_wconv_w1<<<6144, 256, 0, stream>>>(bp_w1, WB);
    k_mfma3<<<dim3(12, 3, 4), 256, 0, stream>>>(EA, WB, nullptr, nullptr, 384, 1536, 1024, 4, parts);
    k_ewred<<<1542, 256, 0, stream>>>(parts, EW);
    k_conv1<<<Bn * Tn / 4, 256, 0, stream>>>(tokens, EW, bp_b1, bp_w2, cA, cB, cC);
    k_patchstats<<<(Bn * Pn + 255) / 256, 256, 0, stream>>>(cA, cB, cC, bp_b2, ent, idxb);
    k_xp<<<Bn * Pn, 256, 0, stream>>>(tokens, idxb, emb, enc_norm_w, xp);

    for (int l = 0; l < Ln; l++) {
        k_router<<<Bn * Pn, 256, 0, stream>>>(xp, router_w + (long)l * Dn, ent, rl);
        k_topk<<<Bn, Pn, 0, stream>>>(rl, sel, g);
        k_gather_ln1<<<Bn * KCn, 256, 0, stream>>>(xp, sel, ln1_w + (long)l * Dn, xs, hHL);

        // fused Q|K|V GEMM: B rows 0..1023 = q_w, 1024..1279 = k_w, 1280..1535 = v_w
        k_wconv_qkv<<<dim3(48, 32), 256, 0, stream>>>(q_w + (long)l * Dn * Dn,
                                                      k_w + (long)l * Dn * 256,
                                                      v_w + (long)l * Dn * 256, WHL);
        k_mfma3<<<dim3(12, 8, 2), 256, 0, stream>>>(hHL, WHL, nullptr, nullptr, 1024, 1536, 1024, 2, parts);
        k_qkv_finish<<<Bn * KCn, 256, 0, stream>>>(parts, sel, qkv);

        k_attn<<<dim3(4, NHn, Bn), 256, 0, stream>>>(qkv, aoutHL);

        k_wconv<<<dim3(32, 32), 256, 0, stream>>>(o_w + (long)l * Dn * Dn, WHL, 1024, 1024, 0);
        k_mfma3<<<dim3(8, 8, 4), 256, 0, stream>>>(aoutHL, WHL, nullptr, nullptr, 1024, 1024, 1024, 4, parts);
        k_add_ln2_red<<<Bn * KCn, 256, 0, stream>>>(parts, xs, ln2_w + (long)l * Dn, ao, h2HL);

        // fused gate|up GEMM: B rows 0..4095 = gate, 4096..8191 = up (spans WT+PARTS;
        // parts is dead here — last consumer was add_ln2_red, next is down's splitK)
        k_wconv2<<<dim3(256, 32), 256, 0, stream>>>(gate_w + (long)l * Dn * FFn,
                                                    up_w + (long)l * Dn * FFn, WHL, 1024, 4096);
        k_mfma3<<<dim3(64, 8, 1), 256, 0, stream>>>(h2HL, WHL, gupC, nullptr, 1024, 8192, 1024, 1, parts);

        k_silu_mul<<<(Bn * KCn * FFn + 255) / 256, 256, 0, stream>>>(gupC, ghHL, Bn * KCn * FFn);

        k_wconv<<<dim3(32, 128), 256, 0, stream>>>(down_w + (long)l * FFn * Dn, WHL, 4096, 1024, 0);
        k_mfma3<<<dim3(8, 8, 4), 256, 0, stream>>>(ghHL, WHL, nullptr, nullptr, 1024, 1024, 4096, 4, parts);
        k_scatter_red<<<Bn * KCn, 256, 0, stream>>>(xp, ao, parts, g, sel);
    }

    // decoder: fused proj|mlp1 GEMM (N=4352, splitK=1, concat bias), then
    // fused win+dec_norm, then head GEMM
    k_xcvt<<<8192, 256, 0, stream>>>(xp, xpHL, 2097152);
    k_catbias<<<17, 256, 0, stream>>>(dec_proj_b, dec_mlp_b1, biasc);
    k_wconv<<<dim3(128, 32), 256, 0, stream>>>(dec_proj_w, WHL, 1024, 4096, 0);
    k_wconv<<<dim3(8, 32), 256, 0, stream>>>(dec_mlp_w1, WHL, 1024, 256, 4096);
    k_mfma3<<<dim3(34, 16, 1), 256, 0, stream>>>(xpHL, WHL, projC, biasc, 2048, 4352, 1024, 1, parts);
    k_dec_norm_win<<<Bn * Pn * Sn, 256, 0, stream>>>(projC, dec_mlp_w2, dec_mlp_b2, dec_norm_w, yHL);
    k_wconv<<<dim3(9, 32), 256, 0, stream>>>(head_w, WHL, 1024, 257, 0);
    k_mfma3<<<dim3(3, 64, 2), 256, 0, stream>>>(yHL, WHL, nullptr, nullptr, 8192, 257, 1024, 2, parts);
    k_reduce<<<8224, 256, 0, stream>>>(parts, out, nullptr, 2105344, 2, 257);
}

// Round 5
// 1437.370 us; speedup vs baseline: 1.2486x; 1.0127x over previous
//
#include <hip/hip_runtime.h>
#include <hip/hip_bf16.h>
#include <math.h>

// ---- model dims ----
constexpr int Bn  = 4;
constexpr int Tn  = 8192;
constexpr int Dn  = 1024;
constexpr int Pn  = 512;
constexpr int SEGn= 16;     // T/P
constexpr int Sn  = 4;
constexpr int Ln  = 4;
constexpr int NHn = 16;
constexpr int NKVn= 4;
constexpr int HDn = 64;
constexpr int FFn = 4096;
constexpr int KCn = 256;
constexpr int Vn  = 257;
constexpr int DHn = 512;    // conv hidden (D/2)

// ---- workspace layout (float elements). total = 33,015,296 floats = 126 MB ----
constexpr long OFF_EW  = 0;                       // 3*257*512 = 394752
constexpr long OFF_CA  = 394752;                  // B*T
constexpr long OFF_CB  = 427520;
constexpr long OFF_CC  = 460288;
constexpr long OFF_ENT = 493056;                  // B*P
constexpr long OFF_IDX = 495104;                  // B*P (int)
constexpr long OFF_XP  = 497152;                  // B*P*D = 2097152
constexpr long OFF_RL  = 2594304;                 // B*P
constexpr long OFF_SEL = 2596352;                 // B*KC (int)
constexpr long OFF_G   = 2597376;                 // B*KC
constexpr long SCR     = 2598400;
// layer-phase scratch (offsets relative to SCR):
constexpr long SC_XS   = 0;         // 1048576
constexpr long SC_H    = 1048576;   // 1048576 (interleaved hi|lo ushort rows)
constexpr long SC_QKV  = 2097152;   // 1572864 (fused q|k|v fp32, row stride 1536)
constexpr long SC_AOUT = 3670016;   // 1048576 (hi|lo)
constexpr long SC_AO   = 4718592;   // 1048576
constexpr long SC_H2   = 5767168;   // 1048576 (hi|lo)
constexpr long SC_GU   = 6815744;   // 8388608 (fused gate|up C, row stride 8192)
// decoder-phase (overlays layer region):
constexpr long SC_PROJ = 0;         // 8388608 (proj C, row stride 4096)
constexpr long SC_Y    = 8921088;   // 8388608 (hi|lo: 8192 rows x 2048 ushort)
// encoder-phase temporaries (overlay scr, used before layer loop):
constexpr long SC_EA   = 0;         // 384*2048 ushort = 393216 floats
constexpr long SC_WB   = 524288;    // 1536*2048 ushort = 1572864 floats
// new regions (absolute float offsets in ws):
constexpr long OFF_WT    = 19908096;  // 4M floats = 8M ushort: WHL [N][2K] interleaved
constexpr long OFF_PARTS = 24102400;  // 4718592 floats nominal; qkv(sk4)/o(sk8) parts
                                      // spill into OFF_GHL (ghHL dead at those points);
                                      // ALSO rows 4096.. of gate|up B-panel (parts dead)
constexpr long OFF_GHL   = 28820992;  // 4M floats: silu-out hl (layer) / xp hl (dec)
// total 33015296

typedef __attribute__((ext_vector_type(8))) short short8;
typedef __attribute__((ext_vector_type(4))) float floatx4;

// ---- helpers ----
__device__ __forceinline__ float geluf(float x) {
    // tanh-gelu via fast exp: tanh(u) = 1 - 2/(e^{2u}+1) (branchless, inf-safe)
    float u = 0.7978845608028654f * (x + 0.044715f * x * x * x);
    float e = __expf(2.f * u);
    float t = 1.f - 2.f / (e + 1.f);
    return 0.5f * x * (1.f + t);
}
__device__ __forceinline__ float sigmf(float x) { return 1.f / (1.f + expf(-x)); }

// fp32 -> bf16 hi/lo split (truncation; x ~= hi + lo, err ~2^-17 rel)
__device__ __forceinline__ void cvt_hilo(float x, unsigned short& h, unsigned short& l) {
    unsigned u = __float_as_uint(x);
    h = (unsigned short)(u >> 16);
    float r = x - __uint_as_float(u & 0xffff0000u);
    l = (unsigned short)(__float_as_uint(r) >> 16);
}

// async global->LDS, 16B per lane (dest = wave-uniform base + lane*16)
typedef const __attribute__((address_space(1))) unsigned int* gas_p;
typedef __attribute__((address_space(3))) unsigned int* las_p;
__device__ __forceinline__ void gload16(const unsigned short* g, unsigned short* l) {
    __builtin_amdgcn_global_load_lds((gas_p)g, (las_p)l, 16, 0, 0);
}

// block (256 threads) sum reduce; red must be __shared__ float[4]
__device__ __forceinline__ float blk_sum256(float v, float* red) {
    for (int o = 32; o > 0; o >>= 1) v += __shfl_down(v, o);
    int lane = threadIdx.x & 63, w = threadIdx.x >> 6;
    if (lane == 0) red[w] = v;
    __syncthreads();
    float r = red[0] + red[1] + red[2] + red[3];
    __syncthreads();
    return r;
}

// ---- encoder A-operand: emb padded to 384 rows, interleaved hi|lo ----
__global__ void k_emb_pad(const float* __restrict__ emb, unsigned short* __restrict__ EA) {
    int i = blockIdx.x * blockDim.x + threadIdx.x;
    if (i >= 384 * 1024) return;
    int r = i >> 10, d = i & 1023;
    float v = (r < Vn) ? emb[r * 1024 + d] : 0.f;
    unsigned short hh, ll;
    cvt_hilo(v, hh, ll);
    EA[(long)r * 2048 + d] = hh;
    EA[(long)r * 2048 + 1024 + d] = ll;
}

// ---- encoder B-operand: WB[n=o*3+dk][k] = w1[o][k][dk], interleaved hi|lo ----
__global__ void k_wconv_w1(const float* __restrict__ w1, unsigned short* __restrict__ WB) {
    int i = blockIdx.x * blockDim.x + threadIdx.x;
    if (i >= 1536 * 1024) return;
    int n = i >> 10, k = i & 1023;
    float v = w1[(n / 3) * 3072 + k * 3 + (n % 3)];
    unsigned short hh, ll;
    cvt_hilo(v, hh, ll);
    WB[(long)n * 2048 + k] = hh;
    WB[(long)n * 2048 + 1024 + k] = ll;
}

// ---- reduce EW splitK=8 partials and remap [v][o*3+dk] -> [dk][v][o] ----
__global__ void k_ewred(const float* __restrict__ parts, float* __restrict__ EW) {
    int i = blockIdx.x * blockDim.x + threadIdx.x;
    if (i >= 3 * Vn * DHn) return;
    int dk = i / (Vn * DHn);
    int rem = i - dk * (Vn * DHn);
    int v = rem >> 9, o = rem & 511;
    long src = (long)v * 1536 + o * 3 + dk;
    float s = 0.f;
    constexpr long MN = 384L * 1536;
    #pragma unroll
    for (int c = 0; c < 8; c++) s += parts[c * MN + src];
    EW[i] = s;
}

// ---- K1: per (b,t): h1 column via EW lookups + gelu, reduce to 3 dots with w2 ----
__global__ void k_conv1(const int* __restrict__ tok, const float* __restrict__ EW,
                        const float* __restrict__ b1, const float* __restrict__ w2,
                        float* __restrict__ cA, float* __restrict__ cB, float* __restrict__ cC) {
    int wave = threadIdx.x >> 6, lane = threadIdx.x & 63;
    int gidx = blockIdx.x * 4 + wave;     // b*T + t
    int b = gidx / Tn, t = gidx - b * Tn;
    int tk  = tok[b * Tn + t];
    int tkm = (t > 0)      ? tok[b * Tn + t - 1] : -1;
    int tkp = (t < Tn - 1) ? tok[b * Tn + t + 1] : -1;
    const float* E0 = EW;
    const float* E1 = EW + (long)Vn * DHn;
    const float* E2 = EW + 2L * Vn * DHn;
    float a0 = 0.f, a1 = 0.f, a2 = 0.f;
    #pragma unroll
    for (int u = 0; u < DHn / 64; u++) {
        int o = lane + u * 64;
        float s = b1[o] + E1[tk * DHn + o];
        if (tkm >= 0) s += E0[tkm * DHn + o];
        if (tkp >= 0) s += E2[tkp * DHn + o];
        float hg = geluf(s);
        a0 += hg * w2[o * 3 + 0];
        a1 += hg * w2[o * 3 + 1];
        a2 += hg * w2[o * 3 + 2];
    }
    for (int o = 32; o > 0; o >>= 1) {
        a0 += __shfl_down(a0, o); a1 += __shfl_down(a1, o); a2 += __shfl_down(a2, o);
    }
    if (lane == 0) { cA[gidx] = a0; cB[gidx] = a1; cC[gidx] = a2; }
}

// ---- K2: lg per token -> per-patch softmax -> ent, idx ----
__global__ void k_patchstats(const float* __restrict__ cA, const float* __restrict__ cB,
                             const float* __restrict__ cC, const float* __restrict__ b2,
                             float* __restrict__ ent_out, int* __restrict__ idx_out) {
    int pid = blockIdx.x * blockDim.x + threadIdx.x;   // b*P + p
    if (pid >= Bn * Pn) return;
    int b = pid / Pn, p = pid - b * Pn;
    float lgv[SEGn];
    float m = -3.4e38f;
    for (int s = 0; s < SEGn; s++) {
        int t = p * SEGn + s;
        float v = b2[0] + cB[b * Tn + t];
        if (t > 0)      v += cA[b * Tn + t - 1];
        if (t < Tn - 1) v += cC[b * Tn + t + 1];
        lgv[s] = v; m = fmaxf(m, v);
    }
    float Z = 0.f;
    for (int s = 0; s < SEGn; s++) { lgv[s] = expf(lgv[s] - m); Z += lgv[s]; }
    float inv = 1.f / Z;
    float bp = 0.f, en = 0.f;
    for (int s = 0; s < SEGn; s++) {
        float w = lgv[s] * inv;
        bp += w * (float)(p * SEGn + s);
        en -= w * logf(fmaxf(w, 1e-8f));
    }
    en *= (1.f / 2.772588722239781f);   // / ln(16)
    ent_out[pid] = en;
    int ix = (int)bp;
    ix = ix < 0 ? 0 : (ix > Tn - 1 ? Tn - 1 : ix);
    idx_out[pid] = ix;
}

// ---- K3: xp[b,p,:] = rmsnorm(emb[tok[b, idx[b,p]]], enc_norm_w). block per row ----
__global__ void k_xp(const int* __restrict__ tok, const int* __restrict__ idx,
                     const float* __restrict__ emb, const float* __restrict__ nw,
                     float* __restrict__ xp) {
    int pid = blockIdx.x;
    int b = pid / Pn;
    int tk = tok[b * Tn + idx[pid]];
    const float* row = emb + (long)tk * Dn;
    __shared__ float red[4];
    float v[4]; float ss = 0.f;
    #pragma unroll
    for (int j = 0; j < 4; j++) { v[j] = row[threadIdx.x + j * 256]; ss += v[j] * v[j]; }
    ss = blk_sum256(ss, red);
    float sc = 1.f / sqrtf(ss * (1.f / Dn) + 1e-6f);
    #pragma unroll
    for (int j = 0; j < 4; j++) {
        int d = threadIdx.x + j * 256;
        xp[(long)pid * Dn + d] = v[j] * sc * nw[d];
    }
}

// ---- K4: rl[b,p] = xp[b,p,:]·rw + ent. block per row ----
__global__ void k_router(const float* __restrict__ xp, const float* __restrict__ rw,
                         const float* __restrict__ ent, float* __restrict__ rl) {
    int pid = blockIdx.x;
    const float* xr = xp + (long)pid * Dn;
    __shared__ float red[4];
    float s = 0.f;
    #pragma unroll
    for (int j = 0; j < 4; j++) { int d = threadIdx.x + j * 256; s += xr[d] * rw[d]; }
    s = blk_sum256(s, red);
    if (threadIdx.x == 0) rl[pid] = s + ent[pid];
}

// ---- K5: exact top-k (KC of P) with jax tie semantics, output ascending by index ----
__global__ void k_topk(const float* __restrict__ rl, int* __restrict__ sel, float* __restrict__ g) {
    int b = blockIdx.x, p = threadIdx.x;
    __shared__ float vals[Pn];
    __shared__ int flag[Pn];
    float v = rl[b * Pn + p];
    vals[p] = v;
    __syncthreads();
    int rank = 0;
    for (int q = 0; q < Pn; q++) {
        float vq = vals[q];
        rank += (vq > v || (vq == v && q < p)) ? 1 : 0;
    }
    int selected = rank < KCn ? 1 : 0;
    flag[p] = selected;
    __syncthreads();
    if (selected) {
        int pos = 0;
        for (int q = 0; q < p; q++) pos += flag[q];
        sel[b * KCn + pos] = p;
        g[b * KCn + pos] = sigmf(v);
    }
}

// ---- K6: gather xs = xp[b, sel]; h = rmsnorm(xs, ln1) emitted interleaved hi|lo ----
__global__ void k_gather_ln1(const float* __restrict__ xp, const int* __restrict__ sel,
                             const float* __restrict__ w, float* __restrict__ xs,
                             unsigned short* __restrict__ hHL) {
    int r = blockIdx.x;            // b*KC + j
    int b = r / KCn;
    int p = sel[r];
    const float* src = xp + ((long)b * Pn + p) * Dn;
    __shared__ float red[4];
    float v[4]; float ss = 0.f;
    #pragma unroll
    for (int j = 0; j < 4; j++) { v[j] = src[threadIdx.x + j * 256]; ss += v[j] * v[j]; }
    ss = blk_sum256(ss, red);
    float sc = 1.f / sqrtf(ss * (1.f / Dn) + 1e-6f);
    #pragma unroll
    for (int j = 0; j < 4; j++) {
        int d = threadIdx.x + j * 256;
        xs[(long)r * Dn + d] = v[j];
        unsigned short hh, ll;
        cvt_hilo(v[j] * sc * w[d], hh, ll);
        hHL[(long)r * 2048 + d] = hh;
        hHL[(long)r * 2048 + 1024 + d] = ll;
    }
}

// ---- weight convert+transpose core: W[K][N] fp32 -> WHL[roff+n][2K] hi|lo ----
__device__ __forceinline__ void wconv_body(const float* __restrict__ Wm,
                                           unsigned short* __restrict__ Whl,
                                           int K, int N, int roff, int n0, int k0) {
    __shared__ float t[32][33];
    int tx = threadIdx.x & 31, ty = threadIdx.x >> 5;
    #pragma unroll
    for (int r = 0; r < 4; r++) {
        int k = k0 + ty + 8 * r, n = n0 + tx;
        t[ty + 8 * r][tx] = (n < N) ? Wm[(long)k * N + n] : 0.f;
    }
    __syncthreads();
    long K2 = 2L * K;
    #pragma unroll
    for (int r = 0; r < 4; r++) {
        int n = n0 + ty + 8 * r, k = k0 + tx;
        float v = t[tx][ty + 8 * r];
        unsigned short hh, ll;
        cvt_hilo(v, hh, ll);
        Whl[(long)(roff + n) * K2 + k] = hh;
        Whl[(long)(roff + n) * K2 + K + k] = ll;
    }
}

// grid (ceil(N/32), K/32), block 256
__global__ void k_wconv(const float* __restrict__ Wm, unsigned short* __restrict__ Whl,
                        int K, int N, int roff) {
    wconv_body(Wm, Whl, K, N, roff, blockIdx.x * 32, blockIdx.y * 32);
}

// two equal-N panels stacked: rows 0..Nh-1 = A, Nh..2Nh-1 = B. grid (2*Nh/32, K/32)
__global__ void k_wconv2(const float* __restrict__ Wa, const float* __restrict__ Wb,
                         unsigned short* __restrict__ Whl, int K, int Nh) {
    int nb = Nh >> 5;
    int bx = blockIdx.x;
    const float* src = (bx < nb) ? Wa : Wb;
    int xb = (bx < nb) ? bx : bx - nb;
    int roff = (bx < nb) ? 0 : Nh;
    wconv_body(src, Whl, K, Nh, roff, xb * 32, blockIdx.y * 32);
}

// q|k|v panels: rows 0..1023 = q_w, 1024..1279 = k_w, 1280..1535 = v_w. grid (48,32)
__global__ void k_wconv_qkv(const float* __restrict__ qw, const float* __restrict__ kw,
                            const float* __restrict__ vw, unsigned short* __restrict__ Whl) {
    int bx = blockIdx.x;
    const float* src; int xb, roff, Nsrc;
    if (bx < 32)      { src = qw; xb = bx;      roff = 0;    Nsrc = 1024; }
    else if (bx < 40) { src = kw; xb = bx - 32; roff = 1024; Nsrc = 256; }
    else              { src = vw; xb = bx - 40; roff = 1280; Nsrc = 256; }
    wconv_body(src, Whl, 1024, Nsrc, roff, xb * 32, blockIdx.y * 32);
}

// ---- elementwise fp32 -> interleaved hi|lo rows of 1024 ----
__global__ void k_xcvt(const float* __restrict__ src, unsigned short* __restrict__ dhl, int n) {
    int i = blockIdx.x * blockDim.x + threadIdx.x;
    if (i >= n) return;
    int r = i >> 10, d = i & 1023;
    unsigned short hh, ll;
    cvt_hilo(src[i], hh, ll);
    dhl[(long)r * 2048 + d] = hh;
    dhl[(long)r * 2048 + 1024 + d] = ll;
}

// ---- MFMA GEMM on interleaved hi|lo operands. A[M][2K], B[N][2K] ushort rows.
//      2-phase pipeline: double-buffered LDS; stage tile ks+1 via global_load_lds
//      BEFORE computing tile ks; single __syncthreads per K-step (implicit
//      vmcnt(0)+barrier drains AFTER the MFMA cluster -> flight overlaps compute).
//      XOR chunk swizzle on source+read (rule #21).
// grid (ceil(N/128), M/128, splitK), block 256. splitK>1 -> parts; else C(+bias).
// M%128==0, (K/splitK)%32==0. NOTE: keep total blocks <= 512 (2 blocks/CU
// residency) or an exact multiple — 544 blocks cost a +53% tail (R4 proj).
__global__ __launch_bounds__(256, 2) void k_mfma3(
        const unsigned short* __restrict__ Ag, const unsigned short* __restrict__ Bg,
        float* __restrict__ Cmat, const float* __restrict__ bias,
        int M, int N, int K, int splitK, float* __restrict__ parts) {
    __shared__ alignas(16) unsigned short As[2][128 * 64], Bs[2][128 * 64];
    int tid = threadIdx.x;
    int m0 = blockIdx.y * 128, n0 = blockIdx.x * 128;
    int kc = blockIdx.z;
    int Kc = K / splitK, kbase = kc * Kc, KT = Kc >> 5;
    int lane = tid & 63, wid = tid >> 6;
    int wm = (wid & 1) * 64, wn = (wid >> 1) * 64;
    int quad = lane >> 4, l16 = lane & 15;

    // staging geometry: 16 segments of 1KB per tile (4 per wave); lane L covers
    // row seg*8 + (L>>3), LDS slot L&7, which must hold logical chunk (L&7)^(row&7).
    int srow8 = lane >> 3;
    int spos  = lane & 7;
    int cch   = spos ^ srow8;                       // row&7 == srow8 for every segment
    long K2 = 2L * K;
    long coff = (cch < 4) ? (long)(cch * 8) : (long)K + (long)((cch - 4) * 8);
    const unsigned short* Aseg = Ag + (long)(m0 + srow8) * K2 + coff;
    const unsigned short* Bseg = Bg + (long)(n0 + srow8) * K2 + coff;   // OOB rows (pad) read garbage, never stored

    floatx4 acc[4][4];
    #pragma unroll
    for (int i = 0; i < 4; i++)
        #pragma unroll
        for (int j = 0; j < 4; j++) acc[i][j] = (floatx4){0.f, 0.f, 0.f, 0.f};

    auto stagef = [&](unsigned short* Ad, unsigned short* Bd, long kb) {
        #pragma unroll
        for (int t = 0; t < 4; t++) {
            int sa = wid * 4 + t;
            gload16(Aseg + (long)sa * 8 * K2 + kb, Ad + sa * 512);
            gload16(Bseg + (long)sa * 8 * K2 + kb, Bd + sa * 512);
        }
    };

    int ph = quad ^ (l16 & 7);                      // hi-chunk slot; lo = ph^4
    stagef(As[0], Bs[0], kbase);
    __syncthreads();                                // tile 0 resident
    int cur = 0;
    for (int ks = 0; ks < KT; ks++) {
        if (ks + 1 < KT)                            // prefetch next tile into other buf
            stagef(As[cur ^ 1], Bs[cur ^ 1], kbase + (long)(ks + 1) * 32);

        const unsigned short* Ac = As[cur];
        const unsigned short* Bc = Bs[cur];
        short8 ah[4], al2[4], bh[4], bl2[4];
        #pragma unroll
        for (int i = 0; i < 4; i++) {
            int r = wm + i * 16 + l16;
            ah[i]  = *(const short8*)&Ac[r * 64 + ph * 8];
            al2[i] = *(const short8*)&Ac[r * 64 + (ph ^ 4) * 8];
        }
        #pragma unroll
        for (int j = 0; j < 4; j++) {
            int c = wn + j * 16 + l16;
            bh[j]  = *(const short8*)&Bc[c * 64 + ph * 8];
            bl2[j] = *(const short8*)&Bc[c * 64 + (ph ^ 4) * 8];
        }
        #pragma unroll
        for (int i = 0; i < 4; i++)
            #pragma unroll
            for (int j = 0; j < 4; j++) {
                acc[i][j] = __builtin_amdgcn_mfma_f32_16x16x32_bf16(ah[i],  bh[j],  acc[i][j], 0, 0, 0);
                acc[i][j] = __builtin_amdgcn_mfma_f32_16x16x32_bf16(ah[i],  bl2[j], acc[i][j], 0, 0, 0);
                acc[i][j] = __builtin_amdgcn_mfma_f32_16x16x32_bf16(al2[i], bh[j],  acc[i][j], 0, 0, 0);
            }
        __syncthreads();   // drains this iter's prefetch (vmcnt0) + WAR protection
        cur ^= 1;
    }

    // epilogue: C/D layout col=lane&15, row=quad*4+reg (m89/m91)
    long MN = (long)M * N;
    #pragma unroll
    for (int j = 0; j < 4; j++) {
        int n = n0 + wn + j * 16 + l16;
        if (n >= N) continue;
        float bvx = bias ? bias[n] : 0.f;
        #pragma unroll
        for (int i = 0; i < 4; i++) {
            int mb = m0 + wm + i * 16 + quad * 4;
            #pragma unroll
            for (int r = 0; r < 4; r++) {
                if (splitK > 1) parts[kc * MN + (long)(mb + r) * N + n] = acc[i][j][r];
                else            Cmat[(long)(mb + r) * N + n] = acc[i][j][r] + bvx;
            }
        }
    }
}

// ---- reduce splitK partials (+optional bias) ----
__global__ void k_reduce(const float* __restrict__ parts, float* __restrict__ out,
                         const float* __restrict__ bias, long MN, int sk, int N) {
    long i = (long)blockIdx.x * blockDim.x + threadIdx.x;
    if (i >= MN) return;
    float s = 0.f;
    for (int c = 0; c < sk; c++) s += parts[c * MN + i];
    if (bias) s += bias[(int)(i % N)];
    out[i] = s;
}

// ---- fused QKV finish: sum splitK=4 parts + RoPE (q heads 0-15, k slots 16-19,
//      v slots 20-23 pass-through). block per row (B*KC), 256 thr, 768 pairs ----
__global__ void k_qkv_finish(const float* __restrict__ parts, const int* __restrict__ sel,
                             float* __restrict__ qkv) {
    int r = blockIdx.x;
    int pos = sel[r];
    constexpr long MN = 1024L * 1536;
    #pragma unroll
    for (int it = 0; it < 3; it++) {
        int pp = threadIdx.x + it * 256;          // 0..767
        int head = pp >> 5, d = pp & 31;
        long c1 = (long)r * 1536 + head * 64 + d;
        float s1 = 0.f, s2 = 0.f;
        #pragma unroll
        for (int c = 0; c < 4; c++) {
            s1 += parts[c * MN + c1];
            s2 += parts[c * MN + c1 + 32];
        }
        if (head < 20) {
            float theta = powf(10000.f, -(float)(2 * d) / 64.f);
            float ang = (float)pos * theta;
            float cc = cosf(ang), ssn = sinf(ang);
            qkv[c1]      = s1 * cc - s2 * ssn;
            qkv[c1 + 32] = s2 * cc + s1 * ssn;
        } else {
            qkv[c1] = s1; qkv[c1 + 32] = s2;
        }
    }
}

// ---- MFMA flash attention; fused qkv buffer (row stride 1536: q cols 0..1023,
//      k cols 1024..1279, v cols 1280..1535); epilogue emits aout hi|lo ----
constexpr int APS = 72;
__global__ __launch_bounds__(256) void k_attn(const float* __restrict__ qkv,
                       unsigned short* __restrict__ aoHL) {
    int bx = blockIdx.x, h = blockIdx.y, b = blockIdx.z;
    int hk = h >> 2;
    int qb0 = bx * 64;
    int tid = threadIdx.x, lane = tid & 63, wid = tid >> 6;
    int quad = lane >> 4, l16 = lane & 15;
    __shared__ alignas(16) unsigned short LdsA[9216], LdsB[9216];
    unsigned short* Kh = LdsA;          unsigned short* Kl = LdsB;
    unsigned short* Ph = LdsA;          unsigned short* Pl = LdsB;
    unsigned short* Vth = LdsA + 4608;  unsigned short* Vtl = LdsB + 4608;

    int qrow = qb0 + wid * 16 + l16;
    short8 qh[2], ql[2];
    #pragma unroll
    for (int ks = 0; ks < 2; ks++) {
        const float* qp = qkv + ((long)(b * KCn + qrow)) * 1536 + h * HDn + ks * 32 + quad * 8;
        float tmp[8];
        *(float4*)tmp = *(const float4*)qp;
        *(float4*)(tmp + 4) = *(const float4*)(qp + 4);
        #pragma unroll
        for (int j = 0; j < 8; j++) {
            unsigned short hh, ll;
            cvt_hilo(tmp[j], hh, ll);
            qh[ks][j] = (short)hh; ql[ks][j] = (short)ll;
        }
    }

    floatx4 sacc[16];
    #pragma unroll
    for (int t = 0; t < 16; t++) sacc[t] = (floatx4){0.f, 0.f, 0.f, 0.f};

    int qmax = qb0 + 63;
    int nkc = qmax / 128 + 1;
    for (int kc = 0; kc < nkc; kc++) {
        __syncthreads();
        {
            int r = tid >> 1, dh = (tid & 1) * 32;
            const float* kp = qkv + ((long)(b * KCn + kc * 128 + r)) * 1536 + 1024 + hk * HDn + dh;
            #pragma unroll
            for (int f = 0; f < 8; f++) {
                float tmp[4];
                *(float4*)tmp = *(const float4*)(kp + f * 4);
                unsigned short h0, h1, h2, h3, l0, l1, l2, l3;
                cvt_hilo(tmp[0], h0, l0); cvt_hilo(tmp[1], h1, l1);
                cvt_hilo(tmp[2], h2, l2); cvt_hilo(tmp[3], h3, l3);
                *(ushort4*)&Kh[r * APS + dh + f * 4] = make_ushort4(h0, h1, h2, h3);
                *(ushort4*)&Kl[r * APS + dh + f * 4] = make_ushort4(l0, l1, l2, l3);
            }
        }
        __syncthreads();
        #pragma unroll
        for (int tj = 0; tj < 8; tj++) {
            int kr = tj * 16 + l16;
            int gt = kc * 8 + tj;
            #pragma unroll
            for (int ks = 0; ks < 2; ks++) {
                short8 bh0 = *(const short8*)&Kh[kr * APS + ks * 32 + quad * 8];
                short8 bl0 = *(const short8*)&Kl[kr * APS + ks * 32 + quad * 8];
                sacc[gt] = __builtin_amdgcn_mfma_f32_16x16x32_bf16(qh[ks], bh0, sacc[gt], 0, 0, 0);
                sacc[gt] = __builtin_amdgcn_mfma_f32_16x16x32_bf16(qh[ks], bl0, sacc[gt], 0, 0, 0);
                sacc[gt] = __builtin_amdgcn_mfma_f32_16x16x32_bf16(ql[ks], bh0, sacc[gt], 0, 0, 0);
            }
        }
    }

    float rowinv[4];
    #pragma unroll
    for (int r = 0; r < 4; r++) {
        int qg = qb0 + wid * 16 + quad * 4 + r;
        float mm = -3.4e38f;
        #pragma unroll
        for (int t = 0; t < 16; t++) {
            int key = t * 16 + l16;
            float s = (key <= qg) ? sacc[t][r] * 0.125f : -1e30f;
            sacc[t][r] = s;
            mm = fmaxf(mm, s);
        }
        #pragma unroll
        for (int o = 1; o < 16; o <<= 1) mm = fmaxf(mm, __shfl_xor(mm, o));
        float zz = 0.f;
        #pragma unroll
        for (int t = 0; t < 16; t++) {
            float e = expf(sacc[t][r] - mm);
            sacc[t][r] = e; zz += e;
        }
        #pragma unroll
        for (int o = 1; o < 16; o <<= 1) zz += __shfl_xor(zz, o);
        rowinv[r] = 1.f / zz;
    }

    floatx4 oacc[4];
    #pragma unroll
    for (int dt = 0; dt < 4; dt++) oacc[dt] = (floatx4){0.f, 0.f, 0.f, 0.f};
    int npv = qmax / 64 + 1;
    for (int c4 = 0; c4 < npv; c4++) {
        __syncthreads();
        {
            #pragma unroll
            for (int it = 0; it < 4; it++) {
                int task = tid + 256 * it;
                int kloc = task & 63, d4 = (task >> 6) * 4;
                float tmp[4];
                *(float4*)tmp = *(const float4*)(qkv + ((long)(b * KCn + c4 * 64 + kloc)) * 1536 + 1280 + hk * HDn + d4);
                #pragma unroll
                for (int i = 0; i < 4; i++) {
                    unsigned short hh, ll;
                    cvt_hilo(tmp[i], hh, ll);
                    Vth[(d4 + i) * APS + kloc] = hh;
                    Vtl[(d4 + i) * APS + kloc] = ll;
                }
            }
        }
        #pragma unroll
        for (int tt = 0; tt < 4; tt++) {
            int t = c4 * 4 + tt;
            #pragma unroll
            for (int r = 0; r < 4; r++) {
                int row = wid * 16 + quad * 4 + r;
                float pv2 = sacc[t][r] * rowinv[r];
                unsigned short hh, ll;
                cvt_hilo(pv2, hh, ll);
                Ph[row * APS + tt * 16 + l16] = hh;
                Pl[row * APS + tt * 16 + l16] = ll;
            }
        }
        __syncthreads();
        short8 pah[2], pal[2];
        #pragma unroll
        for (int ks = 0; ks < 2; ks++) {
            pah[ks] = *(const short8*)&Ph[(wid * 16 + l16) * APS + ks * 32 + quad * 8];
            pal[ks] = *(const short8*)&Pl[(wid * 16 + l16) * APS + ks * 32 + quad * 8];
        }
        #pragma unroll
        for (int dt = 0; dt < 4; dt++) {
            #pragma unroll
            for (int ks = 0; ks < 2; ks++) {
                short8 vbh = *(const short8*)&Vth[(dt * 16 + l16) * APS + ks * 32 + quad * 8];
                short8 vbl = *(const short8*)&Vtl[(dt * 16 + l16) * APS + ks * 32 + quad * 8];
                oacc[dt] = __builtin_amdgcn_mfma_f32_16x16x32_bf16(pah[ks], vbh, oacc[dt], 0, 0, 0);
                oacc[dt] = __builtin_amdgcn_mfma_f32_16x16x32_bf16(pah[ks], vbl, oacc[dt], 0, 0, 0);
                oacc[dt] = __builtin_amdgcn_mfma_f32_16x16x32_bf16(pal[ks], vbh, oacc[dt], 0, 0, 0);
            }
        }
    }

    #pragma unroll
    for (int dt = 0; dt < 4; dt++) {
        #pragma unroll
        for (int r = 0; r < 4; r++) {
            int row = qb0 + wid * 16 + quad * 4 + r;
            long base = ((long)(b * KCn + row)) * 2048 + h * HDn + dt * 16 + l16;
            unsigned short hh, ll;
            cvt_hilo(oacc[dt][r], hh, ll);
            aoHL[base] = hh; aoHL[base + 1024] = ll;
        }
    }
}

// ---- fused: ao = reduce(O splitK=8 parts); x2 = xs + ao; h2 = rmsnorm hi|lo ----
__global__ void k_add_ln2_red(const float* __restrict__ parts, const float* __restrict__ xs,
                              const float* __restrict__ w, float* __restrict__ ao,
                              unsigned short* __restrict__ h2HL) {
    int r = blockIdx.x;
    constexpr long MN = 1024L * 1024;
    __shared__ float red[4];
    float v[4]; float ss = 0.f;
    #pragma unroll
    for (int j = 0; j < 4; j++) {
        int d = threadIdx.x + j * 256;
        long i = (long)r * Dn + d;
        float a = 0.f;
        #pragma unroll
        for (int c = 0; c < 8; c++) a += parts[c * MN + i];
        ao[i] = a;
        float x = xs[i] + a;
        v[j] = x; ss += x * x;
    }
    ss = blk_sum256(ss, red);
    float sc = 1.f / sqrtf(ss * (1.f / Dn) + 1e-6f);
    #pragma unroll
    for (int j = 0; j < 4; j++) {
        int d = threadIdx.x + j * 256;
        unsigned short hh, ll;
        cvt_hilo(v[j] * sc * w[d], hh, ll);
        h2HL[(long)r * 2048 + d] = hh;
        h2HL[(long)r * 2048 + 1024 + d] = ll;
    }
}

// ---- silu(gate)*up on fused C (row stride 8192: gate 0..4095, up 4096..8191) ----
__global__ void k_silu_mul(const float* __restrict__ C, unsigned short* __restrict__ ghl, int n) {
    int i = blockIdx.x * blockDim.x + threadIdx.x;
    if (i < n) {
        int r = i >> 12, c = i & 4095;
        float x = C[(long)r * 8192 + c];
        float u = C[(long)r * 8192 + 4096 + c];
        unsigned short hh, ll;
        cvt_hilo(x * sigmf(x) * u, hh, ll);
        ghl[(long)r * 8192 + c] = hh;
        ghl[(long)r * 8192 + 4096 + c] = ll;
    }
}

// ---- fused: ff = reduce(down splitK=4 parts); xp[b, sel[b,j], :] += g*(ao+ff) ----
__global__ void k_scatter_red(float* __restrict__ xp, const float* __restrict__ ao,
                              const float* __restrict__ parts, const float* __restrict__ g,
                              const int* __restrict__ sel) {
    int r = blockIdx.x;
    int b = r / KCn;
    int p = sel[r];
    float gg = g[r];
    constexpr long MN = 1024L * 1024;
    float* dst = xp + ((long)b * Pn + p) * Dn;
    #pragma unroll
    for (int j = 0; j < 4; j++) {
        int d = threadIdx.x + j * 256;
        long i = (long)r * Dn + d;
        float f = 0.f;
        #pragma unroll
        for (int c = 0; c < 4; c++) f += parts[c * MN + i];
        dst[d] += gg * (ao[i] + f);
    }
}

// ---- fused decoder norm: hmlp row = sum of mlp1 splitK=4 parts + b1;
//      win = sigmoid(gelu(hmlp)@w2[:,s]+b2[s]); y = rmsnorm(proj*win, w) hi|lo.
//      proj C row stride 4096 (cols s*1024..). block per (bp,s) ----
__global__ void k_dec_norm_win(const float* __restrict__ projC, const float* __restrict__ mparts,
                               const float* __restrict__ b1, const float* __restrict__ w2,
                               const float* __restrict__ b2, const float* __restrict__ w,
                               unsigned short* __restrict__ yHL) {
    int r = blockIdx.x;            // bp*4 + s
    int bp = r >> 2, s = r & 3;
    constexpr long MN = 2048L * 256;
    __shared__ float red[4];
    long hi = (long)bp * 256 + threadIdx.x;
    float hv = b1[threadIdx.x];
    #pragma unroll
    for (int c = 0; c < 4; c++) hv += mparts[c * MN + hi];
    float acc = geluf(hv) * w2[threadIdx.x * 4 + s];
    acc = blk_sum256(acc, red);
    float wv = sigmf(acc + b2[s]);
    const float* pr = projC + (long)bp * 4096 + s * 1024;
    float v[4]; float ss = 0.f;
    #pragma unroll
    for (int j = 0; j < 4; j++) {
        int d = threadIdx.x + j * 256;
        float x = pr[d] * wv;
        v[j] = x; ss += x * x;
    }
    ss = blk_sum256(ss, red);
    float sc = 1.f / sqrtf(ss * (1.f / Dn) + 1e-6f);
    #pragma unroll
    for (int j = 0; j < 4; j++) {
        int d = threadIdx.x + j * 256;
        unsigned short hh, ll;
        cvt_hilo(v[j] * sc * w[d], hh, ll);
        yHL[(long)r * 2048 + d] = hh;
        yHL[(long)r * 2048 + 1024 + d] = ll;
    }
}

extern "C" void kernel_launch(void* const* d_in, const int* in_sizes, int n_in,
                              void* d_out, int out_size, void* d_ws, size_t ws_size,
                              hipStream_t stream) {
    const int*   tokens     = (const int*)  d_in[0];
    const float* emb        = (const float*)d_in[1];
    const float* bp_w1      = (const float*)d_in[2];
    const float* bp_b1      = (const float*)d_in[3];
    const float* bp_w2      = (const float*)d_in[4];
    const float* bp_b2      = (const float*)d_in[5];
    const float* enc_norm_w = (const float*)d_in[6];
    const float* router_w   = (const float*)d_in[7];
    const float* ln1_w      = (const float*)d_in[8];
    const float* ln2_w      = (const float*)d_in[9];
    const float* q_w        = (const float*)d_in[10];
    const float* k_w        = (const float*)d_in[11];
    const float* v_w        = (const float*)d_in[12];
    const float* o_w        = (const float*)d_in[13];
    const float* gate_w     = (const float*)d_in[14];
    const float* up_w       = (const float*)d_in[15];
    const float* down_w     = (const float*)d_in[16];
    const float* dec_proj_w = (const float*)d_in[17];
    const float* dec_proj_b = (const float*)d_in[18];
    const float* dec_mlp_w1 = (const float*)d_in[19];
    const float* dec_mlp_b1 = (const float*)d_in[20];
    const float* dec_mlp_w2 = (const float*)d_in[21];
    const float* dec_mlp_b2 = (const float*)d_in[22];
    const float* dec_norm_w = (const float*)d_in[23];
    const float* head_w     = (const float*)d_in[24];
    float* out = (float*)d_out;

    float* W = (float*)d_ws;
    float* EW   = W + OFF_EW;
    float* cA   = W + OFF_CA;
    float* cB   = W + OFF_CB;
    float* cC   = W + OFF_CC;
    float* ent  = W + OFF_ENT;
    int*   idxb = (int*)(W + OFF_IDX);
    float* xp   = W + OFF_XP;
    float* rl   = W + OFF_RL;
    int*   sel  = (int*)(W + OFF_SEL);
    float* g    = W + OFF_G;
    float* scr  = W + SCR;
    float* xs   = scr + SC_XS;
    unsigned short* hHL   = (unsigned short*)(scr + SC_H);
    float* qkv  = scr + SC_QKV;
    unsigned short* aoutHL = (unsigned short*)(scr + SC_AOUT);
    float* ao   = scr + SC_AO;
    unsigned short* h2HL  = (unsigned short*)(scr + SC_H2);
    float* gupC = scr + SC_GU;
    float* projC= scr + SC_PROJ;
    unsigned short* yHL   = (unsigned short*)(scr + SC_Y);
    unsigned short* EA    = (unsigned short*)(scr + SC_EA);   // encoder only
    unsigned short* WB    = (unsigned short*)(scr + SC_WB);   // encoder only
    unsigned short* WHL   = (unsigned short*)(W + OFF_WT);
    float* parts = W + OFF_PARTS;
    unsigned short* ghHL  = (unsigned short*)(W + OFF_GHL);   // layer: silu-out hl
    unsigned short* xpHL  = (unsigned short*)(W + OFF_GHL);   // decoder: xp hl

    // byte-patch encoder: EW via MFMA hi/lo GEMM (M=384 pad, N=1536, K=1024, sk=8:
    // 288 blocks, one residency round; parts = 8*589824 = 4718592 floats exactly)
    k_emb_pad<<<1536, 256, 0, stream>>>(emb, EA);
    k_wconv_w1<<<6144, 256, 0, stream>>>(bp_w1, WB);
    k_mfma3<<<dim3(12, 3, 8), 256, 0, stream>>>(EA, WB, nullptr, nullptr, 384, 1536, 1024, 8, parts);
    k_ewred<<<1542, 256, 0, stream>>>(parts, EW);
    k_conv1<<<Bn * Tn / 4, 256, 0, stream>>>(tokens, EW, bp_b1, bp_w2, cA, cB, cC);
    k_patchstats<<<(Bn * Pn + 255) / 256, 256, 0, stream>>>(cA, cB, cC, bp_b2, ent, idxb);
    k_xp<<<Bn * Pn, 256, 0, stream>>>(tokens, idxb, emb, enc_norm_w, xp);

    for (int l = 0; l < Ln; l++) {
        k_router<<<Bn * Pn, 256, 0, stream>>>(xp, router_w + (long)l * Dn, ent, rl);
        k_topk<<<Bn, Pn, 0, stream>>>(rl, sel, g);
        k_gather_ln1<<<Bn * KCn, 256, 0, stream>>>(xp, sel, ln1_w + (long)l * Dn, xs, hHL);

        // fused Q|K|V GEMM, splitK=4 (384 blocks, one round; parts 6.29M floats
        // spill into OFF_GHL — ghHL dead here, prev layer's consumed by down GEMM)
        k_wconv_qkv<<<dim3(48, 32), 256, 0, stream>>>(q_w + (long)l * Dn * Dn,
                                                      k_w + (long)l * Dn * 256,
                                                      v_w + (long)l * Dn * 256, WHL);
        k_mfma3<<<dim3(12, 8, 4), 256, 0, stream>>>(hHL, WHL, nullptr, nullptr, 1024, 1536, 1024, 4, parts);
        k_qkv_finish<<<Bn * KCn, 256, 0, stream>>>(parts, sel, qkv);

        k_attn<<<dim3(4, NHn, Bn), 256, 0, stream>>>(qkv, aoutHL);

        // O GEMM splitK=8 (512 blocks = exactly 2/CU; parts 8M floats spill into
        // OFF_GHL — still dead until silu_mul below)
        k_wconv<<<dim3(32, 32), 256, 0, stream>>>(o_w + (long)l * Dn * Dn, WHL, 1024, 1024, 0);
        k_mfma3<<<dim3(8, 8, 8), 256, 0, stream>>>(aoutHL, WHL, nullptr, nullptr, 1024, 1024, 1024, 8, parts);
        k_add_ln2_red<<<Bn * KCn, 256, 0, stream>>>(parts, xs, ln2_w + (long)l * Dn, ao, h2HL);

        // fused gate|up GEMM: B rows 0..4095 = gate, 4096..8191 = up (tail spans
        // PARTS — o parts consumed by add_ln2_red above)
        k_wconv2<<<dim3(256, 32), 256, 0, stream>>>(gate_w + (long)l * Dn * FFn,
                                                    up_w + (long)l * Dn * FFn, WHL, 1024, 4096);
        k_mfma3<<<dim3(64, 8, 1), 256, 0, stream>>>(h2HL, WHL, gupC, nullptr, 1024, 8192, 1024, 1, parts);

        k_silu_mul<<<(Bn * KCn * FFn + 255) / 256, 256, 0, stream>>>(gupC, ghHL, Bn * KCn * FFn);

        // down GEMM splitK=4 (parts 4M floats — must NOT spill into OFF_GHL: ghHL
        // is this GEMM's A operand)
        k_wconv<<<dim3(32, 128), 256, 0, stream>>>(down_w + (long)l * FFn * Dn, WHL, 4096, 1024, 0);
        k_mfma3<<<dim3(8, 8, 4), 256, 0, stream>>>(ghHL, WHL, nullptr, nullptr, 1024, 1024, 4096, 4, parts);
        k_scatter_red<<<Bn * KCn, 256, 0, stream>>>(xp, ao, parts, g, sel);
    }

    // decoder: proj GEMM N=4096 (512 blocks — exact pack, no tail; R4's N=4352 =
    // 544 blocks cost +53% tail), mlp1 GEMM splitK=4, fused win+norm reads parts
    k_xcvt<<<8192, 256, 0, stream>>>(xp, xpHL, 2097152);
    k_wconv<<<dim3(128, 32), 256, 0, stream>>>(dec_proj_w, WHL, 1024, 4096, 0);
    k_mfma3<<<dim3(32, 16, 1), 256, 0, stream>>>(xpHL, WHL, projC, dec_proj_b, 2048, 4096, 1024, 1, parts);
    k_wconv<<<dim3(8, 32), 256, 0, stream>>>(dec_mlp_w1, WHL, 1024, 256, 0);
    k_mfma3<<<dim3(2, 16, 4), 256, 0, stream>>>(xpHL, WHL, nullptr, nullptr, 2048, 256, 1024, 4, parts);
    k_dec_norm_win<<<Bn * Pn * Sn, 256, 0, stream>>>(projC, parts, dec_mlp_b1, dec_mlp_w2, dec_mlp_b2, dec_norm_w, yHL);
    k_wconv<<<dim3(9, 32), 256, 0, stream>>>(head_w, WHL, 1024, 257, 0);
    k_mfma3<<<dim3(3, 64, 2), 256, 0, stream>>>(yHL, WHL, nullptr, nullptr, 8192, 257, 1024, 2, parts);
    k_reduce<<<8224, 256, 0, stream>>>(parts, out, nullptr, 2105344, 2, 257);
}

// Round 6
// 1415.286 us; speedup vs baseline: 1.2680x; 1.0156x over previous
//
#include <hip/hip_runtime.h>
#include <hip/hip_bf16.h>
#include <math.h>

// ---- model dims ----
constexpr int Bn  = 4;
constexpr int Tn  = 8192;
constexpr int Dn  = 1024;
constexpr int Pn  = 512;
constexpr int SEGn= 16;     // T/P
constexpr int Sn  = 4;
constexpr int Ln  = 4;
constexpr int NHn = 16;
constexpr int NKVn= 4;
constexpr int HDn = 64;
constexpr int FFn = 4096;
constexpr int KCn = 256;
constexpr int Vn  = 257;
constexpr int DHn = 512;    // conv hidden (D/2)

// ---- workspace layout (float elements). total = 33,015,296 floats = 126 MB ----
constexpr long OFF_EW  = 0;                       // 3*257*512 = 394752
constexpr long OFF_CA  = 394752;                  // B*T
constexpr long OFF_CB  = 427520;
constexpr long OFF_CC  = 460288;
constexpr long OFF_ENT = 493056;                  // B*P
constexpr long OFF_IDX = 495104;                  // B*P (int)
constexpr long OFF_XP  = 497152;                  // B*P*D = 2097152
constexpr long OFF_RL  = 2594304;                 // B*P
constexpr long OFF_SEL = 2596352;                 // B*KC (int)
constexpr long OFF_G   = 2597376;                 // B*KC
constexpr long SCR     = 2598400;
// layer-phase scratch (offsets relative to SCR):
constexpr long SC_XS   = 0;         // 1048576
constexpr long SC_H    = 1048576;   // 1048576 (interleaved hi|lo ushort rows)
constexpr long SC_QKV  = 2097152;   // 1572864 floats = 3.1M ushort: per-row 3072
                                    // ushort [qh1024|ql1024|kh256|kl256|vh256|vl256]
constexpr long SC_AOUT = 3670016;   // 1048576 (hi|lo)
constexpr long SC_AO   = 4718592;   // 1048576
constexpr long SC_H2   = 5767168;   // 1048576 (hi|lo)
constexpr long SC_GU   = 6815744;   // 8388608 (fused gate|up C, row stride 8192;
                                    //          ALSO down GEMM's sk=8 parts after silu)
// decoder-phase (overlays layer region):
constexpr long SC_PROJ = 0;         // 8388608 (proj C, row stride 4096)
constexpr long SC_Y    = 8921088;   // 8388608 (hi|lo: 8192 rows x 2048 ushort)
// encoder-phase temporaries (overlay scr, used before layer loop):
constexpr long SC_EA   = 0;         // 384*2048 ushort = 393216 floats
constexpr long SC_WB   = 524288;    // 1536*2048 ushort = 1572864 floats
// new regions (absolute float offsets in ws):
constexpr long OFF_WT    = 19908096;  // 4M floats = 8M ushort: WHL [N][2K] interleaved
constexpr long OFF_PARTS = 24102400;  // 4718592 floats nominal; qkv(sk4)/o(sk8) parts
                                      // spill into OFF_GHL (ghHL dead at those points);
                                      // ALSO rows 4096.. of gate|up B-panel (parts dead)
constexpr long OFF_GHL   = 28820992;  // 4M floats: silu-out hl (layer) / xp hl (dec)
// total 33015296

typedef __attribute__((ext_vector_type(8))) short short8;
typedef __attribute__((ext_vector_type(4))) float floatx4;

// ---- helpers ----
__device__ __forceinline__ float geluf(float x) {
    // tanh-gelu via fast exp: tanh(u) = 1 - 2/(e^{2u}+1) (branchless, inf-safe)
    float u = 0.7978845608028654f * (x + 0.044715f * x * x * x);
    float e = __expf(2.f * u);
    float t = 1.f - 2.f / (e + 1.f);
    return 0.5f * x * (1.f + t);
}
__device__ __forceinline__ float sigmf(float x) { return 1.f / (1.f + expf(-x)); }

// fp32 -> bf16 hi/lo split (truncation; x ~= hi + lo, err ~2^-17 rel)
__device__ __forceinline__ void cvt_hilo(float x, unsigned short& h, unsigned short& l) {
    unsigned u = __float_as_uint(x);
    h = (unsigned short)(u >> 16);
    float r = x - __uint_as_float(u & 0xffff0000u);
    l = (unsigned short)(__float_as_uint(r) >> 16);
}

// async global->LDS, 16B per lane (dest = wave-uniform base + lane*16)
typedef const __attribute__((address_space(1))) unsigned int* gas_p;
typedef __attribute__((address_space(3))) unsigned int* las_p;
__device__ __forceinline__ void gload16(const unsigned short* g, unsigned short* l) {
    __builtin_amdgcn_global_load_lds((gas_p)g, (las_p)l, 16, 0, 0);
}

// block (256 threads) sum reduce; red must be __shared__ float[4]
__device__ __forceinline__ float blk_sum256(float v, float* red) {
    for (int o = 32; o > 0; o >>= 1) v += __shfl_down(v, o);
    int lane = threadIdx.x & 63, w = threadIdx.x >> 6;
    if (lane == 0) red[w] = v;
    __syncthreads();
    float r = red[0] + red[1] + red[2] + red[3];
    __syncthreads();
    return r;
}

// ---- encoder A-operand: emb padded to 384 rows, interleaved hi|lo ----
__global__ void k_emb_pad(const float* __restrict__ emb, unsigned short* __restrict__ EA) {
    int i = blockIdx.x * blockDim.x + threadIdx.x;
    if (i >= 384 * 1024) return;
    int r = i >> 10, d = i & 1023;
    float v = (r < Vn) ? emb[r * 1024 + d] : 0.f;
    unsigned short hh, ll;
    cvt_hilo(v, hh, ll);
    EA[(long)r * 2048 + d] = hh;
    EA[(long)r * 2048 + 1024 + d] = ll;
}

// ---- encoder B-operand: WB[n=o*3+dk][k] = w1[o][k][dk], interleaved hi|lo ----
__global__ void k_wconv_w1(const float* __restrict__ w1, unsigned short* __restrict__ WB) {
    int i = blockIdx.x * blockDim.x + threadIdx.x;
    if (i >= 1536 * 1024) return;
    int n = i >> 10, k = i & 1023;
    float v = w1[(n / 3) * 3072 + k * 3 + (n % 3)];
    unsigned short hh, ll;
    cvt_hilo(v, hh, ll);
    WB[(long)n * 2048 + k] = hh;
    WB[(long)n * 2048 + 1024 + k] = ll;
}

// ---- reduce EW splitK=8 partials and remap [v][o*3+dk] -> [dk][v][o] ----
__global__ void k_ewred(const float* __restrict__ parts, float* __restrict__ EW) {
    int i = blockIdx.x * blockDim.x + threadIdx.x;
    if (i >= 3 * Vn * DHn) return;
    int dk = i / (Vn * DHn);
    int rem = i - dk * (Vn * DHn);
    int v = rem >> 9, o = rem & 511;
    long src = (long)v * 1536 + o * 3 + dk;
    float s = 0.f;
    constexpr long MN = 384L * 1536;
    #pragma unroll
    for (int c = 0; c < 8; c++) s += parts[c * MN + src];
    EW[i] = s;
}

// ---- K1: per (b,t): h1 column via EW lookups + gelu, reduce to 3 dots with w2 ----
__global__ void k_conv1(const int* __restrict__ tok, const float* __restrict__ EW,
                        const float* __restrict__ b1, const float* __restrict__ w2,
                        float* __restrict__ cA, float* __restrict__ cB, float* __restrict__ cC) {
    int wave = threadIdx.x >> 6, lane = threadIdx.x & 63;
    int gidx = blockIdx.x * 4 + wave;     // b*T + t
    int b = gidx / Tn, t = gidx - b * Tn;
    int tk  = tok[b * Tn + t];
    int tkm = (t > 0)      ? tok[b * Tn + t - 1] : -1;
    int tkp = (t < Tn - 1) ? tok[b * Tn + t + 1] : -1;
    const float* E0 = EW;
    const float* E1 = EW + (long)Vn * DHn;
    const float* E2 = EW + 2L * Vn * DHn;
    float a0 = 0.f, a1 = 0.f, a2 = 0.f;
    #pragma unroll
    for (int u = 0; u < DHn / 64; u++) {
        int o = lane + u * 64;
        float s = b1[o] + E1[tk * DHn + o];
        if (tkm >= 0) s += E0[tkm * DHn + o];
        if (tkp >= 0) s += E2[tkp * DHn + o];
        float hg = geluf(s);
        a0 += hg * w2[o * 3 + 0];
        a1 += hg * w2[o * 3 + 1];
        a2 += hg * w2[o * 3 + 2];
    }
    for (int o = 32; o > 0; o >>= 1) {
        a0 += __shfl_down(a0, o); a1 += __shfl_down(a1, o); a2 += __shfl_down(a2, o);
    }
    if (lane == 0) { cA[gidx] = a0; cB[gidx] = a1; cC[gidx] = a2; }
}

// ---- K2: lg per token -> per-patch softmax -> ent, idx ----
__global__ void k_patchstats(const float* __restrict__ cA, const float* __restrict__ cB,
                             const float* __restrict__ cC, const float* __restrict__ b2,
                             float* __restrict__ ent_out, int* __restrict__ idx_out) {
    int pid = blockIdx.x * blockDim.x + threadIdx.x;   // b*P + p
    if (pid >= Bn * Pn) return;
    int b = pid / Pn, p = pid - b * Pn;
    float lgv[SEGn];
    float m = -3.4e38f;
    for (int s = 0; s < SEGn; s++) {
        int t = p * SEGn + s;
        float v = b2[0] + cB[b * Tn + t];
        if (t > 0)      v += cA[b * Tn + t - 1];
        if (t < Tn - 1) v += cC[b * Tn + t + 1];
        lgv[s] = v; m = fmaxf(m, v);
    }
    float Z = 0.f;
    for (int s = 0; s < SEGn; s++) { lgv[s] = expf(lgv[s] - m); Z += lgv[s]; }
    float inv = 1.f / Z;
    float bp = 0.f, en = 0.f;
    for (int s = 0; s < SEGn; s++) {
        float w = lgv[s] * inv;
        bp += w * (float)(p * SEGn + s);
        en -= w * logf(fmaxf(w, 1e-8f));
    }
    en *= (1.f / 2.772588722239781f);   // / ln(16)
    ent_out[pid] = en;
    int ix = (int)bp;
    ix = ix < 0 ? 0 : (ix > Tn - 1 ? Tn - 1 : ix);
    idx_out[pid] = ix;
}

// ---- K3: xp[b,p,:] = rmsnorm(emb[tok[b, idx[b,p]]], enc_norm_w). block per row ----
__global__ void k_xp(const int* __restrict__ tok, const int* __restrict__ idx,
                     const float* __restrict__ emb, const float* __restrict__ nw,
                     float* __restrict__ xp) {
    int pid = blockIdx.x;
    int b = pid / Pn;
    int tk = tok[b * Tn + idx[pid]];
    const float* row = emb + (long)tk * Dn;
    __shared__ float red[4];
    float v[4]; float ss = 0.f;
    #pragma unroll
    for (int j = 0; j < 4; j++) { v[j] = row[threadIdx.x + j * 256]; ss += v[j] * v[j]; }
    ss = blk_sum256(ss, red);
    float sc = 1.f / sqrtf(ss * (1.f / Dn) + 1e-6f);
    #pragma unroll
    for (int j = 0; j < 4; j++) {
        int d = threadIdx.x + j * 256;
        xp[(long)pid * Dn + d] = v[j] * sc * nw[d];
    }
}

// ---- K4: rl[b,p] = xp[b,p,:]·rw + ent. block per row ----
__global__ void k_router(const float* __restrict__ xp, const float* __restrict__ rw,
                         const float* __restrict__ ent, float* __restrict__ rl) {
    int pid = blockIdx.x;
    const float* xr = xp + (long)pid * Dn;
    __shared__ float red[4];
    float s = 0.f;
    #pragma unroll
    for (int j = 0; j < 4; j++) { int d = threadIdx.x + j * 256; s += xr[d] * rw[d]; }
    s = blk_sum256(s, red);
    if (threadIdx.x == 0) rl[pid] = s + ent[pid];
}

// ---- K5: exact top-k (KC of P) with jax tie semantics, output ascending by index ----
__global__ void k_topk(const float* __restrict__ rl, int* __restrict__ sel, float* __restrict__ g) {
    int b = blockIdx.x, p = threadIdx.x;
    __shared__ float vals[Pn];
    __shared__ int flag[Pn];
    float v = rl[b * Pn + p];
    vals[p] = v;
    __syncthreads();
    int rank = 0;
    for (int q = 0; q < Pn; q++) {
        float vq = vals[q];
        rank += (vq > v || (vq == v && q < p)) ? 1 : 0;
    }
    int selected = rank < KCn ? 1 : 0;
    flag[p] = selected;
    __syncthreads();
    if (selected) {
        int pos = 0;
        for (int q = 0; q < p; q++) pos += flag[q];
        sel[b * KCn + pos] = p;
        g[b * KCn + pos] = sigmf(v);
    }
}

// ---- K6: gather xs = xp[b, sel]; h = rmsnorm(xs, ln1) emitted interleaved hi|lo ----
__global__ void k_gather_ln1(const float* __restrict__ xp, const int* __restrict__ sel,
                             const float* __restrict__ w, float* __restrict__ xs,
                             unsigned short* __restrict__ hHL) {
    int r = blockIdx.x;            // b*KC + j
    int b = r / KCn;
    int p = sel[r];
    const float* src = xp + ((long)b * Pn + p) * Dn;
    __shared__ float red[4];
    float v[4]; float ss = 0.f;
    #pragma unroll
    for (int j = 0; j < 4; j++) { v[j] = src[threadIdx.x + j * 256]; ss += v[j] * v[j]; }
    ss = blk_sum256(ss, red);
    float sc = 1.f / sqrtf(ss * (1.f / Dn) + 1e-6f);
    #pragma unroll
    for (int j = 0; j < 4; j++) {
        int d = threadIdx.x + j * 256;
        xs[(long)r * Dn + d] = v[j];
        unsigned short hh, ll;
        cvt_hilo(v[j] * sc * w[d], hh, ll);
        hHL[(long)r * 2048 + d] = hh;
        hHL[(long)r * 2048 + 1024 + d] = ll;
    }
}

// ---- weight convert+transpose core: W[K][N] fp32 -> WHL[roff+n][2K] hi|lo ----
__device__ __forceinline__ void wconv_body(const float* __restrict__ Wm,
                                           unsigned short* __restrict__ Whl,
                                           int K, int N, int roff, int n0, int k0) {
    __shared__ float t[32][33];
    int tx = threadIdx.x & 31, ty = threadIdx.x >> 5;
    #pragma unroll
    for (int r = 0; r < 4; r++) {
        int k = k0 + ty + 8 * r, n = n0 + tx;
        t[ty + 8 * r][tx] = (n < N) ? Wm[(long)k * N + n] : 0.f;
    }
    __syncthreads();
    long K2 = 2L * K;
    #pragma unroll
    for (int r = 0; r < 4; r++) {
        int n = n0 + ty + 8 * r, k = k0 + tx;
        float v = t[tx][ty + 8 * r];
        unsigned short hh, ll;
        cvt_hilo(v, hh, ll);
        Whl[(long)(roff + n) * K2 + k] = hh;
        Whl[(long)(roff + n) * K2 + K + k] = ll;
    }
}

// grid (ceil(N/32), K/32), block 256
__global__ void k_wconv(const float* __restrict__ Wm, unsigned short* __restrict__ Whl,
                        int K, int N, int roff) {
    wconv_body(Wm, Whl, K, N, roff, blockIdx.x * 32, blockIdx.y * 32);
}

// two equal-N panels stacked: rows 0..Nh-1 = A, Nh..2Nh-1 = B. grid (2*Nh/32, K/32)
__global__ void k_wconv2(const float* __restrict__ Wa, const float* __restrict__ Wb,
                         unsigned short* __restrict__ Whl, int K, int Nh) {
    int nb = Nh >> 5;
    int bx = blockIdx.x;
    const float* src = (bx < nb) ? Wa : Wb;
    int xb = (bx < nb) ? bx : bx - nb;
    int roff = (bx < nb) ? 0 : Nh;
    wconv_body(src, Whl, K, Nh, roff, xb * 32, blockIdx.y * 32);
}

// q|k|v panels: rows 0..1023 = q_w, 1024..1279 = k_w, 1280..1535 = v_w. grid (48,32)
__global__ void k_wconv_qkv(const float* __restrict__ qw, const float* __restrict__ kw,
                            const float* __restrict__ vw, unsigned short* __restrict__ Whl) {
    int bx = blockIdx.x;
    const float* src; int xb, roff, Nsrc;
    if (bx < 32)      { src = qw; xb = bx;      roff = 0;    Nsrc = 1024; }
    else if (bx < 40) { src = kw; xb = bx - 32; roff = 1024; Nsrc = 256; }
    else              { src = vw; xb = bx - 40; roff = 1280; Nsrc = 256; }
    wconv_body(src, Whl, 1024, Nsrc, roff, xb * 32, blockIdx.y * 32);
}

// ---- elementwise fp32 -> interleaved hi|lo rows of 1024 ----
__global__ void k_xcvt(const float* __restrict__ src, unsigned short* __restrict__ dhl, int n) {
    int i = blockIdx.x * blockDim.x + threadIdx.x;
    if (i >= n) return;
    int r = i >> 10, d = i & 1023;
    unsigned short hh, ll;
    cvt_hilo(src[i], hh, ll);
    dhl[(long)r * 2048 + d] = hh;
    dhl[(long)r * 2048 + 1024 + d] = ll;
}

// ---- MFMA GEMM on interleaved hi|lo operands. A[M][2K], B[N][2K] ushort rows.
//      2-phase pipeline: double-buffered LDS; stage tile ks+1 via global_load_lds
//      BEFORE computing tile ks; single __syncthreads per K-step (implicit
//      vmcnt(0)+barrier drains AFTER the MFMA cluster -> flight overlaps compute).
//      XOR chunk swizzle on source+read (rule #21).
// grid (ceil(N/128), M/128, splitK), block 256. splitK>1 -> parts; else C(+bias).
// M%128==0, (K/splitK)%32==0. NOTE: keep total blocks <= 512 (2 blocks/CU
// residency) or an exact multiple — 544 blocks cost a +53% tail (R4 proj).
__global__ __launch_bounds__(256, 2) void k_mfma3(
        const unsigned short* __restrict__ Ag, const unsigned short* __restrict__ Bg,
        float* __restrict__ Cmat, const float* __restrict__ bias,
        int M, int N, int K, int splitK, float* __restrict__ parts) {
    __shared__ alignas(16) unsigned short As[2][128 * 64], Bs[2][128 * 64];
    int tid = threadIdx.x;
    int m0 = blockIdx.y * 128, n0 = blockIdx.x * 128;
    int kc = blockIdx.z;
    int Kc = K / splitK, kbase = kc * Kc, KT = Kc >> 5;
    int lane = tid & 63, wid = tid >> 6;
    int wm = (wid & 1) * 64, wn = (wid >> 1) * 64;
    int quad = lane >> 4, l16 = lane & 15;

    // staging geometry: 16 segments of 1KB per tile (4 per wave); lane L covers
    // row seg*8 + (L>>3), LDS slot L&7, which must hold logical chunk (L&7)^(row&7).
    int srow8 = lane >> 3;
    int spos  = lane & 7;
    int cch   = spos ^ srow8;                       // row&7 == srow8 for every segment
    long K2 = 2L * K;
    long coff = (cch < 4) ? (long)(cch * 8) : (long)K + (long)((cch - 4) * 8);
    const unsigned short* Aseg = Ag + (long)(m0 + srow8) * K2 + coff;
    const unsigned short* Bseg = Bg + (long)(n0 + srow8) * K2 + coff;   // OOB rows (pad) read garbage, never stored

    floatx4 acc[4][4];
    #pragma unroll
    for (int i = 0; i < 4; i++)
        #pragma unroll
        for (int j = 0; j < 4; j++) acc[i][j] = (floatx4){0.f, 0.f, 0.f, 0.f};

    auto stagef = [&](unsigned short* Ad, unsigned short* Bd, long kb) {
        #pragma unroll
        for (int t = 0; t < 4; t++) {
            int sa = wid * 4 + t;
            gload16(Aseg + (long)sa * 8 * K2 + kb, Ad + sa * 512);
            gload16(Bseg + (long)sa * 8 * K2 + kb, Bd + sa * 512);
        }
    };

    int ph = quad ^ (l16 & 7);                      // hi-chunk slot; lo = ph^4
    stagef(As[0], Bs[0], kbase);
    __syncthreads();                                // tile 0 resident
    int cur = 0;
    for (int ks = 0; ks < KT; ks++) {
        if (ks + 1 < KT)                            // prefetch next tile into other buf
            stagef(As[cur ^ 1], Bs[cur ^ 1], kbase + (long)(ks + 1) * 32);

        const unsigned short* Ac = As[cur];
        const unsigned short* Bc = Bs[cur];
        short8 ah[4], al2[4], bh[4], bl2[4];
        #pragma unroll
        for (int i = 0; i < 4; i++) {
            int r = wm + i * 16 + l16;
            ah[i]  = *(const short8*)&Ac[r * 64 + ph * 8];
            al2[i] = *(const short8*)&Ac[r * 64 + (ph ^ 4) * 8];
        }
        #pragma unroll
        for (int j = 0; j < 4; j++) {
            int c = wn + j * 16 + l16;
            bh[j]  = *(const short8*)&Bc[c * 64 + ph * 8];
            bl2[j] = *(const short8*)&Bc[c * 64 + (ph ^ 4) * 8];
        }
        #pragma unroll
        for (int i = 0; i < 4; i++)
            #pragma unroll
            for (int j = 0; j < 4; j++) {
                acc[i][j] = __builtin_amdgcn_mfma_f32_16x16x32_bf16(ah[i],  bh[j],  acc[i][j], 0, 0, 0);
                acc[i][j] = __builtin_amdgcn_mfma_f32_16x16x32_bf16(ah[i],  bl2[j], acc[i][j], 0, 0, 0);
                acc[i][j] = __builtin_amdgcn_mfma_f32_16x16x32_bf16(al2[i], bh[j],  acc[i][j], 0, 0, 0);
            }
        __syncthreads();   // drains this iter's prefetch (vmcnt0) + WAR protection
        cur ^= 1;
    }

    // epilogue: C/D layout col=lane&15, row=quad*4+reg (m89/m91)
    long MN = (long)M * N;
    #pragma unroll
    for (int j = 0; j < 4; j++) {
        int n = n0 + wn + j * 16 + l16;
        if (n >= N) continue;
        float bvx = bias ? bias[n] : 0.f;
        #pragma unroll
        for (int i = 0; i < 4; i++) {
            int mb = m0 + wm + i * 16 + quad * 4;
            #pragma unroll
            for (int r = 0; r < 4; r++) {
                if (splitK > 1) parts[kc * MN + (long)(mb + r) * N + n] = acc[i][j][r];
                else            Cmat[(long)(mb + r) * N + n] = acc[i][j][r] + bvx;
            }
        }
    }
}

// ---- reduce splitK partials (+optional bias) ----
__global__ void k_reduce(const float* __restrict__ parts, float* __restrict__ out,
                         const float* __restrict__ bias, long MN, int sk, int N) {
    long i = (long)blockIdx.x * blockDim.x + threadIdx.x;
    if (i >= MN) return;
    float s = 0.f;
    for (int c = 0; c < sk; c++) s += parts[c * MN + i];
    if (bias) s += bias[(int)(i % N)];
    out[i] = s;
}

// ---- fused QKV finish: sum splitK=4 parts + RoPE (q heads 0-15, k slots 16-19,
//      v slots 20-23) -> hi/lo ushort rows of 3072: [qh|ql|kh|kl|vh|vl].
//      block per row (B*KC), 256 thr, 768 pairs ----
__global__ void k_qkv_finish(const float* __restrict__ parts, const int* __restrict__ sel,
                             unsigned short* __restrict__ qkvHL) {
    int r = blockIdx.x;
    int pos = sel[r];
    constexpr long MN = 1024L * 1536;
    #pragma unroll
    for (int it = 0; it < 3; it++) {
        int pp = threadIdx.x + it * 256;          // 0..767
        int head = pp >> 5, d = pp & 31;
        long c1 = (long)r * 1536 + head * 64 + d;
        float s1 = 0.f, s2 = 0.f;
        #pragma unroll
        for (int c = 0; c < 4; c++) {
            s1 += parts[c * MN + c1];
            s2 += parts[c * MN + c1 + 32];
        }
        float o1, o2;
        if (head < 20) {
            float theta = powf(10000.f, -(float)(2 * d) / 64.f);
            float ang = (float)pos * theta;
            float cc = cosf(ang), ssn = sinf(ang);
            o1 = s1 * cc - s2 * ssn;
            o2 = s2 * cc + s1 * ssn;
        } else {
            o1 = s1; o2 = s2;
        }
        // section offsets in the 3072-ushort row
        long hb, lb; int dloc;
        if (head < 16)      { hb = 0;    lb = 1024; dloc = head * 64 + d; }
        else if (head < 20) { hb = 2048; lb = 2304; dloc = (head - 16) * 64 + d; }
        else                { hb = 2560; lb = 2816; dloc = (head - 20) * 64 + d; }
        long base = (long)r * 3072;
        unsigned short h1, l1, h2, l2;
        cvt_hilo(o1, h1, l1);
        cvt_hilo(o2, h2, l2);
        qkvHL[base + hb + dloc]      = h1;
        qkvHL[base + lb + dloc]      = l1;
        qkvHL[base + hb + dloc + 32] = h2;
        qkvHL[base + lb + dloc + 32] = l2;
    }
}

// ---- MFMA flash attention; qkvHL rows of 3072 ushort [qh|ql|kh|kl|vh|vl] —
//      all operands pre-split hi/lo, staging is pure copies (no cvt).
//      epilogue emits aout hi|lo ----
constexpr int APS = 72;
__global__ __launch_bounds__(256) void k_attn(const unsigned short* __restrict__ qkvHL,
                       unsigned short* __restrict__ aoHL) {
    int bx = blockIdx.x, h = blockIdx.y, b = blockIdx.z;
    int hk = h >> 2;
    int qb0 = bx * 64;
    int tid = threadIdx.x, lane = tid & 63, wid = tid >> 6;
    int quad = lane >> 4, l16 = lane & 15;
    __shared__ alignas(16) unsigned short LdsA[9216], LdsB[9216];
    unsigned short* Kh = LdsA;          unsigned short* Kl = LdsB;
    unsigned short* Ph = LdsA;          unsigned short* Pl = LdsB;
    unsigned short* Vth = LdsA + 4608;  unsigned short* Vtl = LdsB + 4608;

    int qrow = qb0 + wid * 16 + l16;
    short8 qh[2], ql[2];
    #pragma unroll
    for (int ks = 0; ks < 2; ks++) {
        const unsigned short* qp = qkvHL + ((long)(b * KCn + qrow)) * 3072 + h * HDn + ks * 32 + quad * 8;
        qh[ks] = *(const short8*)qp;
        ql[ks] = *(const short8*)(qp + 1024);
    }

    floatx4 sacc[16];
    #pragma unroll
    for (int t = 0; t < 16; t++) sacc[t] = (floatx4){0.f, 0.f, 0.f, 0.f};

    int qmax = qb0 + 63;
    int nkc = qmax / 128 + 1;
    for (int kc = 0; kc < nkc; kc++) {
        __syncthreads();
        {
            int r = tid >> 1, dh = (tid & 1) * 32;
            const unsigned short* kp = qkvHL + ((long)(b * KCn + kc * 128 + r)) * 3072 + 2048 + hk * HDn + dh;
            #pragma unroll
            for (int f = 0; f < 4; f++) {
                *(short8*)&Kh[r * APS + dh + f * 8] = *(const short8*)(kp + f * 8);
                *(short8*)&Kl[r * APS + dh + f * 8] = *(const short8*)(kp + 256 + f * 8);
            }
        }
        __syncthreads();
        #pragma unroll
        for (int tj = 0; tj < 8; tj++) {
            int kr = tj * 16 + l16;
            int gt = kc * 8 + tj;
            #pragma unroll
            for (int ks = 0; ks < 2; ks++) {
                short8 bh0 = *(const short8*)&Kh[kr * APS + ks * 32 + quad * 8];
                short8 bl0 = *(const short8*)&Kl[kr * APS + ks * 32 + quad * 8];
                sacc[gt] = __builtin_amdgcn_mfma_f32_16x16x32_bf16(qh[ks], bh0, sacc[gt], 0, 0, 0);
                sacc[gt] = __builtin_amdgcn_mfma_f32_16x16x32_bf16(qh[ks], bl0, sacc[gt], 0, 0, 0);
                sacc[gt] = __builtin_amdgcn_mfma_f32_16x16x32_bf16(ql[ks], bh0, sacc[gt], 0, 0, 0);
            }
        }
    }

    float rowinv[4];
    #pragma unroll
    for (int r = 0; r < 4; r++) {
        int qg = qb0 + wid * 16 + quad * 4 + r;
        float mm = -3.4e38f;
        #pragma unroll
        for (int t = 0; t < 16; t++) {
            int key = t * 16 + l16;
            float s = (key <= qg) ? sacc[t][r] * 0.125f : -1e30f;
            sacc[t][r] = s;
            mm = fmaxf(mm, s);
        }
        #pragma unroll
        for (int o = 1; o < 16; o <<= 1) mm = fmaxf(mm, __shfl_xor(mm, o));
        float zz = 0.f;
        #pragma unroll
        for (int t = 0; t < 16; t++) {
            float e = expf(sacc[t][r] - mm);
            sacc[t][r] = e; zz += e;
        }
        #pragma unroll
        for (int o = 1; o < 16; o <<= 1) zz += __shfl_xor(zz, o);
        rowinv[r] = 1.f / zz;
    }

    floatx4 oacc[4];
    #pragma unroll
    for (int dt = 0; dt < 4; dt++) oacc[dt] = (floatx4){0.f, 0.f, 0.f, 0.f};
    int npv = qmax / 64 + 1;
    for (int c4 = 0; c4 < npv; c4++) {
        __syncthreads();
        {
            #pragma unroll
            for (int it = 0; it < 4; it++) {
                int task = tid + 256 * it;
                int kloc = task & 63, d4 = (task >> 6) * 4;
                const unsigned short* vp = qkvHL + ((long)(b * KCn + c4 * 64 + kloc)) * 3072 + 2560 + hk * HDn + d4;
                ushort4 th = *(const ushort4*)vp;
                ushort4 tl = *(const ushort4*)(vp + 256);
                Vth[(d4 + 0) * APS + kloc] = th.x; Vtl[(d4 + 0) * APS + kloc] = tl.x;
                Vth[(d4 + 1) * APS + kloc] = th.y; Vtl[(d4 + 1) * APS + kloc] = tl.y;
                Vth[(d4 + 2) * APS + kloc] = th.z; Vtl[(d4 + 2) * APS + kloc] = tl.z;
                Vth[(d4 + 3) * APS + kloc] = th.w; Vtl[(d4 + 3) * APS + kloc] = tl.w;
            }
        }
        #pragma unroll
        for (int tt = 0; tt < 4; tt++) {
            int t = c4 * 4 + tt;
            #pragma unroll
            for (int r = 0; r < 4; r++) {
                int row = wid * 16 + quad * 4 + r;
                float pv2 = sacc[t][r] * rowinv[r];
                unsigned short hh, ll;
                cvt_hilo(pv2, hh, ll);
                Ph[row * APS + tt * 16 + l16] = hh;
                Pl[row * APS + tt * 16 + l16] = ll;
            }
        }
        __syncthreads();
        short8 pah[2], pal[2];
        #pragma unroll
        for (int ks = 0; ks < 2; ks++) {
            pah[ks] = *(const short8*)&Ph[(wid * 16 + l16) * APS + ks * 32 + quad * 8];
            pal[ks] = *(const short8*)&Pl[(wid * 16 + l16) * APS + ks * 32 + quad * 8];
        }
        #pragma unroll
        for (int dt = 0; dt < 4; dt++) {
            #pragma unroll
            for (int ks = 0; ks < 2; ks++) {
                short8 vbh = *(const short8*)&Vth[(dt * 16 + l16) * APS + ks * 32 + quad * 8];
                short8 vbl = *(const short8*)&Vtl[(dt * 16 + l16) * APS + ks * 32 + quad * 8];
                oacc[dt] = __builtin_amdgcn_mfma_f32_16x16x32_bf16(pah[ks], vbh, oacc[dt], 0, 0, 0);
                oacc[dt] = __builtin_amdgcn_mfma_f32_16x16x32_bf16(pah[ks], vbl, oacc[dt], 0, 0, 0);
                oacc[dt] = __builtin_amdgcn_mfma_f32_16x16x32_bf16(pal[ks], vbh, oacc[dt], 0, 0, 0);
            }
        }
    }

    #pragma unroll
    for (int dt = 0; dt < 4; dt++) {
        #pragma unroll
        for (int r = 0; r < 4; r++) {
            int row = qb0 + wid * 16 + quad * 4 + r;
            long base = ((long)(b * KCn + row)) * 2048 + h * HDn + dt * 16 + l16;
            unsigned short hh, ll;
            cvt_hilo(oacc[dt][r], hh, ll);
            aoHL[base] = hh; aoHL[base + 1024] = ll;
        }
    }
}

// ---- fused: ao = reduce(O splitK=8 parts); x2 = xs + ao; h2 = rmsnorm hi|lo ----
__global__ void k_add_ln2_red(const float* __restrict__ parts, const float* __restrict__ xs,
                              const float* __restrict__ w, float* __restrict__ ao,
                              unsigned short* __restrict__ h2HL) {
    int r = blockIdx.x;
    constexpr long MN = 1024L * 1024;
    __shared__ float red[4];
    float v[4]; float ss = 0.f;
    #pragma unroll
    for (int j = 0; j < 4; j++) {
        int d = threadIdx.x + j * 256;
        long i = (long)r * Dn + d;
        float a = 0.f;
        #pragma unroll
        for (int c = 0; c < 8; c++) a += parts[c * MN + i];
        ao[i] = a;
        float x = xs[i] + a;
        v[j] = x; ss += x * x;
    }
    ss = blk_sum256(ss, red);
    float sc = 1.f / sqrtf(ss * (1.f / Dn) + 1e-6f);
    #pragma unroll
    for (int j = 0; j < 4; j++) {
        int d = threadIdx.x + j * 256;
        unsigned short hh, ll;
        cvt_hilo(v[j] * sc * w[d], hh, ll);
        h2HL[(long)r * 2048 + d] = hh;
        h2HL[(long)r * 2048 + 1024 + d] = ll;
    }
}

// ---- silu(gate)*up on fused C (row stride 8192), float4-vectorized ----
__global__ void k_silu_mul(const float* __restrict__ C, unsigned short* __restrict__ ghl, int n4) {
    int i = blockIdx.x * blockDim.x + threadIdx.x;
    if (i >= n4) return;
    int i4 = i << 2;
    int r = i4 >> 12, c = i4 & 4095;
    float4 x = *(const float4*)&C[(long)r * 8192 + c];
    float4 u = *(const float4*)&C[(long)r * 8192 + 4096 + c];
    ushort4 oh, ol;
    unsigned short hh, ll;
    cvt_hilo(x.x * sigmf(x.x) * u.x, hh, ll); oh.x = hh; ol.x = ll;
    cvt_hilo(x.y * sigmf(x.y) * u.y, hh, ll); oh.y = hh; ol.y = ll;
    cvt_hilo(x.z * sigmf(x.z) * u.z, hh, ll); oh.z = hh; ol.z = ll;
    cvt_hilo(x.w * sigmf(x.w) * u.w, hh, ll); oh.w = hh; ol.w = ll;
    *(ushort4*)&ghl[(long)r * 8192 + c] = oh;
    *(ushort4*)&ghl[(long)r * 8192 + 4096 + c] = ol;
}

// ---- fused: ff = reduce(down splitK=8 parts); xp[b, sel[b,j], :] += g*(ao+ff) ----
__global__ void k_scatter_red(float* __restrict__ xp, const float* __restrict__ ao,
                              const float* __restrict__ parts, const float* __restrict__ g,
                              const int* __restrict__ sel) {
    int r = blockIdx.x;
    int b = r / KCn;
    int p = sel[r];
    float gg = g[r];
    constexpr long MN = 1024L * 1024;
    float* dst = xp + ((long)b * Pn + p) * Dn;
    #pragma unroll
    for (int j = 0; j < 4; j++) {
        int d = threadIdx.x + j * 256;
        long i = (long)r * Dn + d;
        float f = 0.f;
        #pragma unroll
        for (int c = 0; c < 8; c++) f += parts[c * MN + i];
        dst[d] += gg * (ao[i] + f);
    }
}

// ---- fused decoder norm: hmlp row = sum of mlp1 splitK=4 parts + b1;
//      win = sigmoid(gelu(hmlp)@w2[:,s]+b2[s]); y = rmsnorm(proj*win, w) hi|lo.
//      proj C row stride 4096 (cols s*1024..). block per (bp,s) ----
__global__ void k_dec_norm_win(const float* __restrict__ projC, const float* __restrict__ mparts,
                               const float* __restrict__ b1, const float* __restrict__ w2,
                               const float* __restrict__ b2, const float* __restrict__ w,
                               unsigned short* __restrict__ yHL) {
    int r = blockIdx.x;            // bp*4 + s
    int bp = r >> 2, s = r & 3;
    constexpr long MN = 2048L * 256;
    __shared__ float red[4];
    long hi = (long)bp * 256 + threadIdx.x;
    float hv = b1[threadIdx.x];
    #pragma unroll
    for (int c = 0; c < 4; c++) hv += mparts[c * MN + hi];
    float acc = geluf(hv) * w2[threadIdx.x * 4 + s];
    acc = blk_sum256(acc, red);
    float wv = sigmf(acc + b2[s]);
    const float* pr = projC + (long)bp * 4096 + s * 1024;
    float v[4]; float ss = 0.f;
    #pragma unroll
    for (int j = 0; j < 4; j++) {
        int d = threadIdx.x + j * 256;
        float x = pr[d] * wv;
        v[j] = x; ss += x * x;
    }
    ss = blk_sum256(ss, red);
    float sc = 1.f / sqrtf(ss * (1.f / Dn) + 1e-6f);
    #pragma unroll
    for (int j = 0; j < 4; j++) {
        int d = threadIdx.x + j * 256;
        unsigned short hh, ll;
        cvt_hilo(v[j] * sc * w[d], hh, ll);
        yHL[(long)r * 2048 + d] = hh;
        yHL[(long)r * 2048 + 1024 + d] = ll;
    }
}

extern "C" void kernel_launch(void* const* d_in, const int* in_sizes, int n_in,
                              void* d_out, int out_size, void* d_ws, size_t ws_size,
                              hipStream_t stream) {
    const int*   tokens     = (const int*)  d_in[0];
    const float* emb        = (const float*)d_in[1];
    const float* bp_w1      = (const float*)d_in[2];
    const float* bp_b1      = (const float*)d_in[3];
    const float* bp_w2      = (const float*)d_in[4];
    const float* bp_b2      = (const float*)d_in[5];
    const float* enc_norm_w = (const float*)d_in[6];
    const float* router_w   = (const float*)d_in[7];
    const float* ln1_w      = (const float*)d_in[8];
    const float* ln2_w      = (const float*)d_in[9];
    const float* q_w        = (const float*)d_in[10];
    const float* k_w        = (const float*)d_in[11];
    const float* v_w        = (const float*)d_in[12];
    const float* o_w        = (const float*)d_in[13];
    const float* gate_w     = (const float*)d_in[14];
    const float* up_w       = (const float*)d_in[15];
    const float* down_w     = (const float*)d_in[16];
    const float* dec_proj_w = (const float*)d_in[17];
    const float* dec_proj_b = (const float*)d_in[18];
    const float* dec_mlp_w1 = (const float*)d_in[19];
    const float* dec_mlp_b1 = (const float*)d_in[20];
    const float* dec_mlp_w2 = (const float*)d_in[21];
    const float* dec_mlp_b2 = (const float*)d_in[22];
    const float* dec_norm_w = (const float*)d_in[23];
    const float* head_w     = (const float*)d_in[24];
    float* out = (float*)d_out;

    float* W = (float*)d_ws;
    float* EW   = W + OFF_EW;
    float* cA   = W + OFF_CA;
    float* cB   = W + OFF_CB;
    float* cC   = W + OFF_CC;
    float* ent  = W + OFF_ENT;
    int*   idxb = (int*)(W + OFF_IDX);
    float* xp   = W + OFF_XP;
    float* rl   = W + OFF_RL;
    int*   sel  = (int*)(W + OFF_SEL);
    float* g    = W + OFF_G;
    float* scr  = W + SCR;
    float* xs   = scr + SC_XS;
    unsigned short* hHL   = (unsigned short*)(scr + SC_H);
    unsigned short* qkvHL = (unsigned short*)(scr + SC_QKV);
    unsigned short* aoutHL = (unsigned short*)(scr + SC_AOUT);
    float* ao   = scr + SC_AO;
    unsigned short* h2HL  = (unsigned short*)(scr + SC_H2);
    float* gupC = scr + SC_GU;
    float* projC= scr + SC_PROJ;
    unsigned short* yHL   = (unsigned short*)(scr + SC_Y);
    unsigned short* EA    = (unsigned short*)(scr + SC_EA);   // encoder only
    unsigned short* WB    = (unsigned short*)(scr + SC_WB);   // encoder only
    unsigned short* WHL   = (unsigned short*)(W + OFF_WT);
    float* parts = W + OFF_PARTS;
    unsigned short* ghHL  = (unsigned short*)(W + OFF_GHL);   // layer: silu-out hl
    unsigned short* xpHL  = (unsigned short*)(W + OFF_GHL);   // decoder: xp hl

    // byte-patch encoder: EW via MFMA hi/lo GEMM (M=384 pad, N=1536, K=1024, sk=8:
    // 288 blocks, one residency round; parts = 8*589824 = 4718592 floats exactly)
    k_emb_pad<<<1536, 256, 0, stream>>>(emb, EA);
    k_wconv_w1<<<6144, 256, 0, stream>>>(bp_w1, WB);
    k_mfma3<<<dim3(12, 3, 8), 256, 0, stream>>>(EA, WB, nullptr, nullptr, 384, 1536, 1024, 8, parts);
    k_ewred<<<1542, 256, 0, stream>>>(parts, EW);
    k_conv1<<<Bn * Tn / 4, 256, 0, stream>>>(tokens, EW, bp_b1, bp_w2, cA, cB, cC);
    k_patchstats<<<(Bn * Pn + 255) / 256, 256, 0, stream>>>(cA, cB, cC, bp_b2, ent, idxb);
    k_xp<<<Bn * Pn, 256, 0, stream>>>(tokens, idxb, emb, enc_norm_w, xp);

    for (int l = 0; l < Ln; l++) {
        k_router<<<Bn * Pn, 256, 0, stream>>>(xp, router_w + (long)l * Dn, ent, rl);
        k_topk<<<Bn, Pn, 0, stream>>>(rl, sel, g);
        k_gather_ln1<<<Bn * KCn, 256, 0, stream>>>(xp, sel, ln1_w + (long)l * Dn, xs, hHL);

        // fused Q|K|V GEMM, splitK=4 (384 blocks, one round; parts 6.29M floats
        // spill into OFF_GHL — ghHL dead here, prev layer's consumed by down GEMM)
        k_wconv_qkv<<<dim3(48, 32), 256, 0, stream>>>(q_w + (long)l * Dn * Dn,
                                                      k_w + (long)l * Dn * 256,
                                                      v_w + (long)l * Dn * 256, WHL);
        k_mfma3<<<dim3(12, 8, 4), 256, 0, stream>>>(hHL, WHL, nullptr, nullptr, 1024, 1536, 1024, 4, parts);
        k_qkv_finish<<<Bn * KCn, 256, 0, stream>>>(parts, sel, qkvHL);

        k_attn<<<dim3(4, NHn, Bn), 256, 0, stream>>>(qkvHL, aoutHL);

        // O GEMM splitK=8 (512 blocks = exactly 2/CU; parts 8M floats spill into
        // OFF_GHL — still dead until silu_mul below)
        k_wconv<<<dim3(32, 32), 256, 0, stream>>>(o_w + (long)l * Dn * Dn, WHL, 1024, 1024, 0);
        k_mfma3<<<dim3(8, 8, 8), 256, 0, stream>>>(aoutHL, WHL, nullptr, nullptr, 1024, 1024, 1024, 8, parts);
        k_add_ln2_red<<<Bn * KCn, 256, 0, stream>>>(parts, xs, ln2_w + (long)l * Dn, ao, h2HL);

        // fused gate|up GEMM: B rows 0..4095 = gate, 4096..8191 = up (tail spans
        // PARTS — o parts consumed by add_ln2_red above)
        k_wconv2<<<dim3(256, 32), 256, 0, stream>>>(gate_w + (long)l * Dn * FFn,
                                                    up_w + (long)l * Dn * FFn, WHL, 1024, 4096);
        k_mfma3<<<dim3(64, 8, 1), 256, 0, stream>>>(h2HL, WHL, gupC, nullptr, 1024, 8192, 1024, 1, parts);

        k_silu_mul<<<(Bn * KCn * FFn / 4 + 255) / 256, 256, 0, stream>>>(gupC, ghHL, Bn * KCn * FFn / 4);

        // down GEMM splitK=8 (512 blocks = 2/CU). parts -> gupC region (8.39M
        // floats, dead after silu_mul; NOT ghHL which is this GEMM's A operand)
        k_wconv<<<dim3(32, 128), 256, 0, stream>>>(down_w + (long)l * FFn * Dn, WHL, 4096, 1024, 0);
        k_mfma3<<<dim3(8, 8, 8), 256, 0, stream>>>(ghHL, WHL, nullptr, nullptr, 1024, 1024, 4096, 8, gupC);
        k_scatter_red<<<Bn * KCn, 256, 0, stream>>>(xp, ao, gupC, g, sel);
    }

    // decoder: proj GEMM N=4096 (512 blocks — exact pack, no tail), mlp1 GEMM
    // splitK=4, fused win+norm reads mlp1 parts directly
    k_xcvt<<<8192, 256, 0, stream>>>(xp, xpHL, 2097152);
    k_wconv<<<dim3(128, 32), 256, 0, stream>>>(dec_proj_w, WHL, 1024, 4096, 0);
    k_mfma3<<<dim3(32, 16, 1), 256, 0, stream>>>(xpHL, WHL, projC, dec_proj_b, 2048, 4096, 1024, 1, parts);
    k_wconv<<<dim3(8, 32), 256, 0, stream>>>(dec_mlp_w1, WHL, 1024, 256, 0);
    k_mfma3<<<dim3(2, 16, 4), 256, 0, stream>>>(xpHL, WHL, nullptr, nullptr, 2048, 256, 1024, 4, parts);
    k_dec_norm_win<<<Bn * Pn * Sn, 256, 0, stream>>>(projC, parts, dec_mlp_b1, dec_mlp_w2, dec_mlp_b2, dec_norm_w, yHL);
    k_wconv<<<dim3(9, 32), 256, 0, stream>>>(head_w, WHL, 1024, 257, 0);
    k_mfma3<<<dim3(3, 64, 2), 256, 0, stream>>>(yHL, WHL, nullptr, nullptr, 8192, 257, 1024, 2, parts);
    k_reduce<<<8224, 256, 0, stream>>>(parts, out, nullptr, 2105344, 2, 257);
}